// Round 2
// baseline (1929.182 us; speedup 1.0000x reference)
//
#include <hip/hip_runtime.h>
#include <hip/hip_bf16.h>

#define TROWS 51712   // 512*101
#define NCITY 101
#define BATCH 512
#define EDIM  128
#define NQ    101

using bf16_t = __hip_bfloat16;
typedef __attribute__((ext_vector_type(8))) __bf16 bf8;
typedef __attribute__((ext_vector_type(4))) float  f32x4;

static __device__ __forceinline__ bf16_t f2b(float v) { return __float2bfloat16(v); }
static __device__ __forceinline__ float  b2f(bf16_t v) { return __bfloat162float(v); }

// ---------------- weight prep: transpose + split-bf16 ----------------
__global__ __launch_bounds__(256)
void transpose_w(const float* __restrict__ src, bf16_t* __restrict__ dhi,
                 bf16_t* __restrict__ dlo, int K, int N, int dstOff, int dstLS)
{
    int gid = blockIdx.x * 256 + threadIdx.x;
    int total = 3 * K * N;
    if (gid >= total) return;
    int l = gid / (K * N);
    int r = gid - l * (K * N);
    int k = r / N;
    int n = r - k * N;
    float w = src[gid];
    bf16_t hi = f2b(w);
    size_t o = (size_t)l * dstLS + dstOff + (size_t)n * K + k;
    dhi[o] = hi;
    dlo[o] = f2b(w - b2f(hi));
}

__global__ __launch_bounds__(256)
void pack_bias(const float* __restrict__ bq, const float* __restrict__ bk,
               const float* __restrict__ bv, float* __restrict__ dst)
{
    int gid = blockIdx.x * 256 + threadIdx.x;
    if (gid >= 3 * 384) return;
    int l = gid / 384, c = gid - l * 384;
    float v = (c < 128) ? bq[l * 128 + c]
            : (c < 256) ? bk[l * 128 + c - 128]
                        : bv[l * 128 + c - 256];
    dst[gid] = v;
}

// ---------------- embedding ----------------
__global__ __launch_bounds__(256)
void embed_kernel(const float* __restrict__ s, const int* __restrict__ d,
                  const float* __restrict__ e_w, const float* __restrict__ e_b,
                  const float* __restrict__ ep_w, const float* __restrict__ ep_b,
                  float* __restrict__ x32, bf16_t* __restrict__ xhi, bf16_t* __restrict__ xlo)
{
    int gid = blockIdx.x * 256 + threadIdx.x;      // over TROWS*128
    int row = gid >> 7;
    int c   = gid & 127;
    int b = row / NCITY;
    int n = row - b * NCITY;
    const float* sp = s + ((size_t)b * NCITY + n) * 2;
    float v;
    if (n == 0) {
        v = sp[0] * ep_w[c] + sp[1] * ep_w[128 + c] + ep_b[c];
    } else {
        float dv = (float)d[b * NCITY + n];
        v = sp[0] * e_w[c] + sp[1] * e_w[128 + c] + dv * e_w[256 + c] + e_b[c];
    }
    x32[gid] = v;
    bf16_t hi = f2b(v);
    xhi[gid] = hi;
    xlo[gid] = f2b(v - b2f(hi));
}

// ---------------- split-bf16 GEMM: C = (Ah+Al)(Bh+Bl)^T ≈ AhBh + AhBl + AlBh ----------------
// A is MxK row-major (hi/lo), Bt is NxK row-major (hi/lo), f32 accum.
// MODE 0: out split bf16 = acc + bias          (QKV)
// MODE 1: out f32  = acc + bias + res          (O-proj / FF2)
// MODE 2: out split bf16 = relu(acc + bias)    (FF1)
template<int MODE>
__global__ __launch_bounds__(256)
void gemm_bt(const bf16_t* __restrict__ Ah, const bf16_t* __restrict__ Al,
             const bf16_t* __restrict__ Bh, const bf16_t* __restrict__ Bl,
             const float* __restrict__ bias, const float* __restrict__ res,
             void* __restrict__ out_hi, void* __restrict__ out_lo,
             int K, int Nout)
{
    const int tid  = threadIdx.x;
    const int wave = tid >> 6;
    const int lane = tid & 63;
    const int quad = lane >> 4;
    const int l16  = lane & 15;
    const int m_w  = blockIdx.x * 64 + (wave >> 1) * 32;
    const int n_w  = blockIdx.y * 64 + (wave & 1) * 32;

    f32x4 acc[2][2] = {};
    const size_t aoff0 = (size_t)(m_w + l16) * K + quad * 8;
    const size_t aoff1 = aoff0 + (size_t)16 * K;
    const size_t boff0 = (size_t)(n_w + l16) * K + quad * 8;
    const size_t boff1 = boff0 + (size_t)16 * K;

    for (int k0 = 0; k0 < K; k0 += 32) {
        bf8 ah0 = *reinterpret_cast<const bf8*>(Ah + aoff0 + k0);
        bf8 ah1 = *reinterpret_cast<const bf8*>(Ah + aoff1 + k0);
        bf8 al0 = *reinterpret_cast<const bf8*>(Al + aoff0 + k0);
        bf8 al1 = *reinterpret_cast<const bf8*>(Al + aoff1 + k0);
        bf8 bh0 = *reinterpret_cast<const bf8*>(Bh + boff0 + k0);
        bf8 bh1 = *reinterpret_cast<const bf8*>(Bh + boff1 + k0);
        bf8 bl0 = *reinterpret_cast<const bf8*>(Bl + boff0 + k0);
        bf8 bl1 = *reinterpret_cast<const bf8*>(Bl + boff1 + k0);
        acc[0][0] = __builtin_amdgcn_mfma_f32_16x16x32_bf16(ah0, bh0, acc[0][0], 0, 0, 0);
        acc[0][1] = __builtin_amdgcn_mfma_f32_16x16x32_bf16(ah0, bh1, acc[0][1], 0, 0, 0);
        acc[1][0] = __builtin_amdgcn_mfma_f32_16x16x32_bf16(ah1, bh0, acc[1][0], 0, 0, 0);
        acc[1][1] = __builtin_amdgcn_mfma_f32_16x16x32_bf16(ah1, bh1, acc[1][1], 0, 0, 0);
        acc[0][0] = __builtin_amdgcn_mfma_f32_16x16x32_bf16(ah0, bl0, acc[0][0], 0, 0, 0);
        acc[0][1] = __builtin_amdgcn_mfma_f32_16x16x32_bf16(ah0, bl1, acc[0][1], 0, 0, 0);
        acc[1][0] = __builtin_amdgcn_mfma_f32_16x16x32_bf16(ah1, bl0, acc[1][0], 0, 0, 0);
        acc[1][1] = __builtin_amdgcn_mfma_f32_16x16x32_bf16(ah1, bl1, acc[1][1], 0, 0, 0);
        acc[0][0] = __builtin_amdgcn_mfma_f32_16x16x32_bf16(al0, bh0, acc[0][0], 0, 0, 0);
        acc[0][1] = __builtin_amdgcn_mfma_f32_16x16x32_bf16(al0, bh1, acc[0][1], 0, 0, 0);
        acc[1][0] = __builtin_amdgcn_mfma_f32_16x16x32_bf16(al1, bh0, acc[1][0], 0, 0, 0);
        acc[1][1] = __builtin_amdgcn_mfma_f32_16x16x32_bf16(al1, bh1, acc[1][1], 0, 0, 0);
    }

    #pragma unroll
    for (int mi = 0; mi < 2; ++mi)
    #pragma unroll
    for (int ni = 0; ni < 2; ++ni) {
        int col = n_w + ni * 16 + l16;
        float bvv = bias[col];
        #pragma unroll
        for (int r = 0; r < 4; ++r) {
            int row = m_w + mi * 16 + quad * 4 + r;
            float v = acc[mi][ni][r] + bvv;
            size_t off = (size_t)row * Nout + col;
            if (MODE == 0) {
                bf16_t hi = f2b(v);
                ((bf16_t*)out_hi)[off] = hi;
                ((bf16_t*)out_lo)[off] = f2b(v - b2f(hi));
            } else if (MODE == 1) {
                ((float*)out_hi)[off] = v + res[off];
            } else {
                v = v > 0.0f ? v : 0.0f;
                bf16_t hi = f2b(v);
                ((bf16_t*)out_hi)[off] = hi;
                ((bf16_t*)out_lo)[off] = f2b(v - b2f(hi));
            }
        }
    }
}

// ---------------- attention: one block per (b, head), f32 math from split inputs ----------------
__global__ __launch_bounds__(256)
void attn_kernel(const bf16_t* __restrict__ qkvh, const bf16_t* __restrict__ qkvl,
                 bf16_t* __restrict__ ohi, bf16_t* __restrict__ olo)
{
    __shared__ float qs[NQ * 17];
    __shared__ float ks[NQ * 17];
    __shared__ float vs[NQ * 17];
    __shared__ float sc[NQ * NQ];

    int bh = blockIdx.x;
    int b = bh >> 3;
    int h = bh & 7;
    int tid = threadIdx.x;
    const size_t base = (size_t)b * NCITY * 384 + h * 16;

    for (int idx = tid; idx < NQ * 16; idx += 256) {
        int j = idx >> 4, t = idx & 15;
        size_t ro = base + (size_t)j * 384 + t;
        qs[j * 17 + t] = b2f(qkvh[ro])       + b2f(qkvl[ro]);
        ks[j * 17 + t] = b2f(qkvh[ro + 128]) + b2f(qkvl[ro + 128]);
        vs[j * 17 + t] = b2f(qkvh[ro + 256]) + b2f(qkvl[ro + 256]);
    }
    __syncthreads();

    const float scale = 0.25f;  // 1/sqrt(16)
    for (int idx = tid; idx < NQ * NQ; idx += 256) {
        int i = idx / NQ;
        int j = idx - i * NQ;
        float acc = 0.0f;
        #pragma unroll
        for (int t = 0; t < 16; ++t) acc += qs[i * 17 + t] * ks[j * 17 + t];
        sc[idx] = acc * scale;
    }
    __syncthreads();

    for (int i = tid; i < NQ; i += 256) {
        float* row = sc + i * NQ;
        float m = -1e30f;
        for (int j = 0; j < NQ; ++j) m = fmaxf(m, row[j]);
        float sum = 0.0f;
        for (int j = 0; j < NQ; ++j) { float e = __expf(row[j] - m); row[j] = e; sum += e; }
        float inv = 1.0f / sum;
        for (int j = 0; j < NQ; ++j) row[j] *= inv;
    }
    __syncthreads();

    for (int idx = tid; idx < NQ * 16; idx += 256) {
        int i = idx >> 4, t = idx & 15;
        float acc = 0.0f;
        for (int j = 0; j < NQ; ++j) acc += sc[i * NQ + j] * vs[j * 17 + t];
        size_t off = ((size_t)b * NCITY + i) * 128 + h * 16 + t;
        bf16_t hi = f2b(acc);
        ohi[off] = hi;
        olo[off] = f2b(acc - b2f(hi));
    }
}

// ---------------- BatchNorm (train mode, biased var) ----------------
__global__ __launch_bounds__(256)
void bn_partial(const float* __restrict__ y, float* __restrict__ stats)
{
    int tid = threadIdx.x;
    int c = tid & 127;
    int half = tid >> 7;
    size_t base = (size_t)blockIdx.x * 128 * 128;   // 128 rows per block
    float s = 0.0f, ss = 0.0f;
    for (int r = half; r < 128; r += 2) {
        float v = y[base + (size_t)r * 128 + c];
        s += v; ss += v * v;
    }
    __shared__ float ls[256], lss[256];
    ls[tid] = s; lss[tid] = ss;
    __syncthreads();
    if (half == 0) {
        s  += ls[tid + 128];
        ss += lss[tid + 128];
        atomicAdd(&stats[c], s);
        atomicAdd(&stats[128 + c], ss);
    }
}

__global__ void bn_final(const float* __restrict__ stats, const float* __restrict__ g,
                         const float* __restrict__ be, float* __restrict__ sh)
{
    int c = threadIdx.x;  // 128 threads
    const float invN = 1.0f / (float)TROWS;
    float mean = stats[c] * invN;
    float var  = stats[128 + c] * invN - mean * mean;
    float inv  = rsqrtf(var + 1e-5f);
    float scl  = g[c] * inv;
    sh[c]       = scl;
    sh[128 + c] = be[c] - mean * scl;
}

__global__ __launch_bounds__(256)
void bn_apply(const float* __restrict__ y, const float* __restrict__ sh,
              float* __restrict__ x32, bf16_t* __restrict__ xhi, bf16_t* __restrict__ xlo)
{
    int gid = blockIdx.x * 256 + threadIdx.x;
    int c = gid & 127;
    float v = y[gid] * sh[c] + sh[128 + c];
    x32[gid] = v;
    bf16_t hi = f2b(v);
    xhi[gid] = hi;
    xlo[gid] = f2b(v - b2f(hi));
}

// ---------------- launch ----------------
extern "C" void kernel_launch(void* const* d_in, const int* in_sizes, int n_in,
                              void* d_out, int out_size, void* d_ws, size_t ws_size,
                              hipStream_t stream)
{
    const float* s    = (const float*)d_in[0];
    const int*   dd   = (const int*)d_in[1];
    const float* e_w  = (const float*)d_in[2];
    const float* e_b  = (const float*)d_in[3];
    const float* ep_w = (const float*)d_in[4];
    const float* ep_b = (const float*)d_in[5];
    const float* Wq   = (const float*)d_in[6];
    const float* bq   = (const float*)d_in[7];
    const float* Wk   = (const float*)d_in[8];
    const float* bk   = (const float*)d_in[9];
    const float* Wv   = (const float*)d_in[10];
    const float* bv   = (const float*)d_in[11];
    const float* Wo   = (const float*)d_in[12];
    const float* bo   = (const float*)d_in[13];
    const float* Wf1  = (const float*)d_in[14];
    const float* bf1  = (const float*)d_in[15];
    const float* Wf2  = (const float*)d_in[16];
    const float* bf2  = (const float*)d_in[17];
    const float* g1   = (const float*)d_in[18];
    const float* be1  = (const float*)d_in[19];
    const float* g2   = (const float*)d_in[20];
    const float* be2  = (const float*)d_in[21];

    char* ws = (char*)d_ws;
    size_t off = 0;
    auto alloc = [&](size_t bytes) -> void* {
        void* p = ws + off;
        off += (bytes + 255) & ~(size_t)255;
        return p;
    };
    float*  x32   = (float*) alloc((size_t)TROWS * 128 * 4);
    float*  y32   = (float*) alloc((size_t)TROWS * 128 * 4);
    bf16_t* xhi   = (bf16_t*)alloc((size_t)TROWS * 128 * 2);
    bf16_t* xlo   = (bf16_t*)alloc((size_t)TROWS * 128 * 2);
    // qkv-hi then o-hi contiguous (TROWS*384 bytes is 256-aligned, no pad) -> h1hi aliases both
    bf16_t* qkvh  = (bf16_t*)alloc((size_t)TROWS * 384 * 2);
    bf16_t* ohi   = (bf16_t*)alloc((size_t)TROWS * 128 * 2);
    bf16_t* qkvl  = (bf16_t*)alloc((size_t)TROWS * 384 * 2);
    bf16_t* olo   = (bf16_t*)alloc((size_t)TROWS * 128 * 2);
    bf16_t* h1h   = qkvh;   // TROWS*512 region spanning qkvh..ohi
    bf16_t* h1l   = qkvl;   // TROWS*512 region spanning qkvl..olo
    bf16_t* wqkvH = (bf16_t*)alloc((size_t)3 * 384 * 128 * 2);
    bf16_t* wqkvL = (bf16_t*)alloc((size_t)3 * 384 * 128 * 2);
    bf16_t* woH   = (bf16_t*)alloc((size_t)3 * 128 * 128 * 2);
    bf16_t* woL   = (bf16_t*)alloc((size_t)3 * 128 * 128 * 2);
    bf16_t* wf1H  = (bf16_t*)alloc((size_t)3 * 512 * 128 * 2);
    bf16_t* wf1L  = (bf16_t*)alloc((size_t)3 * 512 * 128 * 2);
    bf16_t* wf2H  = (bf16_t*)alloc((size_t)3 * 128 * 512 * 2);
    bf16_t* wf2L  = (bf16_t*)alloc((size_t)3 * 128 * 512 * 2);
    float*  bqkv  = (float*) alloc((size_t)3 * 384 * 4);
    float*  stats = (float*) alloc(256 * 4);
    float*  sh    = (float*) alloc(256 * 4);

    dim3 blk(256);

    // weight prep
    transpose_w<<<dim3(192), blk, 0, stream>>>(Wq,  wqkvH, wqkvL, 128, 128, 0,     49152);
    transpose_w<<<dim3(192), blk, 0, stream>>>(Wk,  wqkvH, wqkvL, 128, 128, 16384, 49152);
    transpose_w<<<dim3(192), blk, 0, stream>>>(Wv,  wqkvH, wqkvL, 128, 128, 32768, 49152);
    transpose_w<<<dim3(192), blk, 0, stream>>>(Wo,  woH,   woL,   128, 128, 0,     16384);
    transpose_w<<<dim3(768), blk, 0, stream>>>(Wf1, wf1H,  wf1L,  128, 512, 0,     65536);
    transpose_w<<<dim3(768), blk, 0, stream>>>(Wf2, wf2H,  wf2L,  512, 128, 0,     65536);
    pack_bias<<<dim3(5), blk, 0, stream>>>(bq, bk, bv, bqkv);

    embed_kernel<<<dim3(TROWS * 128 / 256), blk, 0, stream>>>(s, dd, e_w, e_b, ep_w, ep_b,
                                                              x32, xhi, xlo);

    for (int l = 0; l < 3; ++l) {
        // QKV (split)
        gemm_bt<0><<<dim3(808, 6), blk, 0, stream>>>(xhi, xlo,
                                                     wqkvH + (size_t)l * 49152, wqkvL + (size_t)l * 49152,
                                                     bqkv + l * 384, nullptr, qkvh, qkvl, 128, 384);
        // attention
        attn_kernel<<<dim3(4096), blk, 0, stream>>>(qkvh, qkvl, ohi, olo);
        // O-proj + bias + residual
        gemm_bt<1><<<dim3(808, 2), blk, 0, stream>>>(ohi, olo,
                                                     woH + (size_t)l * 16384, woL + (size_t)l * 16384,
                                                     bo + l * 128, x32, y32, nullptr, 128, 128);
        // BN1
        hipMemsetAsync(stats, 0, 256 * 4, stream);
        bn_partial<<<dim3(404), blk, 0, stream>>>(y32, stats);
        bn_final<<<dim3(1), dim3(128), 0, stream>>>(stats, g1 + l * 128, be1 + l * 128, sh);
        bn_apply<<<dim3(TROWS * 128 / 256), blk, 0, stream>>>(y32, sh, x32, xhi, xlo);
        // FF1 (ReLU, split out)
        gemm_bt<2><<<dim3(808, 8), blk, 0, stream>>>(xhi, xlo,
                                                     wf1H + (size_t)l * 65536, wf1L + (size_t)l * 65536,
                                                     bf1 + l * 512, nullptr, h1h, h1l, 128, 512);
        // FF2 + bias + residual
        gemm_bt<1><<<dim3(808, 2), blk, 0, stream>>>(h1h, h1l,
                                                     wf2H + (size_t)l * 65536, wf2L + (size_t)l * 65536,
                                                     bf2 + l * 128, x32, y32, nullptr, 512, 128);
        // BN2
        hipMemsetAsync(stats, 0, 256 * 4, stream);
        bn_partial<<<dim3(404), blk, 0, stream>>>(y32, stats);
        bn_final<<<dim3(1), dim3(128), 0, stream>>>(stats, g2 + l * 128, be2 + l * 128, sh);
        float* xdst = (l == 2) ? (float*)d_out : x32;
        bn_apply<<<dim3(TROWS * 128 / 256), blk, 0, stream>>>(y32, sh, xdst, xhi, xlo);
    }
}

// Round 3
// 1646.395 us; speedup vs baseline: 1.1718x; 1.1718x over previous
//
#include <hip/hip_runtime.h>
#include <hip/hip_bf16.h>

#define TROWS 51712   // 512*101
#define NCITY 101
#define BATCH 512
#define EDIM  128
#define NQ    101

using bf16_t = __hip_bfloat16;
typedef __attribute__((ext_vector_type(8))) __bf16 bf8;
typedef __attribute__((ext_vector_type(4))) __bf16 bf4;
typedef __attribute__((ext_vector_type(4))) float  f32x4;

static __device__ __forceinline__ bf16_t f2b(float v) { return __float2bfloat16(v); }
static __device__ __forceinline__ float  b2f(bf16_t v) { return __bfloat162float(v); }

// ---------------- weight prep: transpose + split-bf16 ----------------
__global__ __launch_bounds__(256)
void transpose_w(const float* __restrict__ src, bf16_t* __restrict__ dhi,
                 bf16_t* __restrict__ dlo, int K, int N, int dstOff, int dstLS)
{
    int gid = blockIdx.x * 256 + threadIdx.x;
    int total = 3 * K * N;
    if (gid >= total) return;
    int l = gid / (K * N);
    int r = gid - l * (K * N);
    int k = r / N;
    int n = r - k * N;
    float w = src[gid];
    bf16_t hi = f2b(w);
    size_t o = (size_t)l * dstLS + dstOff + (size_t)n * K + k;
    dhi[o] = hi;
    dlo[o] = f2b(w - b2f(hi));
}

__global__ __launch_bounds__(256)
void pack_bias(const float* __restrict__ bq, const float* __restrict__ bk,
               const float* __restrict__ bv, float* __restrict__ dst)
{
    int gid = blockIdx.x * 256 + threadIdx.x;
    if (gid >= 3 * 384) return;
    int l = gid / 384, c = gid - l * 384;
    float v = (c < 128) ? bq[l * 128 + c]
            : (c < 256) ? bk[l * 128 + c - 128]
                        : bv[l * 128 + c - 256];
    dst[gid] = v;
}

// ---------------- embedding ----------------
__global__ __launch_bounds__(256)
void embed_kernel(const float* __restrict__ s, const int* __restrict__ d,
                  const float* __restrict__ e_w, const float* __restrict__ e_b,
                  const float* __restrict__ ep_w, const float* __restrict__ ep_b,
                  float* __restrict__ x32, bf16_t* __restrict__ xhi, bf16_t* __restrict__ xlo)
{
    int gid = blockIdx.x * 256 + threadIdx.x;      // over TROWS*128
    int row = gid >> 7;
    int c   = gid & 127;
    int b = row / NCITY;
    int n = row - b * NCITY;
    const float* sp = s + ((size_t)b * NCITY + n) * 2;
    float v;
    if (n == 0) {
        v = sp[0] * ep_w[c] + sp[1] * ep_w[128 + c] + ep_b[c];
    } else {
        float dv = (float)d[b * NCITY + n];
        v = sp[0] * e_w[c] + sp[1] * e_w[128 + c] + dv * e_w[256 + c] + e_b[c];
    }
    x32[gid] = v;
    bf16_t hi = f2b(v);
    xhi[gid] = hi;
    xlo[gid] = f2b(v - b2f(hi));
}

// ---------------- split-bf16 GEMM: C = (Ah+Al)(Bh+Bl)^T ≈ AhBh + AhBl + AlBh ----------------
template<int MODE>
__global__ __launch_bounds__(256)
void gemm_bt(const bf16_t* __restrict__ Ah, const bf16_t* __restrict__ Al,
             const bf16_t* __restrict__ Bh, const bf16_t* __restrict__ Bl,
             const float* __restrict__ bias, const float* __restrict__ res,
             void* __restrict__ out_hi, void* __restrict__ out_lo,
             int K, int Nout)
{
    const int tid  = threadIdx.x;
    const int wave = tid >> 6;
    const int lane = tid & 63;
    const int quad = lane >> 4;
    const int l16  = lane & 15;
    const int m_w  = blockIdx.x * 64 + (wave >> 1) * 32;
    const int n_w  = blockIdx.y * 64 + (wave & 1) * 32;

    f32x4 acc[2][2] = {};
    const size_t aoff0 = (size_t)(m_w + l16) * K + quad * 8;
    const size_t aoff1 = aoff0 + (size_t)16 * K;
    const size_t boff0 = (size_t)(n_w + l16) * K + quad * 8;
    const size_t boff1 = boff0 + (size_t)16 * K;

    for (int k0 = 0; k0 < K; k0 += 32) {
        bf8 ah0 = *reinterpret_cast<const bf8*>(Ah + aoff0 + k0);
        bf8 ah1 = *reinterpret_cast<const bf8*>(Ah + aoff1 + k0);
        bf8 al0 = *reinterpret_cast<const bf8*>(Al + aoff0 + k0);
        bf8 al1 = *reinterpret_cast<const bf8*>(Al + aoff1 + k0);
        bf8 bh0 = *reinterpret_cast<const bf8*>(Bh + boff0 + k0);
        bf8 bh1 = *reinterpret_cast<const bf8*>(Bh + boff1 + k0);
        bf8 bl0 = *reinterpret_cast<const bf8*>(Bl + boff0 + k0);
        bf8 bl1 = *reinterpret_cast<const bf8*>(Bl + boff1 + k0);
        acc[0][0] = __builtin_amdgcn_mfma_f32_16x16x32_bf16(ah0, bh0, acc[0][0], 0, 0, 0);
        acc[0][1] = __builtin_amdgcn_mfma_f32_16x16x32_bf16(ah0, bh1, acc[0][1], 0, 0, 0);
        acc[1][0] = __builtin_amdgcn_mfma_f32_16x16x32_bf16(ah1, bh0, acc[1][0], 0, 0, 0);
        acc[1][1] = __builtin_amdgcn_mfma_f32_16x16x32_bf16(ah1, bh1, acc[1][1], 0, 0, 0);
        acc[0][0] = __builtin_amdgcn_mfma_f32_16x16x32_bf16(ah0, bl0, acc[0][0], 0, 0, 0);
        acc[0][1] = __builtin_amdgcn_mfma_f32_16x16x32_bf16(ah0, bl1, acc[0][1], 0, 0, 0);
        acc[1][0] = __builtin_amdgcn_mfma_f32_16x16x32_bf16(ah1, bl0, acc[1][0], 0, 0, 0);
        acc[1][1] = __builtin_amdgcn_mfma_f32_16x16x32_bf16(ah1, bl1, acc[1][1], 0, 0, 0);
        acc[0][0] = __builtin_amdgcn_mfma_f32_16x16x32_bf16(al0, bh0, acc[0][0], 0, 0, 0);
        acc[0][1] = __builtin_amdgcn_mfma_f32_16x16x32_bf16(al0, bh1, acc[0][1], 0, 0, 0);
        acc[1][0] = __builtin_amdgcn_mfma_f32_16x16x32_bf16(al1, bh0, acc[1][0], 0, 0, 0);
        acc[1][1] = __builtin_amdgcn_mfma_f32_16x16x32_bf16(al1, bh1, acc[1][1], 0, 0, 0);
    }

    #pragma unroll
    for (int mi = 0; mi < 2; ++mi)
    #pragma unroll
    for (int ni = 0; ni < 2; ++ni) {
        int col = n_w + ni * 16 + l16;
        float bvv = bias[col];
        #pragma unroll
        for (int r = 0; r < 4; ++r) {
            int row = m_w + mi * 16 + quad * 4 + r;
            float v = acc[mi][ni][r] + bvv;
            size_t off = (size_t)row * Nout + col;
            if (MODE == 0) {
                bf16_t hi = f2b(v);
                ((bf16_t*)out_hi)[off] = hi;
                ((bf16_t*)out_lo)[off] = f2b(v - b2f(hi));
            } else if (MODE == 1) {
                ((float*)out_hi)[off] = v + res[off];
            } else {
                v = v > 0.0f ? v : 0.0f;
                bf16_t hi = f2b(v);
                ((bf16_t*)out_hi)[off] = hi;
                ((bf16_t*)out_lo)[off] = f2b(v - b2f(hi));
            }
        }
    }
}

// ---------------- MFMA attention: one block per (b, head), 4 waves ----------------
// S^T = K·Q^T via mfma(A=K, B=Q): C-frag lane holds col=l16=query i, row=quad*4+r=key j.
// Softmax = per-column reduce (in-lane 28 vals + shfl_xor 16,32).
// O^T = V^T·P^T: P^T B-frag (k=quad*8+jj over keys) gathered from S^T C-frags via shuffles.
__global__ __launch_bounds__(256)
void attn_kernel(const bf16_t* __restrict__ qkvh, const bf16_t* __restrict__ qkvl,
                 bf16_t* __restrict__ ohi, bf16_t* __restrict__ olo)
{
    __shared__ alignas(16) __bf16 KhS[112 * 40];   // [key j][dk padded 16->32, stride 40]
    __shared__ alignas(16) __bf16 KlS[112 * 40];
    __shared__ alignas(16) __bf16 VhS[16 * 136];   // V^T: [dk t][key j padded ->128, stride 136]
    __shared__ alignas(16) __bf16 VlS[16 * 136];

    const int bh = blockIdx.x;
    const int b = bh >> 3, h = bh & 7;
    const int tid = threadIdx.x;
    const size_t base = (size_t)b * NCITY * 384 + h * 16;

    const __bf16 z = (__bf16)0.0f;
    for (int idx = tid; idx < 112 * 32; idx += 256) {
        int j = idx >> 5, t = idx & 31;
        __bf16 kh = z, kl = z;
        if (j < NCITY && t < 16) {
            size_t ro = base + (size_t)j * 384 + 128 + t;
            kh = __builtin_bit_cast(__bf16, qkvh[ro]);
            kl = __builtin_bit_cast(__bf16, qkvl[ro]);
        }
        KhS[j * 40 + t] = kh;
        KlS[j * 40 + t] = kl;
    }
    for (int idx = tid; idx < 16 * 128; idx += 256) {
        int t = idx >> 7, j = idx & 127;
        __bf16 vh = z, vl = z;
        if (j < NCITY) {
            size_t ro = base + (size_t)j * 384 + 256 + t;
            vh = __builtin_bit_cast(__bf16, qkvh[ro]);
            vl = __builtin_bit_cast(__bf16, qkvl[ro]);
        }
        VhS[t * 136 + j] = vh;
        VlS[t * 136 + j] = vl;
    }
    __syncthreads();

    const int wave = tid >> 6, lane = tid & 63, quad = lane >> 4, l16 = lane & 15;
    const int s0 = l16 + (((2 * quad)     & 3) << 4);
    const int s1 = l16 + (((2 * quad + 1) & 3) << 4);

    for (int it = wave; it < 7; it += 4) {
        // Q B-frag: col=l16 = query row, k=quad*8+jj = dk (zero for dk>=16)
        int row = b * NCITY + it * 16 + l16;
        if (row > TROWS - 1) row = TROWS - 1;   // padded queries: garbage, contained per-column
        bf8 qh = {}, ql = {};
        if (quad < 2) {
            size_t qo = (size_t)row * 384 + h * 16 + quad * 8;
            qh = *reinterpret_cast<const bf8*>(qkvh + qo);
            ql = *reinterpret_cast<const bf8*>(qkvl + qo);
        }
        f32x4 S[7];
        #pragma unroll
        for (int jt = 0; jt < 7; ++jt) {
            bf8 kh = *reinterpret_cast<const bf8*>(KhS + (jt * 16 + l16) * 40 + quad * 8);
            bf8 kl = *reinterpret_cast<const bf8*>(KlS + (jt * 16 + l16) * 40 + quad * 8);
            f32x4 a = {};
            a = __builtin_amdgcn_mfma_f32_16x16x32_bf16(kh, qh, a, 0, 0, 0);
            a = __builtin_amdgcn_mfma_f32_16x16x32_bf16(kh, ql, a, 0, 0, 0);
            a = __builtin_amdgcn_mfma_f32_16x16x32_bf16(kl, qh, a, 0, 0, 0);
            S[jt] = a;
        }
        // softmax over keys (columns are queries i=l16; key index = jt*16+quad*4+r)
        float m = -1e30f;
        #pragma unroll
        for (int jt = 0; jt < 7; ++jt)
            #pragma unroll
            for (int r = 0; r < 4; ++r) { S[jt][r] *= 0.25f; m = fmaxf(m, S[jt][r]); }
        m = fmaxf(m, __shfl_xor(m, 16));
        m = fmaxf(m, __shfl_xor(m, 32));
        float sum = 0.0f;
        #pragma unroll
        for (int jt = 0; jt < 7; ++jt)
            #pragma unroll
            for (int r = 0; r < 4; ++r) {
                int jg = jt * 16 + quad * 4 + r;
                float e = (jg < NCITY) ? __expf(S[jt][r] - m) : 0.0f;
                S[jt][r] = e;
                sum += e;
            }
        sum += __shfl_xor(sum, 16);
        sum += __shfl_xor(sum, 32);
        float inv = 1.0f / sum;
        #pragma unroll
        for (int jt = 0; jt < 7; ++jt)
            #pragma unroll
            for (int r = 0; r < 4; ++r) S[jt][r] *= inv;

        // O^T = V^T · P^T, K-blocks of 32 keys; P^T frag gathered via shuffles
        f32x4 O = {};
        #pragma unroll
        for (int p = 0; p < 4; ++p) {
            float pj[8];
            #pragma unroll
            for (int r = 0; r < 4; ++r) {
                float t0 = S[2 * p][r];
                float t1 = (2 * p + 1 < 7) ? S[2 * p + 1][r] : 0.0f;
                float x0 = __shfl(t0, s0);
                float y0 = __shfl(t1, s0);
                float x1 = __shfl(t0, s1);
                float y1 = __shfl(t1, s1);
                pj[r]     = (quad < 2) ? x0 : y0;
                pj[4 + r] = (quad < 2) ? x1 : y1;
            }
            bf8 ph, pl;
            #pragma unroll
            for (int jj = 0; jj < 8; ++jj) {
                bf16_t hb = f2b(pj[jj]);
                ph[jj] = __builtin_bit_cast(__bf16, hb);
                pl[jj] = __builtin_bit_cast(__bf16, f2b(pj[jj] - b2f(hb)));
            }
            bf8 vh = *reinterpret_cast<const bf8*>(VhS + l16 * 136 + p * 32 + quad * 8);
            bf8 vl = *reinterpret_cast<const bf8*>(VlS + l16 * 136 + p * 32 + quad * 8);
            O = __builtin_amdgcn_mfma_f32_16x16x32_bf16(vh, ph, O, 0, 0, 0);
            O = __builtin_amdgcn_mfma_f32_16x16x32_bf16(vh, pl, O, 0, 0, 0);
            O = __builtin_amdgcn_mfma_f32_16x16x32_bf16(vl, ph, O, 0, 0, 0);
        }
        // O^T C-frag: lane holds O[t=quad*4+r][i=l16]
        int i = it * 16 + l16;
        if (i < NCITY) {
            size_t oo = ((size_t)b * NCITY + i) * 128 + h * 16 + quad * 4;
            bf4 oh4, ol4;
            #pragma unroll
            for (int r = 0; r < 4; ++r) {
                float v = O[r];
                bf16_t hb = f2b(v);
                oh4[r] = __builtin_bit_cast(__bf16, hb);
                ol4[r] = __builtin_bit_cast(__bf16, f2b(v - b2f(hb)));
            }
            *reinterpret_cast<bf4*>(ohi + oo) = oh4;
            *reinterpret_cast<bf4*>(olo + oo) = ol4;
        }
    }
}

// ---------------- BatchNorm (train mode, biased var) ----------------
__global__ __launch_bounds__(256)
void bn_partial(const float* __restrict__ y, float* __restrict__ stats)
{
    int tid = threadIdx.x;
    int c = tid & 127;
    int half = tid >> 7;
    size_t base = (size_t)blockIdx.x * 128 * 128;   // 128 rows per block
    float s = 0.0f, ss = 0.0f;
    for (int r = half; r < 128; r += 2) {
        float v = y[base + (size_t)r * 128 + c];
        s += v; ss += v * v;
    }
    __shared__ float ls[256], lss[256];
    ls[tid] = s; lss[tid] = ss;
    __syncthreads();
    if (half == 0) {
        s  += ls[tid + 128];
        ss += lss[tid + 128];
        atomicAdd(&stats[c], s);
        atomicAdd(&stats[128 + c], ss);
    }
}

__global__ void bn_final(const float* __restrict__ stats, const float* __restrict__ g,
                         const float* __restrict__ be, float* __restrict__ sh)
{
    int c = threadIdx.x;  // 128 threads
    const float invN = 1.0f / (float)TROWS;
    float mean = stats[c] * invN;
    float var  = stats[128 + c] * invN - mean * mean;
    float inv  = rsqrtf(var + 1e-5f);
    float scl  = g[c] * inv;
    sh[c]       = scl;
    sh[128 + c] = be[c] - mean * scl;
}

__global__ __launch_bounds__(256)
void bn_apply(const float* __restrict__ y, const float* __restrict__ sh,
              float* __restrict__ x32, bf16_t* __restrict__ xhi, bf16_t* __restrict__ xlo)
{
    int gid = blockIdx.x * 256 + threadIdx.x;
    int c = gid & 127;
    float v = y[gid] * sh[c] + sh[128 + c];
    x32[gid] = v;
    bf16_t hi = f2b(v);
    xhi[gid] = hi;
    xlo[gid] = f2b(v - b2f(hi));
}

// ---------------- launch ----------------
extern "C" void kernel_launch(void* const* d_in, const int* in_sizes, int n_in,
                              void* d_out, int out_size, void* d_ws, size_t ws_size,
                              hipStream_t stream)
{
    const float* s    = (const float*)d_in[0];
    const int*   dd   = (const int*)d_in[1];
    const float* e_w  = (const float*)d_in[2];
    const float* e_b  = (const float*)d_in[3];
    const float* ep_w = (const float*)d_in[4];
    const float* ep_b = (const float*)d_in[5];
    const float* Wq   = (const float*)d_in[6];
    const float* bq   = (const float*)d_in[7];
    const float* Wk   = (const float*)d_in[8];
    const float* bk   = (const float*)d_in[9];
    const float* Wv   = (const float*)d_in[10];
    const float* bv   = (const float*)d_in[11];
    const float* Wo   = (const float*)d_in[12];
    const float* bo   = (const float*)d_in[13];
    const float* Wf1  = (const float*)d_in[14];
    const float* bf1  = (const float*)d_in[15];
    const float* Wf2  = (const float*)d_in[16];
    const float* bf2  = (const float*)d_in[17];
    const float* g1   = (const float*)d_in[18];
    const float* be1  = (const float*)d_in[19];
    const float* g2   = (const float*)d_in[20];
    const float* be2  = (const float*)d_in[21];

    char* ws = (char*)d_ws;
    size_t off = 0;
    auto alloc = [&](size_t bytes) -> void* {
        void* p = ws + off;
        off += (bytes + 255) & ~(size_t)255;
        return p;
    };
    float*  x32   = (float*) alloc((size_t)TROWS * 128 * 4);
    float*  y32   = (float*) alloc((size_t)TROWS * 128 * 4);
    bf16_t* xhi   = (bf16_t*)alloc((size_t)TROWS * 128 * 2);
    bf16_t* xlo   = (bf16_t*)alloc((size_t)TROWS * 128 * 2);
    bf16_t* qkvh  = (bf16_t*)alloc((size_t)TROWS * 384 * 2);
    bf16_t* ohi   = (bf16_t*)alloc((size_t)TROWS * 128 * 2);
    bf16_t* qkvl  = (bf16_t*)alloc((size_t)TROWS * 384 * 2);
    bf16_t* olo   = (bf16_t*)alloc((size_t)TROWS * 128 * 2);
    bf16_t* h1h   = qkvh;   // TROWS*512 region spanning qkvh..ohi
    bf16_t* h1l   = qkvl;   // TROWS*512 region spanning qkvl..olo
    bf16_t* wqkvH = (bf16_t*)alloc((size_t)3 * 384 * 128 * 2);
    bf16_t* wqkvL = (bf16_t*)alloc((size_t)3 * 384 * 128 * 2);
    bf16_t* woH   = (bf16_t*)alloc((size_t)3 * 128 * 128 * 2);
    bf16_t* woL   = (bf16_t*)alloc((size_t)3 * 128 * 128 * 2);
    bf16_t* wf1H  = (bf16_t*)alloc((size_t)3 * 512 * 128 * 2);
    bf16_t* wf1L  = (bf16_t*)alloc((size_t)3 * 512 * 128 * 2);
    bf16_t* wf2H  = (bf16_t*)alloc((size_t)3 * 128 * 512 * 2);
    bf16_t* wf2L  = (bf16_t*)alloc((size_t)3 * 128 * 512 * 2);
    float*  bqkv  = (float*) alloc((size_t)3 * 384 * 4);
    float*  stats = (float*) alloc(256 * 4);
    float*  sh    = (float*) alloc(256 * 4);

    dim3 blk(256);

    // weight prep
    transpose_w<<<dim3(192), blk, 0, stream>>>(Wq,  wqkvH, wqkvL, 128, 128, 0,     49152);
    transpose_w<<<dim3(192), blk, 0, stream>>>(Wk,  wqkvH, wqkvL, 128, 128, 16384, 49152);
    transpose_w<<<dim3(192), blk, 0, stream>>>(Wv,  wqkvH, wqkvL, 128, 128, 32768, 49152);
    transpose_w<<<dim3(192), blk, 0, stream>>>(Wo,  woH,   woL,   128, 128, 0,     16384);
    transpose_w<<<dim3(768), blk, 0, stream>>>(Wf1, wf1H,  wf1L,  128, 512, 0,     65536);
    transpose_w<<<dim3(768), blk, 0, stream>>>(Wf2, wf2H,  wf2L,  512, 128, 0,     65536);
    pack_bias<<<dim3(5), blk, 0, stream>>>(bq, bk, bv, bqkv);

    embed_kernel<<<dim3(TROWS * 128 / 256), blk, 0, stream>>>(s, dd, e_w, e_b, ep_w, ep_b,
                                                              x32, xhi, xlo);

    for (int l = 0; l < 3; ++l) {
        // QKV (split)
        gemm_bt<0><<<dim3(808, 6), blk, 0, stream>>>(xhi, xlo,
                                                     wqkvH + (size_t)l * 49152, wqkvL + (size_t)l * 49152,
                                                     bqkv + l * 384, nullptr, qkvh, qkvl, 128, 384);
        // attention (MFMA)
        attn_kernel<<<dim3(4096), blk, 0, stream>>>(qkvh, qkvl, ohi, olo);
        // O-proj + bias + residual
        gemm_bt<1><<<dim3(808, 2), blk, 0, stream>>>(ohi, olo,
                                                     woH + (size_t)l * 16384, woL + (size_t)l * 16384,
                                                     bo + l * 128, x32, y32, nullptr, 128, 128);
        // BN1
        hipMemsetAsync(stats, 0, 256 * 4, stream);
        bn_partial<<<dim3(404), blk, 0, stream>>>(y32, stats);
        bn_final<<<dim3(1), dim3(128), 0, stream>>>(stats, g1 + l * 128, be1 + l * 128, sh);
        bn_apply<<<dim3(TROWS * 128 / 256), blk, 0, stream>>>(y32, sh, x32, xhi, xlo);
        // FF1 (ReLU, split out)
        gemm_bt<2><<<dim3(808, 8), blk, 0, stream>>>(xhi, xlo,
                                                     wf1H + (size_t)l * 65536, wf1L + (size_t)l * 65536,
                                                     bf1 + l * 512, nullptr, h1h, h1l, 128, 512);
        // FF2 + bias + residual
        gemm_bt<1><<<dim3(808, 2), blk, 0, stream>>>(h1h, h1l,
                                                     wf2H + (size_t)l * 65536, wf2L + (size_t)l * 65536,
                                                     bf2 + l * 128, x32, y32, nullptr, 512, 128);
        // BN2
        hipMemsetAsync(stats, 0, 256 * 4, stream);
        bn_partial<<<dim3(404), blk, 0, stream>>>(y32, stats);
        bn_final<<<dim3(1), dim3(128), 0, stream>>>(stats, g2 + l * 128, be2 + l * 128, sh);
        float* xdst = (l == 2) ? (float*)d_out : x32;
        bn_apply<<<dim3(TROWS * 128 / 256), blk, 0, stream>>>(y32, sh, xdst, xhi, xlo);
    }
}

// Round 4
// 1132.337 us; speedup vs baseline: 1.7037x; 1.4540x over previous
//
#include <hip/hip_runtime.h>
#include <hip/hip_bf16.h>

#define TROWS 51712   // 512*101
#define NCITY 101
#define BATCH 512
#define EDIM  128
#define NQ    101

using bf16_t = __hip_bfloat16;
typedef __attribute__((ext_vector_type(8))) __bf16 bf8;
typedef __attribute__((ext_vector_type(4))) __bf16 bf4;
typedef __attribute__((ext_vector_type(4))) float  f32x4;

static __device__ __forceinline__ bf16_t f2b(float v) { return __float2bfloat16(v); }
static __device__ __forceinline__ float  b2f(bf16_t v) { return __bfloat162float(v); }

// ---------------- weight prep: transpose + split-bf16 ----------------
__global__ __launch_bounds__(256)
void transpose_w(const float* __restrict__ src, bf16_t* __restrict__ dhi,
                 bf16_t* __restrict__ dlo, int K, int N, int dstOff, int dstLS)
{
    int gid = blockIdx.x * 256 + threadIdx.x;
    int total = 3 * K * N;
    if (gid >= total) return;
    int l = gid / (K * N);
    int r = gid - l * (K * N);
    int k = r / N;
    int n = r - k * N;
    float w = src[gid];
    bf16_t hi = f2b(w);
    size_t o = (size_t)l * dstLS + dstOff + (size_t)n * K + k;
    dhi[o] = hi;
    dlo[o] = f2b(w - b2f(hi));
}

__global__ __launch_bounds__(256)
void pack_bias(const float* __restrict__ bq, const float* __restrict__ bk,
               const float* __restrict__ bv, float* __restrict__ dst)
{
    int gid = blockIdx.x * 256 + threadIdx.x;
    if (gid >= 3 * 384) return;
    int l = gid / 384, c = gid - l * 384;
    float v = (c < 128) ? bq[l * 128 + c]
            : (c < 256) ? bk[l * 128 + c - 128]
                        : bv[l * 128 + c - 256];
    dst[gid] = v;
}

// ---------------- embedding ----------------
__global__ __launch_bounds__(256)
void embed_kernel(const float* __restrict__ s, const int* __restrict__ d,
                  const float* __restrict__ e_w, const float* __restrict__ e_b,
                  const float* __restrict__ ep_w, const float* __restrict__ ep_b,
                  float* __restrict__ x32, bf16_t* __restrict__ xhi, bf16_t* __restrict__ xlo)
{
    int gid = blockIdx.x * 256 + threadIdx.x;      // over TROWS*128
    int row = gid >> 7;
    int c   = gid & 127;
    int b = row / NCITY;
    int n = row - b * NCITY;
    const float* sp = s + ((size_t)b * NCITY + n) * 2;
    float v;
    if (n == 0) {
        v = sp[0] * ep_w[c] + sp[1] * ep_w[128 + c] + ep_b[c];
    } else {
        float dv = (float)d[b * NCITY + n];
        v = sp[0] * e_w[c] + sp[1] * e_w[128 + c] + dv * e_w[256 + c] + e_b[c];
    }
    x32[gid] = v;
    bf16_t hi = f2b(v);
    xhi[gid] = hi;
    xlo[gid] = f2b(v - b2f(hi));
}

// ---------------- LDS-staged split-bf16 GEMM ----------------
// C = (Ah+Al)(Bh+Bl)^T ≈ AhBh + AhBl + AlBh, f32 accum.
// Block tile 64(M) x 128(N), BK=32, 4 waves 2x2 (wave tile 32x64).
// MODE 0: out split bf16 = acc + bias          (QKV)
// MODE 1: out f32  = acc + bias + res, fused BN stats atomics (O-proj / FF2)
// MODE 2: out split bf16 = relu(acc + bias)    (FF1)
#define LDP 40   // padded LDS row stride (elements): 80 B, 16B-aligned, uniform banks
template<int MODE, int KSTEPS>
__global__ __launch_bounds__(256)
void gemm_tile(const bf16_t* __restrict__ Ah, const bf16_t* __restrict__ Al,
               const bf16_t* __restrict__ Bh, const bf16_t* __restrict__ Bl,
               const float* __restrict__ bias, const float* __restrict__ res,
               void* __restrict__ out_hi, void* __restrict__ out_lo,
               float* __restrict__ stats, int Nout)
{
    constexpr int K = KSTEPS * 32;
    __shared__ alignas(16) __bf16 sAh[64 * LDP], sAl[64 * LDP];
    __shared__ alignas(16) __bf16 sBh[128 * LDP], sBl[128 * LDP];

    const int tid = threadIdx.x;
    const int m0 = blockIdx.x * 64;
    const int n0 = blockIdx.y * 128;

    // staging: A 64x32 -> 4 threads/row (8 elems each); B 128x32 -> 2 threads/row (16 elems)
    const int ar = tid >> 2, ac = (tid & 3) * 8;
    const int br = tid >> 1, bc = (tid & 1) * 16;
    const bf16_t* gAh = Ah + (size_t)(m0 + ar) * K + ac;
    const bf16_t* gAl = Al + (size_t)(m0 + ar) * K + ac;
    const bf16_t* gBh = Bh + (size_t)(n0 + br) * K + bc;
    const bf16_t* gBl = Bl + (size_t)(n0 + br) * K + bc;

    const int wave = tid >> 6, lane = tid & 63, quad = lane >> 4, l16 = lane & 15;
    const int wm = (wave >> 1) * 32;
    const int wn = (wave & 1) * 64;

    f32x4 acc[2][4] = {};
    bf8 ra_h, ra_l, rb_h0, rb_h1, rb_l0, rb_l1;

    ra_h  = *(const bf8*)(gAh);
    ra_l  = *(const bf8*)(gAl);
    rb_h0 = *(const bf8*)(gBh);
    rb_h1 = *(const bf8*)(gBh + 8);
    rb_l0 = *(const bf8*)(gBl);
    rb_l1 = *(const bf8*)(gBl + 8);

    for (int ks = 0; ks < KSTEPS; ++ks) {
        __syncthreads();
        *(bf8*)(sAh + ar * LDP + ac) = ra_h;
        *(bf8*)(sAl + ar * LDP + ac) = ra_l;
        *(bf8*)(sBh + br * LDP + bc) = rb_h0;
        *(bf8*)(sBh + br * LDP + bc + 8) = rb_h1;
        *(bf8*)(sBl + br * LDP + bc) = rb_l0;
        *(bf8*)(sBl + br * LDP + bc + 8) = rb_l1;
        __syncthreads();
        if (ks + 1 < KSTEPS) {
            int k0 = (ks + 1) * 32;
            ra_h  = *(const bf8*)(gAh + k0);
            ra_l  = *(const bf8*)(gAl + k0);
            rb_h0 = *(const bf8*)(gBh + k0);
            rb_h1 = *(const bf8*)(gBh + k0 + 8);
            rb_l0 = *(const bf8*)(gBl + k0);
            rb_l1 = *(const bf8*)(gBl + k0 + 8);
        }
        bf8 afh[2], afl[2], bfh[4], bfl[4];
        #pragma unroll
        for (int mi = 0; mi < 2; ++mi) {
            afh[mi] = *(const bf8*)(sAh + (wm + mi * 16 + l16) * LDP + quad * 8);
            afl[mi] = *(const bf8*)(sAl + (wm + mi * 16 + l16) * LDP + quad * 8);
        }
        #pragma unroll
        for (int ni = 0; ni < 4; ++ni) {
            bfh[ni] = *(const bf8*)(sBh + (wn + ni * 16 + l16) * LDP + quad * 8);
            bfl[ni] = *(const bf8*)(sBl + (wn + ni * 16 + l16) * LDP + quad * 8);
        }
        #pragma unroll
        for (int mi = 0; mi < 2; ++mi)
        #pragma unroll
        for (int ni = 0; ni < 4; ++ni) {
            acc[mi][ni] = __builtin_amdgcn_mfma_f32_16x16x32_bf16(afh[mi], bfh[ni], acc[mi][ni], 0, 0, 0);
            acc[mi][ni] = __builtin_amdgcn_mfma_f32_16x16x32_bf16(afh[mi], bfl[ni], acc[mi][ni], 0, 0, 0);
            acc[mi][ni] = __builtin_amdgcn_mfma_f32_16x16x32_bf16(afl[mi], bfh[ni], acc[mi][ni], 0, 0, 0);
        }
    }

    // epilogue: C row = m0 + wm + mi*16 + quad*4 + r, col = n0 + wn + ni*16 + l16
    #pragma unroll
    for (int ni = 0; ni < 4; ++ni) {
        int col = n0 + wn + ni * 16 + l16;
        float bvv = bias[col];
        float s = 0.0f, ss = 0.0f;
        #pragma unroll
        for (int mi = 0; mi < 2; ++mi) {
            #pragma unroll
            for (int r = 0; r < 4; ++r) {
                int row = m0 + wm + mi * 16 + quad * 4 + r;
                float v = acc[mi][ni][r] + bvv;
                size_t off = (size_t)row * Nout + col;
                if (MODE == 0) {
                    bf16_t hi = f2b(v);
                    ((bf16_t*)out_hi)[off] = hi;
                    ((bf16_t*)out_lo)[off] = f2b(v - b2f(hi));
                } else if (MODE == 1) {
                    float o = v + res[off];
                    ((float*)out_hi)[off] = o;
                    s += o; ss += o * o;
                } else {
                    v = v > 0.0f ? v : 0.0f;
                    bf16_t hi = f2b(v);
                    ((bf16_t*)out_hi)[off] = hi;
                    ((bf16_t*)out_lo)[off] = f2b(v - b2f(hi));
                }
            }
        }
        if (MODE == 1) {
            s  += __shfl_xor(s, 16);  s  += __shfl_xor(s, 32);
            ss += __shfl_xor(ss, 16); ss += __shfl_xor(ss, 32);
            if (quad == 0) {
                atomicAdd(&stats[col], s);
                atomicAdd(&stats[128 + col], ss);
            }
        }
    }
}

// ---------------- MFMA attention: one block per (b, head), 4 waves ----------------
__global__ __launch_bounds__(256)
void attn_kernel(const bf16_t* __restrict__ qkvh, const bf16_t* __restrict__ qkvl,
                 bf16_t* __restrict__ ohi, bf16_t* __restrict__ olo)
{
    __shared__ alignas(16) __bf16 KhS[112 * 40];   // [key j][dk padded 16->32, stride 40]
    __shared__ alignas(16) __bf16 KlS[112 * 40];
    __shared__ alignas(16) __bf16 VhS[16 * 136];   // V^T: [dk t][key j padded ->128, stride 136]
    __shared__ alignas(16) __bf16 VlS[16 * 136];

    const int bh = blockIdx.x;
    const int b = bh >> 3, h = bh & 7;
    const int tid = threadIdx.x;
    const size_t base = (size_t)b * NCITY * 384 + h * 16;

    const __bf16 z = (__bf16)0.0f;
    for (int idx = tid; idx < 112 * 32; idx += 256) {
        int j = idx >> 5, t = idx & 31;
        __bf16 kh = z, kl = z;
        if (j < NCITY && t < 16) {
            size_t ro = base + (size_t)j * 384 + 128 + t;
            kh = __builtin_bit_cast(__bf16, qkvh[ro]);
            kl = __builtin_bit_cast(__bf16, qkvl[ro]);
        }
        KhS[j * 40 + t] = kh;
        KlS[j * 40 + t] = kl;
    }
    for (int idx = tid; idx < 16 * 128; idx += 256) {
        int t = idx >> 7, j = idx & 127;
        __bf16 vh = z, vl = z;
        if (j < NCITY) {
            size_t ro = base + (size_t)j * 384 + 256 + t;
            vh = __builtin_bit_cast(__bf16, qkvh[ro]);
            vl = __builtin_bit_cast(__bf16, qkvl[ro]);
        }
        VhS[t * 136 + j] = vh;
        VlS[t * 136 + j] = vl;
    }
    __syncthreads();

    const int wave = tid >> 6, lane = tid & 63, quad = lane >> 4, l16 = lane & 15;
    const int s0 = l16 + (((2 * quad)     & 3) << 4);
    const int s1 = l16 + (((2 * quad + 1) & 3) << 4);

    for (int it = wave; it < 7; it += 4) {
        int row = b * NCITY + it * 16 + l16;
        if (row > TROWS - 1) row = TROWS - 1;
        bf8 qh = {}, ql = {};
        if (quad < 2) {
            size_t qo = (size_t)row * 384 + h * 16 + quad * 8;
            qh = *reinterpret_cast<const bf8*>(qkvh + qo);
            ql = *reinterpret_cast<const bf8*>(qkvl + qo);
        }
        f32x4 S[7];
        #pragma unroll
        for (int jt = 0; jt < 7; ++jt) {
            bf8 kh = *reinterpret_cast<const bf8*>(KhS + (jt * 16 + l16) * 40 + quad * 8);
            bf8 kl = *reinterpret_cast<const bf8*>(KlS + (jt * 16 + l16) * 40 + quad * 8);
            f32x4 a = {};
            a = __builtin_amdgcn_mfma_f32_16x16x32_bf16(kh, qh, a, 0, 0, 0);
            a = __builtin_amdgcn_mfma_f32_16x16x32_bf16(kh, ql, a, 0, 0, 0);
            a = __builtin_amdgcn_mfma_f32_16x16x32_bf16(kl, qh, a, 0, 0, 0);
            S[jt] = a;
        }
        float m = -1e30f;
        #pragma unroll
        for (int jt = 0; jt < 7; ++jt)
            #pragma unroll
            for (int r = 0; r < 4; ++r) { S[jt][r] *= 0.25f; m = fmaxf(m, S[jt][r]); }
        m = fmaxf(m, __shfl_xor(m, 16));
        m = fmaxf(m, __shfl_xor(m, 32));
        float sum = 0.0f;
        #pragma unroll
        for (int jt = 0; jt < 7; ++jt)
            #pragma unroll
            for (int r = 0; r < 4; ++r) {
                int jg = jt * 16 + quad * 4 + r;
                float e = (jg < NCITY) ? __expf(S[jt][r] - m) : 0.0f;
                S[jt][r] = e;
                sum += e;
            }
        sum += __shfl_xor(sum, 16);
        sum += __shfl_xor(sum, 32);
        float inv = 1.0f / sum;
        #pragma unroll
        for (int jt = 0; jt < 7; ++jt)
            #pragma unroll
            for (int r = 0; r < 4; ++r) S[jt][r] *= inv;

        f32x4 O = {};
        #pragma unroll
        for (int p = 0; p < 4; ++p) {
            float pj[8];
            #pragma unroll
            for (int r = 0; r < 4; ++r) {
                float t0 = S[2 * p][r];
                float t1 = (2 * p + 1 < 7) ? S[2 * p + 1][r] : 0.0f;
                float x0 = __shfl(t0, s0);
                float y0 = __shfl(t1, s0);
                float x1 = __shfl(t0, s1);
                float y1 = __shfl(t1, s1);
                pj[r]     = (quad < 2) ? x0 : y0;
                pj[4 + r] = (quad < 2) ? x1 : y1;
            }
            bf8 ph, pl;
            #pragma unroll
            for (int jj = 0; jj < 8; ++jj) {
                bf16_t hb = f2b(pj[jj]);
                ph[jj] = __builtin_bit_cast(__bf16, hb);
                pl[jj] = __builtin_bit_cast(__bf16, f2b(pj[jj] - b2f(hb)));
            }
            bf8 vh = *reinterpret_cast<const bf8*>(VhS + l16 * 136 + p * 32 + quad * 8);
            bf8 vl = *reinterpret_cast<const bf8*>(VlS + l16 * 136 + p * 32 + quad * 8);
            O = __builtin_amdgcn_mfma_f32_16x16x32_bf16(vh, ph, O, 0, 0, 0);
            O = __builtin_amdgcn_mfma_f32_16x16x32_bf16(vh, pl, O, 0, 0, 0);
            O = __builtin_amdgcn_mfma_f32_16x16x32_bf16(vl, ph, O, 0, 0, 0);
        }
        int i = it * 16 + l16;
        if (i < NCITY) {
            size_t oo = ((size_t)b * NCITY + i) * 128 + h * 16 + quad * 4;
            bf4 oh4, ol4;
            #pragma unroll
            for (int r = 0; r < 4; ++r) {
                float v = O[r];
                bf16_t hb = f2b(v);
                oh4[r] = __builtin_bit_cast(__bf16, hb);
                ol4[r] = __builtin_bit_cast(__bf16, f2b(v - b2f(hb)));
            }
            *reinterpret_cast<bf4*>(ohi + oo) = oh4;
            *reinterpret_cast<bf4*>(olo + oo) = ol4;
        }
    }
}

// ---------------- BatchNorm finalize + apply ----------------
__global__ void bn_final(const float* __restrict__ stats, const float* __restrict__ g,
                         const float* __restrict__ be, float* __restrict__ sh)
{
    int c = threadIdx.x;  // 128 threads
    const float invN = 1.0f / (float)TROWS;
    float mean = stats[c] * invN;
    float var  = stats[128 + c] * invN - mean * mean;
    float inv  = rsqrtf(var + 1e-5f);
    float scl  = g[c] * inv;
    sh[c]       = scl;
    sh[128 + c] = be[c] - mean * scl;
}

__global__ __launch_bounds__(256)
void bn_apply(const float* __restrict__ y, const float* __restrict__ sh,
              float* __restrict__ x32, bf16_t* __restrict__ xhi, bf16_t* __restrict__ xlo)
{
    int gid = blockIdx.x * 256 + threadIdx.x;
    int c = gid & 127;
    float v = y[gid] * sh[c] + sh[128 + c];
    x32[gid] = v;
    bf16_t hi = f2b(v);
    xhi[gid] = hi;
    xlo[gid] = f2b(v - b2f(hi));
}

// ---------------- launch ----------------
extern "C" void kernel_launch(void* const* d_in, const int* in_sizes, int n_in,
                              void* d_out, int out_size, void* d_ws, size_t ws_size,
                              hipStream_t stream)
{
    const float* s    = (const float*)d_in[0];
    const int*   dd   = (const int*)d_in[1];
    const float* e_w  = (const float*)d_in[2];
    const float* e_b  = (const float*)d_in[3];
    const float* ep_w = (const float*)d_in[4];
    const float* ep_b = (const float*)d_in[5];
    const float* Wq   = (const float*)d_in[6];
    const float* bq   = (const float*)d_in[7];
    const float* Wk   = (const float*)d_in[8];
    const float* bk   = (const float*)d_in[9];
    const float* Wv   = (const float*)d_in[10];
    const float* bv   = (const float*)d_in[11];
    const float* Wo   = (const float*)d_in[12];
    const float* bo   = (const float*)d_in[13];
    const float* Wf1  = (const float*)d_in[14];
    const float* bf1  = (const float*)d_in[15];
    const float* Wf2  = (const float*)d_in[16];
    const float* bf2  = (const float*)d_in[17];
    const float* g1   = (const float*)d_in[18];
    const float* be1  = (const float*)d_in[19];
    const float* g2   = (const float*)d_in[20];
    const float* be2  = (const float*)d_in[21];

    char* ws = (char*)d_ws;
    size_t off = 0;
    auto alloc = [&](size_t bytes) -> void* {
        void* p = ws + off;
        off += (bytes + 255) & ~(size_t)255;
        return p;
    };
    float*  x32   = (float*) alloc((size_t)TROWS * 128 * 4);
    float*  y32   = (float*) alloc((size_t)TROWS * 128 * 4);
    bf16_t* xhi   = (bf16_t*)alloc((size_t)TROWS * 128 * 2);
    bf16_t* xlo   = (bf16_t*)alloc((size_t)TROWS * 128 * 2);
    bf16_t* qkvh  = (bf16_t*)alloc((size_t)TROWS * 384 * 2);
    bf16_t* ohi   = (bf16_t*)alloc((size_t)TROWS * 128 * 2);
    bf16_t* qkvl  = (bf16_t*)alloc((size_t)TROWS * 384 * 2);
    bf16_t* olo   = (bf16_t*)alloc((size_t)TROWS * 128 * 2);
    bf16_t* h1h   = qkvh;   // TROWS*512 region spanning qkvh..ohi
    bf16_t* h1l   = qkvl;   // TROWS*512 region spanning qkvl..olo
    bf16_t* wqkvH = (bf16_t*)alloc((size_t)3 * 384 * 128 * 2);
    bf16_t* wqkvL = (bf16_t*)alloc((size_t)3 * 384 * 128 * 2);
    bf16_t* woH   = (bf16_t*)alloc((size_t)3 * 128 * 128 * 2);
    bf16_t* woL   = (bf16_t*)alloc((size_t)3 * 128 * 128 * 2);
    bf16_t* wf1H  = (bf16_t*)alloc((size_t)3 * 512 * 128 * 2);
    bf16_t* wf1L  = (bf16_t*)alloc((size_t)3 * 512 * 128 * 2);
    bf16_t* wf2H  = (bf16_t*)alloc((size_t)3 * 128 * 512 * 2);
    bf16_t* wf2L  = (bf16_t*)alloc((size_t)3 * 128 * 512 * 2);
    float*  bqkv  = (float*) alloc((size_t)3 * 384 * 4);
    float*  stats = (float*) alloc(256 * 4);
    float*  sh    = (float*) alloc(256 * 4);

    dim3 blk(256);

    // weight prep
    transpose_w<<<dim3(192), blk, 0, stream>>>(Wq,  wqkvH, wqkvL, 128, 128, 0,     49152);
    transpose_w<<<dim3(192), blk, 0, stream>>>(Wk,  wqkvH, wqkvL, 128, 128, 16384, 49152);
    transpose_w<<<dim3(192), blk, 0, stream>>>(Wv,  wqkvH, wqkvL, 128, 128, 32768, 49152);
    transpose_w<<<dim3(192), blk, 0, stream>>>(Wo,  woH,   woL,   128, 128, 0,     16384);
    transpose_w<<<dim3(768), blk, 0, stream>>>(Wf1, wf1H,  wf1L,  128, 512, 0,     65536);
    transpose_w<<<dim3(768), blk, 0, stream>>>(Wf2, wf2H,  wf2L,  512, 128, 0,     65536);
    pack_bias<<<dim3(5), blk, 0, stream>>>(bq, bk, bv, bqkv);

    embed_kernel<<<dim3(TROWS * 128 / 256), blk, 0, stream>>>(s, dd, e_w, e_b, ep_w, ep_b,
                                                              x32, xhi, xlo);

    for (int l = 0; l < 3; ++l) {
        // QKV (split), K=128, N=384
        gemm_tile<0, 4><<<dim3(808, 3), blk, 0, stream>>>(xhi, xlo,
                                                          wqkvH + (size_t)l * 49152, wqkvL + (size_t)l * 49152,
                                                          bqkv + l * 384, nullptr, qkvh, qkvl, nullptr, 384);
        // attention (MFMA)
        attn_kernel<<<dim3(4096), blk, 0, stream>>>(qkvh, qkvl, ohi, olo);
        // O-proj + bias + residual + fused BN1 stats
        hipMemsetAsync(stats, 0, 256 * 4, stream);
        gemm_tile<1, 4><<<dim3(808, 1), blk, 0, stream>>>(ohi, olo,
                                                          woH + (size_t)l * 16384, woL + (size_t)l * 16384,
                                                          bo + l * 128, x32, y32, nullptr, stats, 128);
        bn_final<<<dim3(1), dim3(128), 0, stream>>>(stats, g1 + l * 128, be1 + l * 128, sh);
        bn_apply<<<dim3(TROWS * 128 / 256), blk, 0, stream>>>(y32, sh, x32, xhi, xlo);
        // FF1 (ReLU, split out), K=128, N=512
        gemm_tile<2, 4><<<dim3(808, 4), blk, 0, stream>>>(xhi, xlo,
                                                          wf1H + (size_t)l * 65536, wf1L + (size_t)l * 65536,
                                                          bf1 + l * 512, nullptr, h1h, h1l, nullptr, 512);
        // FF2 + bias + residual + fused BN2 stats, K=512, N=128
        hipMemsetAsync(stats, 0, 256 * 4, stream);
        gemm_tile<1, 16><<<dim3(808, 1), blk, 0, stream>>>(h1h, h1l,
                                                           wf2H + (size_t)l * 65536, wf2L + (size_t)l * 65536,
                                                           bf2 + l * 128, x32, y32, nullptr, stats, 128);
        bn_final<<<dim3(1), dim3(128), 0, stream>>>(stats, g2 + l * 128, be2 + l * 128, sh);
        float* xdst = (l == 2) ? (float*)d_out : x32;
        bn_apply<<<dim3(TROWS * 128 / 256), blk, 0, stream>>>(y32, sh, xdst, xhi, xlo);
    }
}

// Round 5
// 920.990 us; speedup vs baseline: 2.0947x; 1.2295x over previous
//
#include <hip/hip_runtime.h>
#include <hip/hip_bf16.h>

#define TROWS 51712   // 512*101
#define NCITY 101
#define BATCH 512
#define EDIM  128
#define NQ    101

using bf16_t = __hip_bfloat16;
typedef __attribute__((ext_vector_type(8))) __bf16 bf8;
typedef __attribute__((ext_vector_type(4))) __bf16 bf4;
typedef __attribute__((ext_vector_type(4))) float  f32x4;

static __device__ __forceinline__ bf16_t f2b(float v) { return __float2bfloat16(v); }
static __device__ __forceinline__ float  b2f(bf16_t v) { return __bfloat162float(v); }

// ---------------- weight prep: transpose + split-bf16 ----------------
__global__ __launch_bounds__(256)
void transpose_w(const float* __restrict__ src, bf16_t* __restrict__ dhi,
                 bf16_t* __restrict__ dlo, int K, int N, int dstOff, int dstLS)
{
    int gid = blockIdx.x * 256 + threadIdx.x;
    int total = 3 * K * N;
    if (gid >= total) return;
    int l = gid / (K * N);
    int r = gid - l * (K * N);
    int k = r / N;
    int n = r - k * N;
    float w = src[gid];
    bf16_t hi = f2b(w);
    size_t o = (size_t)l * dstLS + dstOff + (size_t)n * K + k;
    dhi[o] = hi;
    dlo[o] = f2b(w - b2f(hi));
}

__global__ __launch_bounds__(256)
void pack_bias(const float* __restrict__ bq, const float* __restrict__ bk,
               const float* __restrict__ bv, float* __restrict__ dst)
{
    int gid = blockIdx.x * 256 + threadIdx.x;
    if (gid >= 3 * 384) return;
    int l = gid / 384, c = gid - l * 384;
    float v = (c < 128) ? bq[l * 128 + c]
            : (c < 256) ? bk[l * 128 + c - 128]
                        : bv[l * 128 + c - 256];
    dst[gid] = v;
}

// ---------------- embedding ----------------
__global__ __launch_bounds__(256)
void embed_kernel(const float* __restrict__ s, const int* __restrict__ d,
                  const float* __restrict__ e_w, const float* __restrict__ e_b,
                  const float* __restrict__ ep_w, const float* __restrict__ ep_b,
                  float* __restrict__ x32, bf16_t* __restrict__ xhi, bf16_t* __restrict__ xlo)
{
    int gid = blockIdx.x * 256 + threadIdx.x;      // over TROWS*128
    int row = gid >> 7;
    int c   = gid & 127;
    int b = row / NCITY;
    int n = row - b * NCITY;
    const float* sp = s + ((size_t)b * NCITY + n) * 2;
    float v;
    if (n == 0) {
        v = sp[0] * ep_w[c] + sp[1] * ep_w[128 + c] + ep_b[c];
    } else {
        float dv = (float)d[b * NCITY + n];
        v = sp[0] * e_w[c] + sp[1] * e_w[128 + c] + dv * e_w[256 + c] + e_b[c];
    }
    x32[gid] = v;
    bf16_t hi = f2b(v);
    xhi[gid] = hi;
    xlo[gid] = f2b(v - b2f(hi));
}

// ---------------- LDS-staged split-bf16 GEMM ----------------
// ASPLIT=1: C ≈ AhBh + AhBl + AlBh.  ASPLIT=0: C ≈ AhBh + AhBl (A single bf16).
// Block tile 64(M) x 128(N), BK=32, 4 waves 2x2 (wave tile 32x64).
// MODE 0: out bf16 hi = acc + bias             (QKV)
// MODE 1: out f32  = acc + bias + res, fused BN stats atomics (O-proj / FF2)
// MODE 2: out bf16 hi = relu(acc + bias)       (FF1)
#define LDP 40   // padded LDS row stride (elements)
template<int MODE, int KSTEPS, int ASPLIT>
__global__ __launch_bounds__(256)
void gemm_tile(const bf16_t* __restrict__ Ah, const bf16_t* __restrict__ Al,
               const bf16_t* __restrict__ Bh, const bf16_t* __restrict__ Bl,
               const float* __restrict__ bias, const float* __restrict__ res,
               void* __restrict__ out_hi,
               float* __restrict__ stats, int Nout)
{
    constexpr int K = KSTEPS * 32;
    __shared__ alignas(16) __bf16 sAh[64 * LDP];
    __shared__ alignas(16) __bf16 sAl[ASPLIT ? 64 * LDP : 16];
    __shared__ alignas(16) __bf16 sBh[128 * LDP], sBl[128 * LDP];

    const int tid = threadIdx.x;
    const int m0 = blockIdx.x * 64;
    const int n0 = blockIdx.y * 128;

    const int ar = tid >> 2, ac = (tid & 3) * 8;
    const int br = tid >> 1, bc = (tid & 1) * 16;
    const bf16_t* gAh = Ah + (size_t)(m0 + ar) * K + ac;
    const bf16_t* gAl = ASPLIT ? Al + (size_t)(m0 + ar) * K + ac : nullptr;
    const bf16_t* gBh = Bh + (size_t)(n0 + br) * K + bc;
    const bf16_t* gBl = Bl + (size_t)(n0 + br) * K + bc;

    const int wave = tid >> 6, lane = tid & 63, quad = lane >> 4, l16 = lane & 15;
    const int wm = (wave >> 1) * 32;
    const int wn = (wave & 1) * 64;

    f32x4 acc[2][4] = {};
    bf8 ra_h, ra_l, rb_h0, rb_h1, rb_l0, rb_l1;

    ra_h  = *(const bf8*)(gAh);
    if (ASPLIT) ra_l = *(const bf8*)(gAl);
    rb_h0 = *(const bf8*)(gBh);
    rb_h1 = *(const bf8*)(gBh + 8);
    rb_l0 = *(const bf8*)(gBl);
    rb_l1 = *(const bf8*)(gBl + 8);

    for (int ks = 0; ks < KSTEPS; ++ks) {
        __syncthreads();
        *(bf8*)(sAh + ar * LDP + ac) = ra_h;
        if (ASPLIT) *(bf8*)(sAl + ar * LDP + ac) = ra_l;
        *(bf8*)(sBh + br * LDP + bc) = rb_h0;
        *(bf8*)(sBh + br * LDP + bc + 8) = rb_h1;
        *(bf8*)(sBl + br * LDP + bc) = rb_l0;
        *(bf8*)(sBl + br * LDP + bc + 8) = rb_l1;
        __syncthreads();
        if (ks + 1 < KSTEPS) {
            int k0 = (ks + 1) * 32;
            ra_h  = *(const bf8*)(gAh + k0);
            if (ASPLIT) ra_l = *(const bf8*)(gAl + k0);
            rb_h0 = *(const bf8*)(gBh + k0);
            rb_h1 = *(const bf8*)(gBh + k0 + 8);
            rb_l0 = *(const bf8*)(gBl + k0);
            rb_l1 = *(const bf8*)(gBl + k0 + 8);
        }
        bf8 afh[2], afl[2], bfh[4], bfl[4];
        #pragma unroll
        for (int mi = 0; mi < 2; ++mi) {
            afh[mi] = *(const bf8*)(sAh + (wm + mi * 16 + l16) * LDP + quad * 8);
            if (ASPLIT) afl[mi] = *(const bf8*)(sAl + (wm + mi * 16 + l16) * LDP + quad * 8);
        }
        #pragma unroll
        for (int ni = 0; ni < 4; ++ni) {
            bfh[ni] = *(const bf8*)(sBh + (wn + ni * 16 + l16) * LDP + quad * 8);
            bfl[ni] = *(const bf8*)(sBl + (wn + ni * 16 + l16) * LDP + quad * 8);
        }
        #pragma unroll
        for (int mi = 0; mi < 2; ++mi)
        #pragma unroll
        for (int ni = 0; ni < 4; ++ni) {
            acc[mi][ni] = __builtin_amdgcn_mfma_f32_16x16x32_bf16(afh[mi], bfh[ni], acc[mi][ni], 0, 0, 0);
            acc[mi][ni] = __builtin_amdgcn_mfma_f32_16x16x32_bf16(afh[mi], bfl[ni], acc[mi][ni], 0, 0, 0);
            if (ASPLIT)
                acc[mi][ni] = __builtin_amdgcn_mfma_f32_16x16x32_bf16(afl[mi], bfh[ni], acc[mi][ni], 0, 0, 0);
        }
    }

    // epilogue: C row = m0 + wm + mi*16 + quad*4 + r, col = n0 + wn + ni*16 + l16
    #pragma unroll
    for (int ni = 0; ni < 4; ++ni) {
        int col = n0 + wn + ni * 16 + l16;
        float bvv = bias[col];
        float s = 0.0f, ss = 0.0f;
        #pragma unroll
        for (int mi = 0; mi < 2; ++mi) {
            #pragma unroll
            for (int r = 0; r < 4; ++r) {
                int row = m0 + wm + mi * 16 + quad * 4 + r;
                float v = acc[mi][ni][r] + bvv;
                size_t off = (size_t)row * Nout + col;
                if (MODE == 0) {
                    ((bf16_t*)out_hi)[off] = f2b(v);
                } else if (MODE == 1) {
                    float o = v + res[off];
                    ((float*)out_hi)[off] = o;
                    s += o; ss += o * o;
                } else {
                    v = v > 0.0f ? v : 0.0f;
                    ((bf16_t*)out_hi)[off] = f2b(v);
                }
            }
        }
        if (MODE == 1) {
            s  += __shfl_xor(s, 16);  s  += __shfl_xor(s, 32);
            ss += __shfl_xor(ss, 16); ss += __shfl_xor(ss, 32);
            if (quad == 0) {
                atomicAdd(&stats[col], s);
                atomicAdd(&stats[128 + col], ss);
            }
        }
    }
}

// ---------------- MFMA attention (hi-only): one block per (b, head), 7 waves ----------------
// S^T = K·Q^T via mfma(A=K, B=Q): lane holds col=l16=query i, row=quad*4+r=key j.
// Softmax per-column: in-lane 28 + shfl_xor 16,32.
// O^T = V^T·P^T with P^T B-frag gathered from S^T C-frags via shuffles.
__global__ __launch_bounds__(448)
void attn_kernel(const bf16_t* __restrict__ qkvh,
                 bf16_t* __restrict__ ohi, bf16_t* __restrict__ olo)
{
    __shared__ alignas(16) __bf16 KhS[112 * 40];   // [key j][dk padded 16->32]
    __shared__ alignas(16) __bf16 VhS[16 * 136];   // V^T: [dk t][key j padded ->128]

    const int bh = blockIdx.x;
    const int b = bh >> 3, h = bh & 7;
    const int tid = threadIdx.x;
    const size_t base = (size_t)b * NCITY * 384 + h * 16;

    const __bf16 z = (__bf16)0.0f;
    for (int idx = tid; idx < 112 * 32; idx += 448) {
        int j = idx >> 5, t = idx & 31;
        __bf16 kh = z;
        if (j < NCITY && t < 16)
            kh = __builtin_bit_cast(__bf16, qkvh[base + (size_t)j * 384 + 128 + t]);
        KhS[j * 40 + t] = kh;
    }
    for (int idx = tid; idx < 16 * 128; idx += 448) {
        int t = idx >> 7, j = idx & 127;
        __bf16 vh = z;
        if (j < NCITY)
            vh = __builtin_bit_cast(__bf16, qkvh[base + (size_t)j * 384 + 256 + t]);
        VhS[t * 136 + j] = vh;
    }
    __syncthreads();

    const int it = tid >> 6;          // wave = q-tile, 0..6
    const int lane = tid & 63, quad = lane >> 4, l16 = lane & 15;
    const int s0 = l16 + (((2 * quad)     & 3) << 4);
    const int s1 = l16 + (((2 * quad + 1) & 3) << 4);

    int row = b * NCITY + it * 16 + l16;
    if (row > TROWS - 1) row = TROWS - 1;   // padded queries: contained per-column
    bf8 qh = {};
    if (quad < 2)
        qh = *reinterpret_cast<const bf8*>(qkvh + (size_t)row * 384 + h * 16 + quad * 8);

    f32x4 S[7];
    #pragma unroll
    for (int jt = 0; jt < 7; ++jt) {
        bf8 kh = *reinterpret_cast<const bf8*>(KhS + (jt * 16 + l16) * 40 + quad * 8);
        f32x4 a = {};
        a = __builtin_amdgcn_mfma_f32_16x16x32_bf16(kh, qh, a, 0, 0, 0);
        S[jt] = a;
    }
    float m = -1e30f;
    #pragma unroll
    for (int jt = 0; jt < 7; ++jt)
        #pragma unroll
        for (int r = 0; r < 4; ++r) { S[jt][r] *= 0.25f; m = fmaxf(m, S[jt][r]); }
    m = fmaxf(m, __shfl_xor(m, 16));
    m = fmaxf(m, __shfl_xor(m, 32));
    float sum = 0.0f;
    #pragma unroll
    for (int jt = 0; jt < 7; ++jt)
        #pragma unroll
        for (int r = 0; r < 4; ++r) {
            int jg = jt * 16 + quad * 4 + r;
            float e = (jg < NCITY) ? __expf(S[jt][r] - m) : 0.0f;
            S[jt][r] = e;
            sum += e;
        }
    sum += __shfl_xor(sum, 16);
    sum += __shfl_xor(sum, 32);
    float inv = 1.0f / sum;
    #pragma unroll
    for (int jt = 0; jt < 7; ++jt)
        #pragma unroll
        for (int r = 0; r < 4; ++r) S[jt][r] *= inv;

    f32x4 O = {};
    #pragma unroll
    for (int p = 0; p < 4; ++p) {
        float pj[8];
        #pragma unroll
        for (int r = 0; r < 4; ++r) {
            float t0 = S[2 * p][r];
            float t1 = (2 * p + 1 < 7) ? S[2 * p + 1][r] : 0.0f;
            float x0 = __shfl(t0, s0);
            float y0 = __shfl(t1, s0);
            float x1 = __shfl(t0, s1);
            float y1 = __shfl(t1, s1);
            pj[r]     = (quad < 2) ? x0 : y0;
            pj[4 + r] = (quad < 2) ? x1 : y1;
        }
        bf8 ph;
        #pragma unroll
        for (int jj = 0; jj < 8; ++jj)
            ph[jj] = __builtin_bit_cast(__bf16, f2b(pj[jj]));
        bf8 vh = *reinterpret_cast<const bf8*>(VhS + l16 * 136 + p * 32 + quad * 8);
        O = __builtin_amdgcn_mfma_f32_16x16x32_bf16(vh, ph, O, 0, 0, 0);
    }
    int i = it * 16 + l16;
    if (i < NCITY) {
        size_t oo = ((size_t)b * NCITY + i) * 128 + h * 16 + quad * 4;
        bf4 oh4, ol4;
        #pragma unroll
        for (int r = 0; r < 4; ++r) {
            float v = O[r];
            bf16_t hb = f2b(v);
            oh4[r] = __builtin_bit_cast(__bf16, hb);
            ol4[r] = __builtin_bit_cast(__bf16, f2b(v - b2f(hb)));
        }
        *reinterpret_cast<bf4*>(ohi + oo) = oh4;
        *reinterpret_cast<bf4*>(olo + oo) = ol4;
    }
}

// ---------------- BatchNorm finalize + apply ----------------
__global__ void bn_final(const float* __restrict__ stats, const float* __restrict__ g,
                         const float* __restrict__ be, float* __restrict__ sh)
{
    int c = threadIdx.x;  // 128 threads
    const float invN = 1.0f / (float)TROWS;
    float mean = stats[c] * invN;
    float var  = stats[128 + c] * invN - mean * mean;
    float inv  = rsqrtf(var + 1e-5f);
    float scl  = g[c] * inv;
    sh[c]       = scl;
    sh[128 + c] = be[c] - mean * scl;
}

__global__ __launch_bounds__(256)
void bn_apply(const float* __restrict__ y, const float* __restrict__ sh,
              float* __restrict__ x32, bf16_t* __restrict__ xhi, bf16_t* __restrict__ xlo)
{
    int gid = blockIdx.x * 256 + threadIdx.x;
    int c = gid & 127;
    float v = y[gid] * sh[c] + sh[128 + c];
    x32[gid] = v;
    bf16_t hi = f2b(v);
    xhi[gid] = hi;
    xlo[gid] = f2b(v - b2f(hi));
}

// ---------------- launch ----------------
extern "C" void kernel_launch(void* const* d_in, const int* in_sizes, int n_in,
                              void* d_out, int out_size, void* d_ws, size_t ws_size,
                              hipStream_t stream)
{
    const float* s    = (const float*)d_in[0];
    const int*   dd   = (const int*)d_in[1];
    const float* e_w  = (const float*)d_in[2];
    const float* e_b  = (const float*)d_in[3];
    const float* ep_w = (const float*)d_in[4];
    const float* ep_b = (const float*)d_in[5];
    const float* Wq   = (const float*)d_in[6];
    const float* bq   = (const float*)d_in[7];
    const float* Wk   = (const float*)d_in[8];
    const float* bk   = (const float*)d_in[9];
    const float* Wv   = (const float*)d_in[10];
    const float* bv   = (const float*)d_in[11];
    const float* Wo   = (const float*)d_in[12];
    const float* bo   = (const float*)d_in[13];
    const float* Wf1  = (const float*)d_in[14];
    const float* bf1  = (const float*)d_in[15];
    const float* Wf2  = (const float*)d_in[16];
    const float* bf2  = (const float*)d_in[17];
    const float* g1   = (const float*)d_in[18];
    const float* be1  = (const float*)d_in[19];
    const float* g2   = (const float*)d_in[20];
    const float* be2  = (const float*)d_in[21];

    char* ws = (char*)d_ws;
    size_t off = 0;
    auto alloc = [&](size_t bytes) -> void* {
        void* p = ws + off;
        off += (bytes + 255) & ~(size_t)255;
        return p;
    };
    float*  x32   = (float*) alloc((size_t)TROWS * 128 * 4);
    float*  y32   = (float*) alloc((size_t)TROWS * 128 * 4);
    bf16_t* xhi   = (bf16_t*)alloc((size_t)TROWS * 128 * 2);
    bf16_t* xlo   = (bf16_t*)alloc((size_t)TROWS * 128 * 2);
    bf16_t* qkvh  = (bf16_t*)alloc((size_t)TROWS * 384 * 2);   // contiguous with ohi
    bf16_t* ohi   = (bf16_t*)alloc((size_t)TROWS * 128 * 2);
    bf16_t* olo   = (bf16_t*)alloc((size_t)TROWS * 128 * 2);
    bf16_t* h1h   = qkvh;   // TROWS*512 hi region spanning qkvh..ohi (both dead at FF1)
    bf16_t* wqkvH = (bf16_t*)alloc((size_t)3 * 384 * 128 * 2);
    bf16_t* wqkvL = (bf16_t*)alloc((size_t)3 * 384 * 128 * 2);
    bf16_t* woH   = (bf16_t*)alloc((size_t)3 * 128 * 128 * 2);
    bf16_t* woL   = (bf16_t*)alloc((size_t)3 * 128 * 128 * 2);
    bf16_t* wf1H  = (bf16_t*)alloc((size_t)3 * 512 * 128 * 2);
    bf16_t* wf1L  = (bf16_t*)alloc((size_t)3 * 512 * 128 * 2);
    bf16_t* wf2H  = (bf16_t*)alloc((size_t)3 * 128 * 512 * 2);
    bf16_t* wf2L  = (bf16_t*)alloc((size_t)3 * 128 * 512 * 2);
    float*  bqkv  = (float*) alloc((size_t)3 * 384 * 4);
    float*  stats = (float*) alloc(256 * 4);
    float*  sh    = (float*) alloc(256 * 4);

    dim3 blk(256);

    // weight prep
    transpose_w<<<dim3(192), blk, 0, stream>>>(Wq,  wqkvH, wqkvL, 128, 128, 0,     49152);
    transpose_w<<<dim3(192), blk, 0, stream>>>(Wk,  wqkvH, wqkvL, 128, 128, 16384, 49152);
    transpose_w<<<dim3(192), blk, 0, stream>>>(Wv,  wqkvH, wqkvL, 128, 128, 32768, 49152);
    transpose_w<<<dim3(192), blk, 0, stream>>>(Wo,  woH,   woL,   128, 128, 0,     16384);
    transpose_w<<<dim3(768), blk, 0, stream>>>(Wf1, wf1H,  wf1L,  128, 512, 0,     65536);
    transpose_w<<<dim3(768), blk, 0, stream>>>(Wf2, wf2H,  wf2L,  512, 128, 0,     65536);
    pack_bias<<<dim3(5), blk, 0, stream>>>(bq, bk, bv, bqkv);

    embed_kernel<<<dim3(TROWS * 128 / 256), blk, 0, stream>>>(s, dd, e_w, e_b, ep_w, ep_b,
                                                              x32, xhi, xlo);

    for (int l = 0; l < 3; ++l) {
        // QKV (A split, hi-only out), K=128, N=384
        gemm_tile<0, 4, 1><<<dim3(808, 3), blk, 0, stream>>>(xhi, xlo,
                                                             wqkvH + (size_t)l * 49152, wqkvL + (size_t)l * 49152,
                                                             bqkv + l * 384, nullptr, qkvh, nullptr, 384);
        // attention (MFMA, hi-only)
        attn_kernel<<<dim3(4096), dim3(448), 0, stream>>>(qkvh, ohi, olo);
        // O-proj + bias + residual + fused BN1 stats
        hipMemsetAsync(stats, 0, 256 * 4, stream);
        gemm_tile<1, 4, 1><<<dim3(808, 1), blk, 0, stream>>>(ohi, olo,
                                                             woH + (size_t)l * 16384, woL + (size_t)l * 16384,
                                                             bo + l * 128, x32, y32, stats, 128);
        bn_final<<<dim3(1), dim3(128), 0, stream>>>(stats, g1 + l * 128, be1 + l * 128, sh);
        bn_apply<<<dim3(TROWS * 128 / 256), blk, 0, stream>>>(y32, sh, x32, xhi, xlo);
        // FF1 (A split, ReLU hi-only out), K=128, N=512
        gemm_tile<2, 4, 1><<<dim3(808, 4), blk, 0, stream>>>(xhi, xlo,
                                                             wf1H + (size_t)l * 65536, wf1L + (size_t)l * 65536,
                                                             bf1 + l * 512, nullptr, h1h, nullptr, 512);
        // FF2 (A single, 2-term) + bias + residual + fused BN2 stats, K=512, N=128
        hipMemsetAsync(stats, 0, 256 * 4, stream);
        gemm_tile<1, 16, 0><<<dim3(808, 1), blk, 0, stream>>>(h1h, nullptr,
                                                              wf2H + (size_t)l * 65536, wf2L + (size_t)l * 65536,
                                                              bf2 + l * 128, x32, y32, stats, 128);
        bn_final<<<dim3(1), dim3(128), 0, stream>>>(stats, g2 + l * 128, be2 + l * 128, sh);
        float* xdst = (l == 2) ? (float*)d_out : x32;
        bn_apply<<<dim3(TROWS * 128 / 256), blk, 0, stream>>>(y32, sh, xdst, xhi, xlo);
    }
}

// Round 6
// 810.956 us; speedup vs baseline: 2.3789x; 1.1357x over previous
//
#include <hip/hip_runtime.h>
#include <hip/hip_bf16.h>
#include <stdint.h>

#define TROWS 51712   // 512*101
#define NCITY 101
#define BATCH 512
#define EDIM  128
#define NQ    101

using bf16_t = __hip_bfloat16;
typedef __attribute__((ext_vector_type(8))) __bf16 bf8;
typedef __attribute__((ext_vector_type(4))) __bf16 bf4;
typedef __attribute__((ext_vector_type(4))) float  f32x4;

static __device__ __forceinline__ bf16_t f2b(float v) { return __float2bfloat16(v); }
static __device__ __forceinline__ float  b2f(bf16_t v) { return __bfloat162float(v); }

typedef __attribute__((address_space(1))) const unsigned int gu32;
typedef __attribute__((address_space(3))) unsigned int lu32;
static __device__ __forceinline__ void async16(const void* g, const void* l) {
    __builtin_amdgcn_global_load_lds((gu32*)g, (lu32*)(uint32_t)(uintptr_t)l, 16, 0, 0);
}

// ---------------- weight prep: transpose + split-bf16 ----------------
__global__ __launch_bounds__(256)
void transpose_w(const float* __restrict__ src, bf16_t* __restrict__ dhi,
                 bf16_t* __restrict__ dlo, int K, int N, int dstOff, int dstLS)
{
    int gid = blockIdx.x * 256 + threadIdx.x;
    int total = 3 * K * N;
    if (gid >= total) return;
    int l = gid / (K * N);
    int r = gid - l * (K * N);
    int k = r / N;
    int n = r - k * N;
    float w = src[gid];
    bf16_t hi = f2b(w);
    size_t o = (size_t)l * dstLS + dstOff + (size_t)n * K + k;
    dhi[o] = hi;
    dlo[o] = f2b(w - b2f(hi));
}

__global__ __launch_bounds__(256)
void pack_bias(const float* __restrict__ bq, const float* __restrict__ bk,
               const float* __restrict__ bv, float* __restrict__ dst)
{
    int gid = blockIdx.x * 256 + threadIdx.x;
    if (gid >= 3 * 384) return;
    int l = gid / 384, c = gid - l * 384;
    float v = (c < 128) ? bq[l * 128 + c]
            : (c < 256) ? bk[l * 128 + c - 128]
                        : bv[l * 128 + c - 256];
    dst[gid] = v;
}

// ---------------- embedding ----------------
__global__ __launch_bounds__(256)
void embed_kernel(const float* __restrict__ s, const int* __restrict__ d,
                  const float* __restrict__ e_w, const float* __restrict__ e_b,
                  const float* __restrict__ ep_w, const float* __restrict__ ep_b,
                  float* __restrict__ x32, bf16_t* __restrict__ xhi, bf16_t* __restrict__ xlo)
{
    int gid = blockIdx.x * 256 + threadIdx.x;      // over TROWS*128
    int row = gid >> 7;
    int c   = gid & 127;
    int b = row / NCITY;
    int n = row - b * NCITY;
    const float* sp = s + ((size_t)b * NCITY + n) * 2;
    float v;
    if (n == 0) {
        v = sp[0] * ep_w[c] + sp[1] * ep_w[128 + c] + ep_b[c];
    } else {
        float dv = (float)d[b * NCITY + n];
        v = sp[0] * e_w[c] + sp[1] * e_w[128 + c] + dv * e_w[256 + c] + e_b[c];
    }
    x32[gid] = v;
    bf16_t hi = f2b(v);
    xhi[gid] = hi;
    xlo[gid] = f2b(v - b2f(hi));
}

// ---------------- m97-style LDS-staged split-bf16 GEMM ----------------
// ASPLIT=1: C ≈ AhBh + AhBl + AlBh.  ASPLIT=0: C ≈ AhBh + AhBl.
// Block tile 128x128, BK=32, 4 waves 2x2 (wave tile 64x64, acc[4][4]).
// LDS tiles [128 rows][32 cols] bf16 unpadded (m97 layout), staged via
// global_load_lds width=16: lane linear offset = wave*512 + lane*8 elems.
// MODE 0: out bf16 hi = acc + bias             (QKV)
// MODE 1: out f32  = acc + bias + res, fused BN stats atomics (O-proj / FF2)
// MODE 2: out bf16 hi = relu(acc + bias)       (FF1)
template<int MODE, int KSTEPS, int ASPLIT>
__global__ __launch_bounds__(256)
void gemm_tile(const bf16_t* __restrict__ Ah, const bf16_t* __restrict__ Al,
               const bf16_t* __restrict__ Bh, const bf16_t* __restrict__ Bl,
               const float* __restrict__ bias, const float* __restrict__ res,
               void* __restrict__ out_hi, float* __restrict__ stats, int Nout)
{
    constexpr int K = KSTEPS * 32;
    __shared__ alignas(16) __bf16 sAh[128 * 32];
    __shared__ alignas(16) __bf16 sAl[ASPLIT ? 128 * 32 : 8];
    __shared__ alignas(16) __bf16 sBh[128 * 32];
    __shared__ alignas(16) __bf16 sBl[128 * 32];

    const int tid  = threadIdx.x;
    const int wave = tid >> 6, lane = tid & 63;
    const int n0 = blockIdx.x * 128;
    const int m0 = blockIdx.y * 128;

    // staging: seg s covers rows [s*64, s*64+64); wave stages 16 rows, lane -> (row, col8)
    const int sr = wave * 16 + (lane >> 2);
    const int sc = (lane & 3) * 8;
    const size_t gaoff = (size_t)(m0 + sr) * K + sc;
    const size_t gboff = (size_t)(n0 + sr) * K + sc;
    const int ldst = wave * 512;   // elems; + seg*2048

    const int quad = lane >> 4, l16 = lane & 15;
    const int wm = (wave >> 1) * 64, wn = (wave & 1) * 64;

    f32x4 acc[4][4] = {};

    for (int ks = 0; ks < KSTEPS; ++ks) {
        const int k0 = ks * 32;
        __syncthreads();
        async16(Ah + gaoff + k0,                  sAh + ldst);
        async16(Ah + gaoff + (size_t)64 * K + k0, sAh + 2048 + ldst);
        if (ASPLIT) {
            async16(Al + gaoff + k0,                  sAl + ldst);
            async16(Al + gaoff + (size_t)64 * K + k0, sAl + 2048 + ldst);
        }
        async16(Bh + gboff + k0,                  sBh + ldst);
        async16(Bh + gboff + (size_t)64 * K + k0, sBh + 2048 + ldst);
        async16(Bl + gboff + k0,                  sBl + ldst);
        async16(Bl + gboff + (size_t)64 * K + k0, sBl + 2048 + ldst);
        __syncthreads();

        bf8 afh[4], afl[4], bfh[4], bfl[4];
        #pragma unroll
        for (int mi = 0; mi < 4; ++mi) {
            afh[mi] = *(const bf8*)(sAh + (wm + mi * 16 + l16) * 32 + quad * 8);
            if (ASPLIT) afl[mi] = *(const bf8*)(sAl + (wm + mi * 16 + l16) * 32 + quad * 8);
        }
        #pragma unroll
        for (int ni = 0; ni < 4; ++ni) {
            bfh[ni] = *(const bf8*)(sBh + (wn + ni * 16 + l16) * 32 + quad * 8);
            bfl[ni] = *(const bf8*)(sBl + (wn + ni * 16 + l16) * 32 + quad * 8);
        }
        #pragma unroll
        for (int mi = 0; mi < 4; ++mi)
        #pragma unroll
        for (int ni = 0; ni < 4; ++ni) {
            acc[mi][ni] = __builtin_amdgcn_mfma_f32_16x16x32_bf16(afh[mi], bfh[ni], acc[mi][ni], 0, 0, 0);
            acc[mi][ni] = __builtin_amdgcn_mfma_f32_16x16x32_bf16(afh[mi], bfl[ni], acc[mi][ni], 0, 0, 0);
            if (ASPLIT)
                acc[mi][ni] = __builtin_amdgcn_mfma_f32_16x16x32_bf16(afl[mi], bfh[ni], acc[mi][ni], 0, 0, 0);
        }
    }

    // epilogue: row = m0 + wm + mi*16 + quad*4 + r, col = n0 + wn + ni*16 + l16
    #pragma unroll
    for (int ni = 0; ni < 4; ++ni) {
        int col = n0 + wn + ni * 16 + l16;
        float bvv = bias[col];
        float s = 0.0f, ss = 0.0f;
        #pragma unroll
        for (int mi = 0; mi < 4; ++mi) {
            #pragma unroll
            for (int r = 0; r < 4; ++r) {
                int row = m0 + wm + mi * 16 + quad * 4 + r;
                float v = acc[mi][ni][r] + bvv;
                size_t off = (size_t)row * Nout + col;
                if (MODE == 0) {
                    ((bf16_t*)out_hi)[off] = f2b(v);
                } else if (MODE == 1) {
                    float o = v + res[off];
                    ((float*)out_hi)[off] = o;
                    s += o; ss += o * o;
                } else {
                    v = v > 0.0f ? v : 0.0f;
                    ((bf16_t*)out_hi)[off] = f2b(v);
                }
            }
        }
        if (MODE == 1) {
            s  += __shfl_xor(s, 16);  s  += __shfl_xor(s, 32);
            ss += __shfl_xor(ss, 16); ss += __shfl_xor(ss, 32);
            if (quad == 0) {
                atomicAdd(&stats[col], s);
                atomicAdd(&stats[128 + col], ss);
            }
        }
    }
}

// ---------------- MFMA attention (hi-only): one block per (b, head), 7 waves ----------------
__global__ __launch_bounds__(448)
void attn_kernel(const bf16_t* __restrict__ qkvh,
                 bf16_t* __restrict__ ohi, bf16_t* __restrict__ olo)
{
    __shared__ alignas(16) __bf16 KhS[112 * 40];   // [key j][dk padded 16->32]
    __shared__ alignas(16) __bf16 VhS[16 * 136];   // V^T: [dk t][key j padded ->128]

    const int bh = blockIdx.x;
    const int b = bh >> 3, h = bh & 7;
    const int tid = threadIdx.x;
    const size_t base = (size_t)b * NCITY * 384 + h * 16;

    const __bf16 z = (__bf16)0.0f;
    for (int idx = tid; idx < 112 * 32; idx += 448) {
        int j = idx >> 5, t = idx & 31;
        __bf16 kh = z;
        if (j < NCITY && t < 16)
            kh = __builtin_bit_cast(__bf16, qkvh[base + (size_t)j * 384 + 128 + t]);
        KhS[j * 40 + t] = kh;
    }
    for (int idx = tid; idx < 16 * 128; idx += 448) {
        int t = idx >> 7, j = idx & 127;
        __bf16 vh = z;
        if (j < NCITY)
            vh = __builtin_bit_cast(__bf16, qkvh[base + (size_t)j * 384 + 256 + t]);
        VhS[t * 136 + j] = vh;
    }
    __syncthreads();

    const int it = tid >> 6;          // wave = q-tile, 0..6
    const int lane = tid & 63, quad = lane >> 4, l16 = lane & 15;
    const int s0 = l16 + (((2 * quad)     & 3) << 4);
    const int s1 = l16 + (((2 * quad + 1) & 3) << 4);

    int row = b * NCITY + it * 16 + l16;
    if (row > TROWS - 1) row = TROWS - 1;   // padded queries: contained per-column
    bf8 qh = {};
    if (quad < 2)
        qh = *reinterpret_cast<const bf8*>(qkvh + (size_t)row * 384 + h * 16 + quad * 8);

    f32x4 S[7];
    #pragma unroll
    for (int jt = 0; jt < 7; ++jt) {
        bf8 kh = *reinterpret_cast<const bf8*>(KhS + (jt * 16 + l16) * 40 + quad * 8);
        f32x4 a = {};
        a = __builtin_amdgcn_mfma_f32_16x16x32_bf16(kh, qh, a, 0, 0, 0);
        S[jt] = a;
    }
    float m = -1e30f;
    #pragma unroll
    for (int jt = 0; jt < 7; ++jt)
        #pragma unroll
        for (int r = 0; r < 4; ++r) { S[jt][r] *= 0.25f; m = fmaxf(m, S[jt][r]); }
    m = fmaxf(m, __shfl_xor(m, 16));
    m = fmaxf(m, __shfl_xor(m, 32));
    float sum = 0.0f;
    #pragma unroll
    for (int jt = 0; jt < 7; ++jt)
        #pragma unroll
        for (int r = 0; r < 4; ++r) {
            int jg = jt * 16 + quad * 4 + r;
            float e = (jg < NCITY) ? __expf(S[jt][r] - m) : 0.0f;
            S[jt][r] = e;
            sum += e;
        }
    sum += __shfl_xor(sum, 16);
    sum += __shfl_xor(sum, 32);
    float inv = 1.0f / sum;
    #pragma unroll
    for (int jt = 0; jt < 7; ++jt)
        #pragma unroll
        for (int r = 0; r < 4; ++r) S[jt][r] *= inv;

    f32x4 O = {};
    #pragma unroll
    for (int p = 0; p < 4; ++p) {
        float pj[8];
        #pragma unroll
        for (int r = 0; r < 4; ++r) {
            float t0 = S[2 * p][r];
            float t1 = (2 * p + 1 < 7) ? S[2 * p + 1][r] : 0.0f;
            float x0 = __shfl(t0, s0);
            float y0 = __shfl(t1, s0);
            float x1 = __shfl(t0, s1);
            float y1 = __shfl(t1, s1);
            pj[r]     = (quad < 2) ? x0 : y0;
            pj[4 + r] = (quad < 2) ? x1 : y1;
        }
        bf8 ph;
        #pragma unroll
        for (int jj = 0; jj < 8; ++jj)
            ph[jj] = __builtin_bit_cast(__bf16, f2b(pj[jj]));
        bf8 vh = *reinterpret_cast<const bf8*>(VhS + l16 * 136 + p * 32 + quad * 8);
        O = __builtin_amdgcn_mfma_f32_16x16x32_bf16(vh, ph, O, 0, 0, 0);
    }
    int i = it * 16 + l16;
    if (i < NCITY) {
        size_t oo = ((size_t)b * NCITY + i) * 128 + h * 16 + quad * 4;
        bf4 oh4, ol4;
        #pragma unroll
        for (int r = 0; r < 4; ++r) {
            float v = O[r];
            bf16_t hb = f2b(v);
            oh4[r] = __builtin_bit_cast(__bf16, hb);
            ol4[r] = __builtin_bit_cast(__bf16, f2b(v - b2f(hb)));
        }
        *reinterpret_cast<bf4*>(ohi + oo) = oh4;
        *reinterpret_cast<bf4*>(olo + oo) = ol4;
    }
}

// ---------------- BatchNorm finalize + apply ----------------
__global__ void bn_final(const float* __restrict__ stats, const float* __restrict__ g,
                         const float* __restrict__ be, float* __restrict__ sh)
{
    int c = threadIdx.x;  // 128 threads
    const float invN = 1.0f / (float)TROWS;
    float mean = stats[c] * invN;
    float var  = stats[128 + c] * invN - mean * mean;
    float inv  = rsqrtf(var + 1e-5f);
    float scl  = g[c] * inv;
    sh[c]       = scl;
    sh[128 + c] = be[c] - mean * scl;
}

__global__ __launch_bounds__(256)
void bn_apply(const f32x4* __restrict__ y, const float* __restrict__ sh,
              f32x4* __restrict__ x32, bf16_t* __restrict__ xhi, bf16_t* __restrict__ xlo)
{
    int gid = blockIdx.x * 256 + threadIdx.x;   // over TROWS*32 (4 ch each)
    int c = (gid & 31) * 4;
    f32x4 v = y[gid];
    bf4 h4, l4;
    #pragma unroll
    for (int r = 0; r < 4; ++r) {
        float o = v[r] * sh[c + r] + sh[128 + c + r];
        v[r] = o;
        bf16_t hb = f2b(o);
        h4[r] = __builtin_bit_cast(__bf16, hb);
        l4[r] = __builtin_bit_cast(__bf16, f2b(o - b2f(hb)));
    }
    x32[gid] = v;
    *reinterpret_cast<bf4*>(xhi + (size_t)gid * 4) = h4;
    *reinterpret_cast<bf4*>(xlo + (size_t)gid * 4) = l4;
}

// ---------------- launch ----------------
extern "C" void kernel_launch(void* const* d_in, const int* in_sizes, int n_in,
                              void* d_out, int out_size, void* d_ws, size_t ws_size,
                              hipStream_t stream)
{
    const float* s    = (const float*)d_in[0];
    const int*   dd   = (const int*)d_in[1];
    const float* e_w  = (const float*)d_in[2];
    const float* e_b  = (const float*)d_in[3];
    const float* ep_w = (const float*)d_in[4];
    const float* ep_b = (const float*)d_in[5];
    const float* Wq   = (const float*)d_in[6];
    const float* bq   = (const float*)d_in[7];
    const float* Wk   = (const float*)d_in[8];
    const float* bk   = (const float*)d_in[9];
    const float* Wv   = (const float*)d_in[10];
    const float* bv   = (const float*)d_in[11];
    const float* Wo   = (const float*)d_in[12];
    const float* bo   = (const float*)d_in[13];
    const float* Wf1  = (const float*)d_in[14];
    const float* bf1  = (const float*)d_in[15];
    const float* Wf2  = (const float*)d_in[16];
    const float* bf2  = (const float*)d_in[17];
    const float* g1   = (const float*)d_in[18];
    const float* be1  = (const float*)d_in[19];
    const float* g2   = (const float*)d_in[20];
    const float* be2  = (const float*)d_in[21];

    char* ws = (char*)d_ws;
    size_t off = 0;
    auto alloc = [&](size_t bytes) -> void* {
        void* p = ws + off;
        off += (bytes + 255) & ~(size_t)255;
        return p;
    };
    float*  x32   = (float*) alloc((size_t)TROWS * 128 * 4);
    float*  y32   = (float*) alloc((size_t)TROWS * 128 * 4);
    bf16_t* xhi   = (bf16_t*)alloc((size_t)TROWS * 128 * 2);
    bf16_t* xlo   = (bf16_t*)alloc((size_t)TROWS * 128 * 2);
    bf16_t* qkvh  = (bf16_t*)alloc((size_t)TROWS * 384 * 2);   // contiguous with ohi
    bf16_t* ohi   = (bf16_t*)alloc((size_t)TROWS * 128 * 2);
    bf16_t* olo   = (bf16_t*)alloc((size_t)TROWS * 128 * 2);
    bf16_t* h1h   = qkvh;   // TROWS*512 hi region spanning qkvh..ohi (both dead at FF1)
    bf16_t* wqkvH = (bf16_t*)alloc((size_t)3 * 384 * 128 * 2);
    bf16_t* wqkvL = (bf16_t*)alloc((size_t)3 * 384 * 128 * 2);
    bf16_t* woH   = (bf16_t*)alloc((size_t)3 * 128 * 128 * 2);
    bf16_t* woL   = (bf16_t*)alloc((size_t)3 * 128 * 128 * 2);
    bf16_t* wf1H  = (bf16_t*)alloc((size_t)3 * 512 * 128 * 2);
    bf16_t* wf1L  = (bf16_t*)alloc((size_t)3 * 512 * 128 * 2);
    bf16_t* wf2H  = (bf16_t*)alloc((size_t)3 * 128 * 512 * 2);
    bf16_t* wf2L  = (bf16_t*)alloc((size_t)3 * 128 * 512 * 2);
    float*  bqkv  = (float*) alloc((size_t)3 * 384 * 4);
    float*  stats = (float*) alloc(256 * 4);
    float*  sh    = (float*) alloc(256 * 4);

    dim3 blk(256);

    // weight prep
    transpose_w<<<dim3(192), blk, 0, stream>>>(Wq,  wqkvH, wqkvL, 128, 128, 0,     49152);
    transpose_w<<<dim3(192), blk, 0, stream>>>(Wk,  wqkvH, wqkvL, 128, 128, 16384, 49152);
    transpose_w<<<dim3(192), blk, 0, stream>>>(Wv,  wqkvH, wqkvL, 128, 128, 32768, 49152);
    transpose_w<<<dim3(192), blk, 0, stream>>>(Wo,  woH,   woL,   128, 128, 0,     16384);
    transpose_w<<<dim3(768), blk, 0, stream>>>(Wf1, wf1H,  wf1L,  128, 512, 0,     65536);
    transpose_w<<<dim3(768), blk, 0, stream>>>(Wf2, wf2H,  wf2L,  512, 128, 0,     65536);
    pack_bias<<<dim3(5), blk, 0, stream>>>(bq, bk, bv, bqkv);

    embed_kernel<<<dim3(TROWS * 128 / 256), blk, 0, stream>>>(s, dd, e_w, e_b, ep_w, ep_b,
                                                              x32, xhi, xlo);

    for (int l = 0; l < 3; ++l) {
        // QKV (A split, hi-only out), K=128, N=384; grid (ncol, mrow) for A L2-reuse
        gemm_tile<0, 4, 1><<<dim3(3, 404), blk, 0, stream>>>(xhi, xlo,
                                                             wqkvH + (size_t)l * 49152, wqkvL + (size_t)l * 49152,
                                                             bqkv + l * 384, nullptr, qkvh, nullptr, 384);
        // attention (MFMA, hi-only)
        attn_kernel<<<dim3(4096), dim3(448), 0, stream>>>(qkvh, ohi, olo);
        // O-proj + bias + residual + fused BN1 stats
        hipMemsetAsync(stats, 0, 256 * 4, stream);
        gemm_tile<1, 4, 1><<<dim3(1, 404), blk, 0, stream>>>(ohi, olo,
                                                             woH + (size_t)l * 16384, woL + (size_t)l * 16384,
                                                             bo + l * 128, x32, y32, stats, 128);
        bn_final<<<dim3(1), dim3(128), 0, stream>>>(stats, g1 + l * 128, be1 + l * 128, sh);
        bn_apply<<<dim3(TROWS * 32 / 256), blk, 0, stream>>>((const f32x4*)y32, sh,
                                                             (f32x4*)x32, xhi, xlo);
        // FF1 (A split, ReLU hi-only out), K=128, N=512
        gemm_tile<2, 4, 1><<<dim3(4, 404), blk, 0, stream>>>(xhi, xlo,
                                                             wf1H + (size_t)l * 65536, wf1L + (size_t)l * 65536,
                                                             bf1 + l * 512, nullptr, h1h, nullptr, 512);
        // FF2 (A single, 2-term) + bias + residual + fused BN2 stats, K=512, N=128
        hipMemsetAsync(stats, 0, 256 * 4, stream);
        gemm_tile<1, 16, 0><<<dim3(1, 404), blk, 0, stream>>>(h1h, nullptr,
                                                              wf2H + (size_t)l * 65536, wf2L + (size_t)l * 65536,
                                                              bf2 + l * 128, x32, y32, stats, 128);
        bn_final<<<dim3(1), dim3(128), 0, stream>>>(stats, g2 + l * 128, be2 + l * 128, sh);
        float* xdst = (l == 2) ? (float*)d_out : x32;
        bn_apply<<<dim3(TROWS * 32 / 256), blk, 0, stream>>>((const f32x4*)y32, sh,
                                                             (f32x4*)xdst, xhi, xlo);
    }
}

// Round 7
// 810.613 us; speedup vs baseline: 2.3799x; 1.0004x over previous
//
#include <hip/hip_runtime.h>
#include <hip/hip_bf16.h>
#include <stdint.h>

#define TROWS 51712   // 512*101
#define NCITY 101
#define BATCH 512
#define EDIM  128
#define NQ    101
#define NBH   4096    // BATCH*8 heads

using bf16_t = __hip_bfloat16;
typedef __attribute__((ext_vector_type(8))) __bf16 bf8;
typedef __attribute__((ext_vector_type(4))) __bf16 bf4;
typedef __attribute__((ext_vector_type(4))) float  f32x4;

static __device__ __forceinline__ bf16_t f2b(float v) { return __float2bfloat16(v); }
static __device__ __forceinline__ float  b2f(bf16_t v) { return __bfloat162float(v); }

typedef __attribute__((address_space(1))) const unsigned int gu32;
typedef __attribute__((address_space(3))) unsigned int lu32;
static __device__ __forceinline__ void async16(const void* g, const void* l) {
    __builtin_amdgcn_global_load_lds((gu32*)g, (lu32*)(uint32_t)(uintptr_t)l, 16, 0, 0);
}

// ---------------- weight prep: transpose + split-bf16 ----------------
__global__ __launch_bounds__(256)
void transpose_w(const float* __restrict__ src, bf16_t* __restrict__ dhi,
                 bf16_t* __restrict__ dlo, int K, int N, int dstOff, int dstLS)
{
    int gid = blockIdx.x * 256 + threadIdx.x;
    int total = 3 * K * N;
    if (gid >= total) return;
    int l = gid / (K * N);
    int r = gid - l * (K * N);
    int k = r / N;
    int n = r - k * N;
    float w = src[gid];
    bf16_t hi = f2b(w);
    size_t o = (size_t)l * dstLS + dstOff + (size_t)n * K + k;
    dhi[o] = hi;
    dlo[o] = f2b(w - b2f(hi));
}

__global__ __launch_bounds__(256)
void pack_bias(const float* __restrict__ bq, const float* __restrict__ bk,
               const float* __restrict__ bv, float* __restrict__ dst)
{
    int gid = blockIdx.x * 256 + threadIdx.x;
    if (gid >= 3 * 384) return;
    int l = gid / 384, c = gid - l * 384;
    float v = (c < 128) ? bq[l * 128 + c]
            : (c < 256) ? bk[l * 128 + c - 128]
                        : bv[l * 128 + c - 256];
    dst[gid] = v;
}

// ---------------- embedding ----------------
__global__ __launch_bounds__(256)
void embed_kernel(const float* __restrict__ s, const int* __restrict__ d,
                  const float* __restrict__ e_w, const float* __restrict__ e_b,
                  const float* __restrict__ ep_w, const float* __restrict__ ep_b,
                  float* __restrict__ x32, bf16_t* __restrict__ xhi, bf16_t* __restrict__ xlo)
{
    int gid = blockIdx.x * 256 + threadIdx.x;      // over TROWS*128
    int row = gid >> 7;
    int c   = gid & 127;
    int b = row / NCITY;
    int n = row - b * NCITY;
    const float* sp = s + ((size_t)b * NCITY + n) * 2;
    float v;
    if (n == 0) {
        v = sp[0] * ep_w[c] + sp[1] * ep_w[128 + c] + ep_b[c];
    } else {
        float dv = (float)d[b * NCITY + n];
        v = sp[0] * e_w[c] + sp[1] * e_w[128 + c] + dv * e_w[256 + c] + e_b[c];
    }
    x32[gid] = v;
    bf16_t hi = f2b(v);
    xhi[gid] = hi;
    xlo[gid] = f2b(v - b2f(hi));
}

// ---------------- m97-style LDS-staged split-bf16 GEMM ----------------
// ASPLIT=1: C ≈ AhBh + AhBl + AlBh.  ASPLIT=0: C ≈ AhBh + AhBl.
// Block tile 128x128, BK=32, 4 waves 2x2 (wave tile 64x64, acc[4][4]).
// MODE 0: QKV — scatter to Qh[bh][101][16], Kh[bh][101][16], Vt[bh][16][128]
// MODE 1: out f32 = acc + bias + res, fused BN stats atomics (O-proj / FF2)
// MODE 2: out bf16 hi = relu(acc + bias)       (FF1)
template<int MODE, int KSTEPS, int ASPLIT>
__global__ __launch_bounds__(256)
void gemm_tile(const bf16_t* __restrict__ Ah, const bf16_t* __restrict__ Al,
               const bf16_t* __restrict__ Bh, const bf16_t* __restrict__ Bl,
               const float* __restrict__ bias, const float* __restrict__ res,
               void* __restrict__ out_hi, void* __restrict__ outK, void* __restrict__ outV,
               float* __restrict__ stats, int Nout)
{
    constexpr int K = KSTEPS * 32;
    __shared__ alignas(16) __bf16 sAh[128 * 32];
    __shared__ alignas(16) __bf16 sAl[ASPLIT ? 128 * 32 : 8];
    __shared__ alignas(16) __bf16 sBh[128 * 32];
    __shared__ alignas(16) __bf16 sBl[128 * 32];

    const int tid  = threadIdx.x;
    const int wave = tid >> 6, lane = tid & 63;
    const int n0 = blockIdx.x * 128;
    const int m0 = blockIdx.y * 128;

    const int sr = wave * 16 + (lane >> 2);
    const int sc = (lane & 3) * 8;
    const size_t gaoff = (size_t)(m0 + sr) * K + sc;
    const size_t gboff = (size_t)(n0 + sr) * K + sc;
    const int ldst = wave * 512;

    const int quad = lane >> 4, l16 = lane & 15;
    const int wm = (wave >> 1) * 64, wn = (wave & 1) * 64;

    f32x4 acc[4][4] = {};

    for (int ks = 0; ks < KSTEPS; ++ks) {
        const int k0 = ks * 32;
        __syncthreads();
        async16(Ah + gaoff + k0,                  sAh + ldst);
        async16(Ah + gaoff + (size_t)64 * K + k0, sAh + 2048 + ldst);
        if (ASPLIT) {
            async16(Al + gaoff + k0,                  sAl + ldst);
            async16(Al + gaoff + (size_t)64 * K + k0, sAl + 2048 + ldst);
        }
        async16(Bh + gboff + k0,                  sBh + ldst);
        async16(Bh + gboff + (size_t)64 * K + k0, sBh + 2048 + ldst);
        async16(Bl + gboff + k0,                  sBl + ldst);
        async16(Bl + gboff + (size_t)64 * K + k0, sBl + 2048 + ldst);
        __syncthreads();

        bf8 afh[4], afl[4], bfh[4], bfl[4];
        #pragma unroll
        for (int mi = 0; mi < 4; ++mi) {
            afh[mi] = *(const bf8*)(sAh + (wm + mi * 16 + l16) * 32 + quad * 8);
            if (ASPLIT) afl[mi] = *(const bf8*)(sAl + (wm + mi * 16 + l16) * 32 + quad * 8);
        }
        #pragma unroll
        for (int ni = 0; ni < 4; ++ni) {
            bfh[ni] = *(const bf8*)(sBh + (wn + ni * 16 + l16) * 32 + quad * 8);
            bfl[ni] = *(const bf8*)(sBl + (wn + ni * 16 + l16) * 32 + quad * 8);
        }
        #pragma unroll
        for (int mi = 0; mi < 4; ++mi)
        #pragma unroll
        for (int ni = 0; ni < 4; ++ni) {
            acc[mi][ni] = __builtin_amdgcn_mfma_f32_16x16x32_bf16(afh[mi], bfh[ni], acc[mi][ni], 0, 0, 0);
            acc[mi][ni] = __builtin_amdgcn_mfma_f32_16x16x32_bf16(afh[mi], bfl[ni], acc[mi][ni], 0, 0, 0);
            if (ASPLIT)
                acc[mi][ni] = __builtin_amdgcn_mfma_f32_16x16x32_bf16(afl[mi], bfh[ni], acc[mi][ni], 0, 0, 0);
        }
    }

    // epilogue: row = m0 + wm + mi*16 + quad*4 + r, col = n0 + wn + ni*16 + l16
    #pragma unroll
    for (int ni = 0; ni < 4; ++ni) {
        int col = n0 + wn + ni * 16 + l16;
        float bvv = bias[col];
        float s = 0.0f, ss = 0.0f;
        #pragma unroll
        for (int mi = 0; mi < 4; ++mi) {
            #pragma unroll
            for (int r = 0; r < 4; ++r) {
                int row = m0 + wm + mi * 16 + quad * 4 + r;
                float v = acc[mi][ni][r] + bvv;
                if (MODE == 0) {
                    int b   = row / NCITY;
                    int tok = row - b * NCITY;
                    int which = col >> 7;          // wave-uniform per ni
                    int h     = (col >> 4) & 7;    // wave-uniform per ni
                    int bh    = b * 8 + h;
                    bf16_t hv = f2b(v);
                    if (which == 0)
                        ((bf16_t*)out_hi)[((size_t)bh * NCITY + tok) * 16 + l16] = hv;
                    else if (which == 1)
                        ((bf16_t*)outK)[((size_t)bh * NCITY + tok) * 16 + l16] = hv;
                    else
                        ((bf16_t*)outV)[((size_t)bh * 16 + l16) * 128 + tok] = hv;
                } else if (MODE == 1) {
                    size_t off = (size_t)row * Nout + col;
                    float o = v + res[off];
                    ((float*)out_hi)[off] = o;
                    s += o; ss += o * o;
                } else {
                    size_t off = (size_t)row * Nout + col;
                    v = v > 0.0f ? v : 0.0f;
                    ((bf16_t*)out_hi)[off] = f2b(v);
                }
            }
        }
        if (MODE == 1) {
            s  += __shfl_xor(s, 16);  s  += __shfl_xor(s, 32);
            ss += __shfl_xor(ss, 16); ss += __shfl_xor(ss, 32);
            if (quad == 0) {
                atomicAdd(&stats[col], s);
                atomicAdd(&stats[128 + col], ss);
            }
        }
    }
}

// ---------------- LDS-free MFMA attention: one wave per (bh, q-tile) ----------------
// Qh/Kh: [bh][101][16] bf16; Vt: [bh][16][128] (keys padded 101->128, pad*P=0).
// S^T = K·Q^T (A=K direct global, B=Q direct global); softmax per-column;
// O^T = V^T·P^T (A=Vt direct global, P^T gathered from S via shuffles).
__global__ __launch_bounds__(256)
void attn_kernel(const bf16_t* __restrict__ Qh, const bf16_t* __restrict__ Kh,
                 const bf16_t* __restrict__ Vt,
                 bf16_t* __restrict__ ohi, bf16_t* __restrict__ olo)
{
    const int wid = blockIdx.x * 4 + (threadIdx.x >> 6);   // 0..28671
    const int bh = wid / 7;
    const int it = wid - bh * 7;
    if (bh >= NBH) return;
    const int b = bh >> 3, h = bh & 7;

    const int lane = threadIdx.x & 63, quad = lane >> 4, l16 = lane & 15;
    const int s0 = l16 + (((2 * quad)     & 3) << 4);
    const int s1 = l16 + (((2 * quad + 1) & 3) << 4);

    const bf16_t* qbase = Qh + (size_t)bh * NCITY * 16;
    const bf16_t* kbase = Kh + (size_t)bh * NCITY * 16;
    const bf16_t* vbase = Vt + (size_t)bh * 16 * 128;

    // Q B-frag: col=l16=query, k=quad*8+jj=dk (quad>=2 zero)
    bf8 qh = {};
    if (quad < 2)
        qh = *reinterpret_cast<const bf8*>(qbase + (it * 16 + l16) * 16 + quad * 8);

    f32x4 S[7];
    #pragma unroll
    for (int jt = 0; jt < 7; ++jt) {
        bf8 kf = {};
        if (quad < 2)
            kf = *reinterpret_cast<const bf8*>(kbase + (jt * 16 + l16) * 16 + quad * 8);
        f32x4 a = {};
        a = __builtin_amdgcn_mfma_f32_16x16x32_bf16(kf, qh, a, 0, 0, 0);
        S[jt] = a;
    }
    // mask invalid keys BEFORE max (K rows j>=101 hold garbage)
    float m = -1e30f;
    #pragma unroll
    for (int jt = 0; jt < 7; ++jt)
        #pragma unroll
        for (int r = 0; r < 4; ++r) {
            int jg = jt * 16 + quad * 4 + r;
            float sv = (jg < NCITY) ? S[jt][r] * 0.25f : -1e30f;
            S[jt][r] = sv;
            m = fmaxf(m, sv);
        }
    m = fmaxf(m, __shfl_xor(m, 16));
    m = fmaxf(m, __shfl_xor(m, 32));
    float sum = 0.0f;
    #pragma unroll
    for (int jt = 0; jt < 7; ++jt)
        #pragma unroll
        for (int r = 0; r < 4; ++r) {
            float e = __expf(S[jt][r] - m);
            S[jt][r] = e;
            sum += e;
        }
    sum += __shfl_xor(sum, 16);
    sum += __shfl_xor(sum, 32);
    float inv = 1.0f / sum;
    #pragma unroll
    for (int jt = 0; jt < 7; ++jt)
        #pragma unroll
        for (int r = 0; r < 4; ++r) S[jt][r] *= inv;

    // O^T = V^T·P^T over 4 key-blocks of 32
    f32x4 O = {};
    #pragma unroll
    for (int p = 0; p < 4; ++p) {
        float pj[8];
        #pragma unroll
        for (int r = 0; r < 4; ++r) {
            float t0 = S[2 * p][r];
            float t1 = (2 * p + 1 < 7) ? S[2 * p + 1][r] : 0.0f;
            float x0 = __shfl(t0, s0);
            float y0 = __shfl(t1, s0);
            float x1 = __shfl(t0, s1);
            float y1 = __shfl(t1, s1);
            pj[r]     = (quad < 2) ? x0 : y0;
            pj[4 + r] = (quad < 2) ? x1 : y1;
        }
        bf8 ph;
        #pragma unroll
        for (int jj = 0; jj < 8; ++jj)
            ph[jj] = __builtin_bit_cast(__bf16, f2b(pj[jj]));
        bf8 vf = *reinterpret_cast<const bf8*>(vbase + l16 * 128 + p * 32 + quad * 8);
        O = __builtin_amdgcn_mfma_f32_16x16x32_bf16(vf, ph, O, 0, 0, 0);
    }
    // O^T C-frag: lane holds O[dk=quad*4+r][query=l16]
    int i = it * 16 + l16;
    if (i < NCITY) {
        size_t oo = ((size_t)b * NCITY + i) * 128 + h * 16 + quad * 4;
        bf4 oh4, ol4;
        #pragma unroll
        for (int r = 0; r < 4; ++r) {
            float v = O[r];
            bf16_t hb = f2b(v);
            oh4[r] = __builtin_bit_cast(__bf16, hb);
            ol4[r] = __builtin_bit_cast(__bf16, f2b(v - b2f(hb)));
        }
        *reinterpret_cast<bf4*>(ohi + oo) = oh4;
        *reinterpret_cast<bf4*>(olo + oo) = ol4;
    }
}

// ---------------- BatchNorm finalize + apply ----------------
__global__ void bn_final(const float* __restrict__ stats, const float* __restrict__ g,
                         const float* __restrict__ be, float* __restrict__ sh)
{
    int c = threadIdx.x;  // 128 threads
    const float invN = 1.0f / (float)TROWS;
    float mean = stats[c] * invN;
    float var  = stats[128 + c] * invN - mean * mean;
    float inv  = rsqrtf(var + 1e-5f);
    float scl  = g[c] * inv;
    sh[c]       = scl;
    sh[128 + c] = be[c] - mean * scl;
}

__global__ __launch_bounds__(256)
void bn_apply(const f32x4* __restrict__ y, const float* __restrict__ sh,
              f32x4* __restrict__ x32, bf16_t* __restrict__ xhi, bf16_t* __restrict__ xlo)
{
    int gid = blockIdx.x * 256 + threadIdx.x;   // over TROWS*32 (4 ch each)
    int c = (gid & 31) * 4;
    f32x4 v = y[gid];
    bf4 h4, l4;
    #pragma unroll
    for (int r = 0; r < 4; ++r) {
        float o = v[r] * sh[c + r] + sh[128 + c + r];
        v[r] = o;
        bf16_t hb = f2b(o);
        h4[r] = __builtin_bit_cast(__bf16, hb);
        l4[r] = __builtin_bit_cast(__bf16, f2b(o - b2f(hb)));
    }
    x32[gid] = v;
    *reinterpret_cast<bf4*>(xhi + (size_t)gid * 4) = h4;
    *reinterpret_cast<bf4*>(xlo + (size_t)gid * 4) = l4;
}

// ---------------- launch ----------------
extern "C" void kernel_launch(void* const* d_in, const int* in_sizes, int n_in,
                              void* d_out, int out_size, void* d_ws, size_t ws_size,
                              hipStream_t stream)
{
    const float* s    = (const float*)d_in[0];
    const int*   dd   = (const int*)d_in[1];
    const float* e_w  = (const float*)d_in[2];
    const float* e_b  = (const float*)d_in[3];
    const float* ep_w = (const float*)d_in[4];
    const float* ep_b = (const float*)d_in[5];
    const float* Wq   = (const float*)d_in[6];
    const float* bq   = (const float*)d_in[7];
    const float* Wk   = (const float*)d_in[8];
    const float* bk   = (const float*)d_in[9];
    const float* Wv   = (const float*)d_in[10];
    const float* bv   = (const float*)d_in[11];
    const float* Wo   = (const float*)d_in[12];
    const float* bo   = (const float*)d_in[13];
    const float* Wf1  = (const float*)d_in[14];
    const float* bf1  = (const float*)d_in[15];
    const float* Wf2  = (const float*)d_in[16];
    const float* bf2  = (const float*)d_in[17];
    const float* g1   = (const float*)d_in[18];
    const float* be1  = (const float*)d_in[19];
    const float* g2   = (const float*)d_in[20];
    const float* be2  = (const float*)d_in[21];

    char* ws = (char*)d_ws;
    size_t off = 0;
    auto alloc = [&](size_t bytes) -> void* {
        void* p = ws + off;
        off += (bytes + 255) & ~(size_t)255;
        return p;
    };
    float*  x32   = (float*) alloc((size_t)TROWS * 128 * 4);
    float*  y32   = (float*) alloc((size_t)TROWS * 128 * 4);
    bf16_t* xhi   = (bf16_t*)alloc((size_t)TROWS * 128 * 2);
    bf16_t* xlo   = (bf16_t*)alloc((size_t)TROWS * 128 * 2);
    // attention tensors (contiguous; h1 aliases Qh..ohi)
    bf16_t* Qh    = (bf16_t*)alloc((size_t)NBH * NCITY * 16 * 2);   // 13.24 MB
    bf16_t* Kh    = (bf16_t*)alloc((size_t)NBH * NCITY * 16 * 2);   // 13.24 MB
    bf16_t* Vt    = (bf16_t*)alloc((size_t)NBH * 16 * 128 * 2);     // 16.78 MB
    bf16_t* ohi   = (bf16_t*)alloc((size_t)TROWS * 128 * 2);        // 13.24 MB
    bf16_t* olo   = (bf16_t*)alloc((size_t)TROWS * 128 * 2);
    bf16_t* h1h   = Qh;   // TROWS*512 bf16 = 52.95 MB <= Qh..ohi span (56.5 MB)
    bf16_t* wqkvH = (bf16_t*)alloc((size_t)3 * 384 * 128 * 2);
    bf16_t* wqkvL = (bf16_t*)alloc((size_t)3 * 384 * 128 * 2);
    bf16_t* woH   = (bf16_t*)alloc((size_t)3 * 128 * 128 * 2);
    bf16_t* woL   = (bf16_t*)alloc((size_t)3 * 128 * 128 * 2);
    bf16_t* wf1H  = (bf16_t*)alloc((size_t)3 * 512 * 128 * 2);
    bf16_t* wf1L  = (bf16_t*)alloc((size_t)3 * 512 * 128 * 2);
    bf16_t* wf2H  = (bf16_t*)alloc((size_t)3 * 128 * 512 * 2);
    bf16_t* wf2L  = (bf16_t*)alloc((size_t)3 * 128 * 512 * 2);
    float*  bqkv  = (float*) alloc((size_t)3 * 384 * 4);
    float*  stats = (float*) alloc(256 * 4);
    float*  sh    = (float*) alloc(256 * 4);

    dim3 blk(256);

    // weight prep
    transpose_w<<<dim3(192), blk, 0, stream>>>(Wq,  wqkvH, wqkvL, 128, 128, 0,     49152);
    transpose_w<<<dim3(192), blk, 0, stream>>>(Wk,  wqkvH, wqkvL, 128, 128, 16384, 49152);
    transpose_w<<<dim3(192), blk, 0, stream>>>(Wv,  wqkvH, wqkvL, 128, 128, 32768, 49152);
    transpose_w<<<dim3(192), blk, 0, stream>>>(Wo,  woH,   woL,   128, 128, 0,     16384);
    transpose_w<<<dim3(768), blk, 0, stream>>>(Wf1, wf1H,  wf1L,  128, 512, 0,     65536);
    transpose_w<<<dim3(768), blk, 0, stream>>>(Wf2, wf2H,  wf2L,  512, 128, 0,     65536);
    pack_bias<<<dim3(5), blk, 0, stream>>>(bq, bk, bv, bqkv);

    embed_kernel<<<dim3(TROWS * 128 / 256), blk, 0, stream>>>(s, dd, e_w, e_b, ep_w, ep_b,
                                                              x32, xhi, xlo);

    for (int l = 0; l < 3; ++l) {
        // QKV (A split) -> head-blocked Qh/Kh/Vt
        gemm_tile<0, 4, 1><<<dim3(3, 404), blk, 0, stream>>>(xhi, xlo,
                                                             wqkvH + (size_t)l * 49152, wqkvL + (size_t)l * 49152,
                                                             bqkv + l * 384, nullptr, Qh, Kh, Vt, nullptr, 384);
        // attention (LDS-free MFMA): 28672 waves, 4 per block
        attn_kernel<<<dim3(7168), blk, 0, stream>>>(Qh, Kh, Vt, ohi, olo);
        // O-proj + bias + residual + fused BN1 stats
        hipMemsetAsync(stats, 0, 256 * 4, stream);
        gemm_tile<1, 4, 1><<<dim3(1, 404), blk, 0, stream>>>(ohi, olo,
                                                             woH + (size_t)l * 16384, woL + (size_t)l * 16384,
                                                             bo + l * 128, x32, y32, nullptr, nullptr, stats, 128);
        bn_final<<<dim3(1), dim3(128), 0, stream>>>(stats, g1 + l * 128, be1 + l * 128, sh);
        bn_apply<<<dim3(TROWS * 32 / 256), blk, 0, stream>>>((const f32x4*)y32, sh,
                                                             (f32x4*)x32, xhi, xlo);
        // FF1 (A split, ReLU hi-only out), K=128, N=512
        gemm_tile<2, 4, 1><<<dim3(4, 404), blk, 0, stream>>>(xhi, xlo,
                                                             wf1H + (size_t)l * 65536, wf1L + (size_t)l * 65536,
                                                             bf1 + l * 512, nullptr, h1h, nullptr, nullptr, nullptr, 512);
        // FF2 (A single, 2-term) + bias + residual + fused BN2 stats, K=512, N=128
        hipMemsetAsync(stats, 0, 256 * 4, stream);
        gemm_tile<1, 16, 0><<<dim3(1, 404), blk, 0, stream>>>(h1h, nullptr,
                                                              wf2H + (size_t)l * 65536, wf2L + (size_t)l * 65536,
                                                              bf2 + l * 128, x32, y32, nullptr, nullptr, stats, 128);
        bn_final<<<dim3(1), dim3(128), 0, stream>>>(stats, g2 + l * 128, be2 + l * 128, sh);
        float* xdst = (l == 2) ? (float*)d_out : x32;
        bn_apply<<<dim3(TROWS * 32 / 256), blk, 0, stream>>>((const f32x4*)y32, sh,
                                                             (f32x4*)xdst, xhi, xlo);
    }
}

// Round 8
// 671.221 us; speedup vs baseline: 2.8741x; 1.2077x over previous
//
#include <hip/hip_runtime.h>
#include <hip/hip_fp16.h>
#include <stdint.h>

#define TROWS 51712   // 512*101
#define NCITY 101
#define BATCH 512
#define EDIM  128
#define NBH   4096    // BATCH*8 heads

using half_t = _Float16;
typedef __attribute__((ext_vector_type(8))) _Float16 h8;
typedef __attribute__((ext_vector_type(4))) _Float16 h4;
typedef __attribute__((ext_vector_type(4))) float   f32x4;

typedef __attribute__((address_space(1))) const unsigned int gu32;
typedef __attribute__((address_space(3))) unsigned int lu32;
static __device__ __forceinline__ void async16(const void* g, const void* l) {
    __builtin_amdgcn_global_load_lds((gu32*)g, (lu32*)(uint32_t)(uintptr_t)l, 16, 0, 0);
}

// ---------------- weight prep: transpose to [n][k] fp16 ----------------
__global__ __launch_bounds__(256)
void transpose_w(const float* __restrict__ src, half_t* __restrict__ dst,
                 int K, int N, int dstOff, int dstLS)
{
    int gid = blockIdx.x * 256 + threadIdx.x;
    int total = 3 * K * N;
    if (gid >= total) return;
    int l = gid / (K * N);
    int r = gid - l * (K * N);
    int k = r / N;
    int n = r - k * N;
    dst[(size_t)l * dstLS + dstOff + (size_t)n * K + k] = (half_t)src[gid];
}

__global__ __launch_bounds__(256)
void pack_bias(const float* __restrict__ bq, const float* __restrict__ bk,
               const float* __restrict__ bv, float* __restrict__ dst)
{
    int gid = blockIdx.x * 256 + threadIdx.x;
    if (gid >= 3 * 384) return;
    int l = gid / 384, c = gid - l * 384;
    float v = (c < 128) ? bq[l * 128 + c]
            : (c < 256) ? bk[l * 128 + c - 128]
                        : bv[l * 128 + c - 256];
    dst[gid] = v;
}

// ---------------- embedding (fp16 activation mirror only) ----------------
__global__ __launch_bounds__(256)
void embed_kernel(const float* __restrict__ s, const int* __restrict__ d,
                  const float* __restrict__ e_w, const float* __restrict__ e_b,
                  const float* __restrict__ ep_w, const float* __restrict__ ep_b,
                  half_t* __restrict__ xh)
{
    int gid = blockIdx.x * 256 + threadIdx.x;      // over TROWS*128
    int row = gid >> 7;
    int c   = gid & 127;
    int b = row / NCITY;
    int n = row - b * NCITY;
    const float* sp = s + ((size_t)b * NCITY + n) * 2;
    float v;
    if (n == 0) {
        v = sp[0] * ep_w[c] + sp[1] * ep_w[128 + c] + ep_b[c];
    } else {
        float dv = (float)d[b * NCITY + n];
        v = sp[0] * e_w[c] + sp[1] * e_w[128 + c] + dv * e_w[256 + c] + e_b[c];
    }
    xh[gid] = (half_t)v;
}

// ---------------- fp16 GEMM, 1-barrier double-buffered pipeline ----------------
// C = A(M x K fp16) * B(N x K fp16)^T, f32 accum. Block 128x128, BK=32,
// 4 waves 2x2 (wave tile 64x64, acc[4][4]). LDS 2 x (8+8) KB.
// Pipeline: barrier drains loads issued one full compute-phase earlier.
// MODE 0: QKV — scatter fp16 to Qh[bh][101][16], Kh[bh][101][16], Vt[bh][16][128]
// MODE 1: out f32 = acc + bias + res(fp16), fused BN stats (O-proj / FF2)
// MODE 2: out fp16 = relu(acc + bias)       (FF1)
template<int MODE, int KSTEPS>
__global__ __launch_bounds__(256)
void gemm_tile(const half_t* __restrict__ A, const half_t* __restrict__ B,
               const float* __restrict__ bias, const half_t* __restrict__ res,
               void* __restrict__ out, void* __restrict__ outK, void* __restrict__ outV,
               float* __restrict__ stats, int Nout)
{
    constexpr int K = KSTEPS * 32;
    __shared__ alignas(16) half_t sA[2][128 * 32];
    __shared__ alignas(16) half_t sB[2][128 * 32];

    const int tid  = threadIdx.x;
    const int wave = tid >> 6, lane = tid & 63;
    const int n0 = blockIdx.x * 128;
    const int m0 = blockIdx.y * 128;

    const int sr = wave * 16 + (lane >> 2);
    const int sc = (lane & 3) * 8;
    const half_t* gA = A + (size_t)(m0 + sr) * K + sc;
    const half_t* gB = B + (size_t)(n0 + sr) * K + sc;
    const int ldst = wave * 512;   // elems; +2048 for rows 64..127

    const int quad = lane >> 4, l16 = lane & 15;
    const int wm = (wave >> 1) * 64, wn = (wave & 1) * 64;

    f32x4 acc[4][4] = {};

    // preamble: stage k-slice 0 into buf 0
    async16(gA,                  &sA[0][ldst]);
    async16(gA + (size_t)64 * K, &sA[0][2048 + ldst]);
    async16(gB,                  &sB[0][ldst]);
    async16(gB + (size_t)64 * K, &sB[0][2048 + ldst]);

    for (int ks = 0; ks < KSTEPS; ++ks) {
        __syncthreads();   // drains buf[ks&1] loads (issued one phase ago) + syncs reuse
        if (ks + 1 < KSTEPS) {
            const int k0 = (ks + 1) * 32;
            const int nb = (ks + 1) & 1;
            async16(gA + k0,                  &sA[nb][ldst]);
            async16(gA + (size_t)64 * K + k0, &sA[nb][2048 + ldst]);
            async16(gB + k0,                  &sB[nb][ldst]);
            async16(gB + (size_t)64 * K + k0, &sB[nb][2048 + ldst]);
        }
        const int cb = ks & 1;
        h8 af[4], bf[4];
        #pragma unroll
        for (int mi = 0; mi < 4; ++mi)
            af[mi] = *(const h8*)(&sA[cb][(wm + mi * 16 + l16) * 32 + quad * 8]);
        #pragma unroll
        for (int ni = 0; ni < 4; ++ni)
            bf[ni] = *(const h8*)(&sB[cb][(wn + ni * 16 + l16) * 32 + quad * 8]);
        #pragma unroll
        for (int mi = 0; mi < 4; ++mi)
        #pragma unroll
        for (int ni = 0; ni < 4; ++ni)
            acc[mi][ni] = __builtin_amdgcn_mfma_f32_16x16x32_f16(af[mi], bf[ni], acc[mi][ni], 0, 0, 0);
    }

    // epilogue: row = m0 + wm + mi*16 + quad*4 + r, col = n0 + wn + ni*16 + l16
    #pragma unroll
    for (int ni = 0; ni < 4; ++ni) {
        int col = n0 + wn + ni * 16 + l16;
        float bvv = bias[col];
        float s = 0.0f, ss = 0.0f;
        #pragma unroll
        for (int mi = 0; mi < 4; ++mi) {
            #pragma unroll
            for (int r = 0; r < 4; ++r) {
                int row = m0 + wm + mi * 16 + quad * 4 + r;
                float v = acc[mi][ni][r] + bvv;
                if (MODE == 0) {
                    int b   = row / NCITY;
                    int tok = row - b * NCITY;
                    int which = col >> 7;          // wave-uniform per ni
                    int h     = (col >> 4) & 7;    // wave-uniform per ni
                    int bh    = b * 8 + h;
                    half_t hv = (half_t)v;
                    if (which == 0)
                        ((half_t*)out)[((size_t)bh * NCITY + tok) * 16 + l16] = hv;
                    else if (which == 1)
                        ((half_t*)outK)[((size_t)bh * NCITY + tok) * 16 + l16] = hv;
                    else
                        ((half_t*)outV)[((size_t)bh * 16 + l16) * 128 + tok] = hv;
                } else if (MODE == 1) {
                    size_t off = (size_t)row * Nout + col;
                    float o = v + (float)res[off];
                    ((float*)out)[off] = o;
                    s += o; ss += o * o;
                } else {
                    size_t off = (size_t)row * Nout + col;
                    v = v > 0.0f ? v : 0.0f;
                    ((half_t*)out)[off] = (half_t)v;
                }
            }
        }
        if (MODE == 1) {
            s  += __shfl_xor(s, 16);  s  += __shfl_xor(s, 32);
            ss += __shfl_xor(ss, 16); ss += __shfl_xor(ss, 32);
            if (quad == 0) {
                atomicAdd(&stats[col], s);
                atomicAdd(&stats[128 + col], ss);
            }
        }
    }
}

// ---------------- LDS-free fp16 MFMA attention: one wave per (bh, q-tile) ----------------
__global__ __launch_bounds__(256)
void attn_kernel(const half_t* __restrict__ Qh, const half_t* __restrict__ Kh,
                 const half_t* __restrict__ Vt, half_t* __restrict__ oh)
{
    const int wid = blockIdx.x * 4 + (threadIdx.x >> 6);   // 0..28671
    const int bh = wid / 7;
    const int it = wid - bh * 7;
    if (bh >= NBH) return;
    const int b = bh >> 3, h = bh & 7;

    const int lane = threadIdx.x & 63, quad = lane >> 4, l16 = lane & 15;
    const int s0 = l16 + (((2 * quad)     & 3) << 4);
    const int s1 = l16 + (((2 * quad + 1) & 3) << 4);

    const half_t* qbase = Qh + (size_t)bh * NCITY * 16;
    const half_t* kbase = Kh + (size_t)bh * NCITY * 16;
    const half_t* vbase = Vt + (size_t)bh * 16 * 128;

    h8 qf = {};
    if (quad < 2)
        qf = *reinterpret_cast<const h8*>(qbase + (it * 16 + l16) * 16 + quad * 8);

    f32x4 S[7];
    #pragma unroll
    for (int jt = 0; jt < 7; ++jt) {
        h8 kf = {};
        if (quad < 2)
            kf = *reinterpret_cast<const h8*>(kbase + (jt * 16 + l16) * 16 + quad * 8);
        f32x4 a = {};
        a = __builtin_amdgcn_mfma_f32_16x16x32_f16(kf, qf, a, 0, 0, 0);
        S[jt] = a;
    }
    float m = -1e30f;
    #pragma unroll
    for (int jt = 0; jt < 7; ++jt)
        #pragma unroll
        for (int r = 0; r < 4; ++r) {
            int jg = jt * 16 + quad * 4 + r;
            float sv = (jg < NCITY) ? S[jt][r] * 0.25f : -1e30f;
            S[jt][r] = sv;
            m = fmaxf(m, sv);
        }
    m = fmaxf(m, __shfl_xor(m, 16));
    m = fmaxf(m, __shfl_xor(m, 32));
    float sum = 0.0f;
    #pragma unroll
    for (int jt = 0; jt < 7; ++jt)
        #pragma unroll
        for (int r = 0; r < 4; ++r) {
            float e = __expf(S[jt][r] - m);
            S[jt][r] = e;
            sum += e;
        }
    sum += __shfl_xor(sum, 16);
    sum += __shfl_xor(sum, 32);
    float inv = 1.0f / sum;
    #pragma unroll
    for (int jt = 0; jt < 7; ++jt)
        #pragma unroll
        for (int r = 0; r < 4; ++r) S[jt][r] *= inv;

    f32x4 O = {};
    #pragma unroll
    for (int p = 0; p < 4; ++p) {
        float pj[8];
        #pragma unroll
        for (int r = 0; r < 4; ++r) {
            float t0 = S[2 * p][r];
            float t1 = (2 * p + 1 < 7) ? S[2 * p + 1][r] : 0.0f;
            float x0 = __shfl(t0, s0);
            float y0 = __shfl(t1, s0);
            float x1 = __shfl(t0, s1);
            float y1 = __shfl(t1, s1);
            pj[r]     = (quad < 2) ? x0 : y0;
            pj[4 + r] = (quad < 2) ? x1 : y1;
        }
        h8 ph;
        #pragma unroll
        for (int jj = 0; jj < 8; ++jj)
            ph[jj] = (half_t)pj[jj];
        h8 vf = *reinterpret_cast<const h8*>(vbase + l16 * 128 + p * 32 + quad * 8);
        O = __builtin_amdgcn_mfma_f32_16x16x32_f16(vf, ph, O, 0, 0, 0);
    }
    int i = it * 16 + l16;
    if (i < NCITY) {
        size_t oo = ((size_t)b * NCITY + i) * 128 + h * 16 + quad * 4;
        h4 o4;
        #pragma unroll
        for (int r = 0; r < 4; ++r) o4[r] = (half_t)O[r];
        *reinterpret_cast<h4*>(oh + oo) = o4;
    }
}

// ---------------- BatchNorm finalize + apply ----------------
__global__ void bn_final(const float* __restrict__ stats, const float* __restrict__ g,
                         const float* __restrict__ be, float* __restrict__ sh)
{
    int c = threadIdx.x;  // 128 threads
    const float invN = 1.0f / (float)TROWS;
    float mean = stats[c] * invN;
    float var  = stats[128 + c] * invN - mean * mean;
    float inv  = rsqrtf(var + 1e-5f);
    float scl  = g[c] * inv;
    sh[c]       = scl;
    sh[128 + c] = be[c] - mean * scl;
}

__global__ __launch_bounds__(256)
void bn_apply(const f32x4* __restrict__ y, const float* __restrict__ sh,
              half_t* __restrict__ xh, float* __restrict__ dst32)
{
    int gid = blockIdx.x * 256 + threadIdx.x;   // over TROWS*32 (4 ch each)
    int c = (gid & 31) * 4;
    f32x4 v = y[gid];
    h4 hv;
    #pragma unroll
    for (int r = 0; r < 4; ++r) {
        float o = v[r] * sh[c + r] + sh[128 + c + r];
        v[r] = o;
        hv[r] = (half_t)o;
    }
    *reinterpret_cast<h4*>(xh + (size_t)gid * 4) = hv;
    if (dst32) ((f32x4*)dst32)[gid] = v;
}

// ---------------- launch ----------------
extern "C" void kernel_launch(void* const* d_in, const int* in_sizes, int n_in,
                              void* d_out, int out_size, void* d_ws, size_t ws_size,
                              hipStream_t stream)
{
    const float* s    = (const float*)d_in[0];
    const int*   dd   = (const int*)d_in[1];
    const float* e_w  = (const float*)d_in[2];
    const float* e_b  = (const float*)d_in[3];
    const float* ep_w = (const float*)d_in[4];
    const float* ep_b = (const float*)d_in[5];
    const float* Wq   = (const float*)d_in[6];
    const float* bq   = (const float*)d_in[7];
    const float* Wk   = (const float*)d_in[8];
    const float* bk   = (const float*)d_in[9];
    const float* Wv   = (const float*)d_in[10];
    const float* bv   = (const float*)d_in[11];
    const float* Wo   = (const float*)d_in[12];
    const float* bo   = (const float*)d_in[13];
    const float* Wf1  = (const float*)d_in[14];
    const float* bf1  = (const float*)d_in[15];
    const float* Wf2  = (const float*)d_in[16];
    const float* bf2  = (const float*)d_in[17];
    const float* g1   = (const float*)d_in[18];
    const float* be1  = (const float*)d_in[19];
    const float* g2   = (const float*)d_in[20];
    const float* be2  = (const float*)d_in[21];

    char* ws = (char*)d_ws;
    size_t off = 0;
    auto alloc = [&](size_t bytes) -> void* {
        void* p = ws + off;
        off += (bytes + 255) & ~(size_t)255;
        return p;
    };
    float*  y32   = (float*) alloc((size_t)TROWS * 128 * 4);
    half_t* xh    = (half_t*)alloc((size_t)TROWS * 128 * 2);
    // attention tensors (contiguous; h1 aliases Qh..oh span)
    half_t* Qh    = (half_t*)alloc((size_t)NBH * NCITY * 16 * 2);   // 13.24 MB
    half_t* Kh    = (half_t*)alloc((size_t)NBH * NCITY * 16 * 2);   // 13.24 MB
    half_t* Vt    = (half_t*)alloc((size_t)NBH * 16 * 128 * 2);     // 16.78 MB
    half_t* oh    = (half_t*)alloc((size_t)TROWS * 128 * 2);        // 13.24 MB
    half_t* h1    = Qh;   // TROWS*512 fp16 = 52.95 MB <= span 56.5 MB
    half_t* wqkv  = (half_t*)alloc((size_t)3 * 384 * 128 * 2);
    half_t* wo    = (half_t*)alloc((size_t)3 * 128 * 128 * 2);
    half_t* wf1   = (half_t*)alloc((size_t)3 * 512 * 128 * 2);
    half_t* wf2   = (half_t*)alloc((size_t)3 * 128 * 512 * 2);
    float*  bqkv  = (float*) alloc((size_t)3 * 384 * 4);
    float*  stats = (float*) alloc(256 * 4);
    float*  sh    = (float*) alloc(256 * 4);

    dim3 blk(256);

    // weight prep
    transpose_w<<<dim3(192), blk, 0, stream>>>(Wq,  wqkv, 128, 128, 0,     49152);
    transpose_w<<<dim3(192), blk, 0, stream>>>(Wk,  wqkv, 128, 128, 16384, 49152);
    transpose_w<<<dim3(192), blk, 0, stream>>>(Wv,  wqkv, 128, 128, 32768, 49152);
    transpose_w<<<dim3(192), blk, 0, stream>>>(Wo,  wo,   128, 128, 0,     16384);
    transpose_w<<<dim3(768), blk, 0, stream>>>(Wf1, wf1,  128, 512, 0,     65536);
    transpose_w<<<dim3(768), blk, 0, stream>>>(Wf2, wf2,  512, 128, 0,     65536);
    pack_bias<<<dim3(5), blk, 0, stream>>>(bq, bk, bv, bqkv);

    embed_kernel<<<dim3(TROWS * 128 / 256), blk, 0, stream>>>(s, dd, e_w, e_b, ep_w, ep_b, xh);

    for (int l = 0; l < 3; ++l) {
        // QKV -> head-blocked Qh/Kh/Vt (fp16)
        gemm_tile<0, 4><<<dim3(3, 404), blk, 0, stream>>>(xh, wqkv + (size_t)l * 49152,
                                                          bqkv + l * 384, nullptr,
                                                          Qh, Kh, Vt, nullptr, 384);
        // attention (LDS-free fp16 MFMA)
        attn_kernel<<<dim3(7168), blk, 0, stream>>>(Qh, Kh, Vt, oh);
        // O-proj + bias + residual(xh) + fused BN1 stats
        hipMemsetAsync(stats, 0, 256 * 4, stream);
        gemm_tile<1, 4><<<dim3(1, 404), blk, 0, stream>>>(oh, wo + (size_t)l * 16384,
                                                          bo + l * 128, xh,
                                                          y32, nullptr, nullptr, stats, 128);
        bn_final<<<dim3(1), dim3(128), 0, stream>>>(stats, g1 + l * 128, be1 + l * 128, sh);
        bn_apply<<<dim3(TROWS * 32 / 256), blk, 0, stream>>>((const f32x4*)y32, sh, xh, nullptr);
        // FF1 (ReLU fp16 out), K=128, N=512
        gemm_tile<2, 4><<<dim3(4, 404), blk, 0, stream>>>(xh, wf1 + (size_t)l * 65536,
                                                          bf1 + l * 512, nullptr,
                                                          h1, nullptr, nullptr, nullptr, 512);
        // FF2 + bias + residual(xh) + fused BN2 stats, K=512, N=128
        hipMemsetAsync(stats, 0, 256 * 4, stream);
        gemm_tile<1, 16><<<dim3(1, 404), blk, 0, stream>>>(h1, wf2 + (size_t)l * 65536,
                                                           bf2 + l * 128, xh,
                                                           y32, nullptr, nullptr, stats, 128);
        bn_final<<<dim3(1), dim3(128), 0, stream>>>(stats, g2 + l * 128, be2 + l * 128, sh);
        bn_apply<<<dim3(TROWS * 32 / 256), blk, 0, stream>>>((const f32x4*)y32, sh, xh,
                                                             (l == 2) ? (float*)d_out : nullptr);
    }
}

// Round 9
// 594.723 us; speedup vs baseline: 3.2438x; 1.1286x over previous
//
#include <hip/hip_runtime.h>
#include <hip/hip_fp16.h>
#include <stdint.h>

#define TROWS 51712   // 512*101
#define NCITY 101
#define BATCH 512
#define EDIM  128
#define NBH   4096    // BATCH*8 heads

using half_t = _Float16;
typedef __attribute__((ext_vector_type(8))) _Float16 h8;
typedef __attribute__((ext_vector_type(4))) _Float16 h4;
typedef __attribute__((ext_vector_type(4))) float   f32x4;

typedef __attribute__((address_space(1))) const unsigned int gu32;
typedef __attribute__((address_space(3))) unsigned int lu32;
static __device__ __forceinline__ void async16(const void* g, const void* l) {
    __builtin_amdgcn_global_load_lds((gu32*)g, (lu32*)(uint32_t)(uintptr_t)l, 16, 0, 0);
}

// ---------------- weight prep: transpose to [n][k] fp16 ----------------
__global__ __launch_bounds__(256)
void transpose_w(const float* __restrict__ src, half_t* __restrict__ dst,
                 int K, int N, int dstOff, int dstLS)
{
    int gid = blockIdx.x * 256 + threadIdx.x;
    int total = 3 * K * N;
    if (gid >= total) return;
    int l = gid / (K * N);
    int r = gid - l * (K * N);
    int k = r / N;
    int n = r - k * N;
    dst[(size_t)l * dstLS + dstOff + (size_t)n * K + k] = (half_t)src[gid];
}

__global__ __launch_bounds__(256)
void pack_bias(const float* __restrict__ bq, const float* __restrict__ bk,
               const float* __restrict__ bv, float* __restrict__ dst)
{
    int gid = blockIdx.x * 256 + threadIdx.x;
    if (gid >= 3 * 384) return;
    int l = gid / 384, c = gid - l * 384;
    float v = (c < 128) ? bq[l * 128 + c]
            : (c < 256) ? bk[l * 128 + c - 128]
                        : bv[l * 128 + c - 256];
    dst[gid] = v;
}

// ---------------- embedding (fp16 activation mirror only) ----------------
__global__ __launch_bounds__(256)
void embed_kernel(const float* __restrict__ s, const int* __restrict__ d,
                  const float* __restrict__ e_w, const float* __restrict__ e_b,
                  const float* __restrict__ ep_w, const float* __restrict__ ep_b,
                  half_t* __restrict__ xh)
{
    int gid = blockIdx.x * 256 + threadIdx.x;      // over TROWS*128
    int row = gid >> 7;
    int c   = gid & 127;
    int b = row / NCITY;
    int n = row - b * NCITY;
    const float* sp = s + ((size_t)b * NCITY + n) * 2;
    float v;
    if (n == 0) {
        v = sp[0] * ep_w[c] + sp[1] * ep_w[128 + c] + ep_b[c];
    } else {
        float dv = (float)d[b * NCITY + n];
        v = sp[0] * e_w[c] + sp[1] * e_w[128 + c] + dv * e_w[256 + c] + e_b[c];
    }
    xh[gid] = (half_t)v;
}

// ---------------- fp16 GEMM, 1-barrier double-buffered pipeline ----------------
// C = A(M x K fp16) * B(N x K fp16)^T, f32 accum. Block 128x128, BK=32,
// 4 waves 2x2 (wave tile 64x64, acc[4][4]). LDS 2 x (8+8) KB.
// MODE 0: QKV — scatter fp16 to Q/K/V, all [bh][tok][16] (32B-segment stores)
// MODE 1: out fp16 y = acc + bias + res(fp16), fused BN stats (O-proj / FF2)
// MODE 2: out fp16 = relu(acc + bias)       (FF1)
template<int MODE, int KSTEPS>
__global__ __launch_bounds__(256)
void gemm_tile(const half_t* __restrict__ A, const half_t* __restrict__ B,
               const float* __restrict__ bias, const half_t* __restrict__ res,
               void* __restrict__ out, void* __restrict__ outK, void* __restrict__ outV,
               float* __restrict__ stats, int Nout)
{
    constexpr int K = KSTEPS * 32;
    __shared__ alignas(16) half_t sA[2][128 * 32];
    __shared__ alignas(16) half_t sB[2][128 * 32];

    const int tid  = threadIdx.x;
    const int wave = tid >> 6, lane = tid & 63;
    const int n0 = blockIdx.x * 128;
    const int m0 = blockIdx.y * 128;

    const int sr = wave * 16 + (lane >> 2);
    const int sc = (lane & 3) * 8;
    const half_t* gA = A + (size_t)(m0 + sr) * K + sc;
    const half_t* gB = B + (size_t)(n0 + sr) * K + sc;
    const int ldst = wave * 512;   // elems; +2048 for rows 64..127

    const int quad = lane >> 4, l16 = lane & 15;
    const int wm = (wave >> 1) * 64, wn = (wave & 1) * 64;

    f32x4 acc[4][4] = {};

    async16(gA,                  &sA[0][ldst]);
    async16(gA + (size_t)64 * K, &sA[0][2048 + ldst]);
    async16(gB,                  &sB[0][ldst]);
    async16(gB + (size_t)64 * K, &sB[0][2048 + ldst]);

    for (int ks = 0; ks < KSTEPS; ++ks) {
        __syncthreads();   // drains loads issued one full compute-phase ago
        if (ks + 1 < KSTEPS) {
            const int k0 = (ks + 1) * 32;
            const int nb = (ks + 1) & 1;
            async16(gA + k0,                  &sA[nb][ldst]);
            async16(gA + (size_t)64 * K + k0, &sA[nb][2048 + ldst]);
            async16(gB + k0,                  &sB[nb][ldst]);
            async16(gB + (size_t)64 * K + k0, &sB[nb][2048 + ldst]);
        }
        const int cb = ks & 1;
        h8 af[4], bf[4];
        #pragma unroll
        for (int mi = 0; mi < 4; ++mi)
            af[mi] = *(const h8*)(&sA[cb][(wm + mi * 16 + l16) * 32 + quad * 8]);
        #pragma unroll
        for (int ni = 0; ni < 4; ++ni)
            bf[ni] = *(const h8*)(&sB[cb][(wn + ni * 16 + l16) * 32 + quad * 8]);
        #pragma unroll
        for (int mi = 0; mi < 4; ++mi)
        #pragma unroll
        for (int ni = 0; ni < 4; ++ni)
            acc[mi][ni] = __builtin_amdgcn_mfma_f32_16x16x32_f16(af[mi], bf[ni], acc[mi][ni], 0, 0, 0);
    }

    // epilogue: row = m0 + wm + mi*16 + quad*4 + r, col = n0 + wn + ni*16 + l16
    #pragma unroll
    for (int ni = 0; ni < 4; ++ni) {
        int col = n0 + wn + ni * 16 + l16;
        float bvv = bias[col];
        float s = 0.0f, ss = 0.0f;
        #pragma unroll
        for (int mi = 0; mi < 4; ++mi) {
            #pragma unroll
            for (int r = 0; r < 4; ++r) {
                int row = m0 + wm + mi * 16 + quad * 4 + r;
                float v = acc[mi][ni][r] + bvv;
                if (MODE == 0) {
                    int b   = row / NCITY;
                    int tok = row - b * NCITY;
                    int which = col >> 7;          // wave-uniform per ni
                    int h     = (col >> 4) & 7;    // wave-uniform per ni
                    int bh    = b * 8 + h;
                    half_t hv = (half_t)v;
                    half_t* dst = (which == 0) ? (half_t*)out
                                : (which == 1) ? (half_t*)outK : (half_t*)outV;
                    dst[((size_t)bh * NCITY + tok) * 16 + l16] = hv;
                } else if (MODE == 1) {
                    size_t off = (size_t)row * Nout + col;
                    float o = v + (float)res[off];
                    ((half_t*)out)[off] = (half_t)o;
                    s += o; ss += o * o;
                } else {
                    size_t off = (size_t)row * Nout + col;
                    v = v > 0.0f ? v : 0.0f;
                    ((half_t*)out)[off] = (half_t)v;
                }
            }
        }
        if (MODE == 1) {
            s  += __shfl_xor(s, 16);  s  += __shfl_xor(s, 32);
            ss += __shfl_xor(ss, 16); ss += __shfl_xor(ss, 32);
            if (quad == 0) {
                atomicAdd(&stats[col], s);
                atomicAdd(&stats[128 + col], ss);
            }
        }
    }
}

// ---------------- LDS-free fp16 MFMA attention: one wave per (bh, q-tile) ----------------
// Q/K/V all [bh][tok][16]. S^T = K·Q^T; softmax per-column;
// O = P·V (A=P gathered from S via shuffles, B=V gathered scalar from global).
__global__ __launch_bounds__(256)
void attn_kernel(const half_t* __restrict__ Qh, const half_t* __restrict__ Kh,
                 const half_t* __restrict__ V, half_t* __restrict__ oh)
{
    const int wid = blockIdx.x * 4 + (threadIdx.x >> 6);   // 0..28671
    const int bh = wid / 7;
    const int it = wid - bh * 7;
    if (bh >= NBH) return;
    const int b = bh >> 3, h = bh & 7;

    const int lane = threadIdx.x & 63, quad = lane >> 4, l16 = lane & 15;
    // P A-frag gather: src lanes for jj 0..3 and 4..7
    const int s0 = (((quad & 1) * 2)    ) * 16 + l16;
    const int s1 = (((quad & 1) * 2) + 1) * 16 + l16;
    const bool hi2 = (quad >> 1) != 0;

    const half_t* qbase = Qh + (size_t)bh * NCITY * 16;
    const half_t* kbase = Kh + (size_t)bh * NCITY * 16;
    const half_t* vbase = V  + (size_t)bh * NCITY * 16;

    h8 qf = {};
    if (quad < 2)
        qf = *reinterpret_cast<const h8*>(qbase + (it * 16 + l16) * 16 + quad * 8);

    f32x4 S[7];
    #pragma unroll
    for (int jt = 0; jt < 7; ++jt) {
        h8 kf = {};
        if (quad < 2)
            kf = *reinterpret_cast<const h8*>(kbase + (jt * 16 + l16) * 16 + quad * 8);
        f32x4 a = {};
        a = __builtin_amdgcn_mfma_f32_16x16x32_f16(kf, qf, a, 0, 0, 0);
        S[jt] = a;
    }
    float m = -1e30f;
    #pragma unroll
    for (int jt = 0; jt < 7; ++jt)
        #pragma unroll
        for (int r = 0; r < 4; ++r) {
            int jg = jt * 16 + quad * 4 + r;
            float sv = (jg < NCITY) ? S[jt][r] * 0.25f : -1e30f;
            S[jt][r] = sv;
            m = fmaxf(m, sv);
        }
    m = fmaxf(m, __shfl_xor(m, 16));
    m = fmaxf(m, __shfl_xor(m, 32));
    float sum = 0.0f;
    #pragma unroll
    for (int jt = 0; jt < 7; ++jt)
        #pragma unroll
        for (int r = 0; r < 4; ++r) {
            float e = __expf(S[jt][r] - m);
            S[jt][r] = e;
            sum += e;
        }
    sum += __shfl_xor(sum, 16);
    sum += __shfl_xor(sum, 32);
    float inv = 1.0f / sum;
    #pragma unroll
    for (int jt = 0; jt < 7; ++jt)
        #pragma unroll
        for (int r = 0; r < 4; ++r) S[jt][r] *= inv;

    // O = P·V over 4 key-blocks of 32.  A-frag: P[q=l16][k=p*32+quad*8+jj]
    f32x4 O = {};
    #pragma unroll
    for (int p = 0; p < 4; ++p) {
        // V B-frag gather: V[tok=p*32+quad*8+jj][dk=l16] (OOB toks hit finite
        // neighbor data; P=0 there so product is 0)
        h8 vf;
        #pragma unroll
        for (int jj = 0; jj < 8; ++jj)
            vf[jj] = vbase[(size_t)(p * 32 + quad * 8 + jj) * 16 + l16];
        float pj[8];
        #pragma unroll
        for (int r = 0; r < 4; ++r) {
            float a0 = __shfl(S[2 * p][r],     s0);
            float b0 = __shfl(S[2 * p + 1][r], s0);
            float a1 = __shfl(S[2 * p][r],     s1);
            float b1 = __shfl(S[2 * p + 1][r], s1);
            pj[r]     = hi2 ? b0 : a0;
            pj[4 + r] = hi2 ? b1 : a1;
        }
        h8 ph;
        #pragma unroll
        for (int jj = 0; jj < 8; ++jj)
            ph[jj] = (half_t)pj[jj];
        O = __builtin_amdgcn_mfma_f32_16x16x32_f16(ph, vf, O, 0, 0, 0);
    }
    // C-frag: lane holds O[q=it*16+quad*4+r][dk=l16]
    #pragma unroll
    for (int r = 0; r < 4; ++r) {
        int q = it * 16 + quad * 4 + r;
        if (q < NCITY)
            oh[((size_t)b * NCITY + q) * 128 + h * 16 + l16] = (half_t)O[r];
    }
}

// ---------------- BatchNorm finalize + apply ----------------
__global__ void bn_final(const float* __restrict__ stats, const float* __restrict__ g,
                         const float* __restrict__ be, float* __restrict__ sh)
{
    int c = threadIdx.x;  // 128 threads
    const float invN = 1.0f / (float)TROWS;
    float mean = stats[c] * invN;
    float var  = stats[128 + c] * invN - mean * mean;
    float inv  = rsqrtf(var + 1e-5f);
    float scl  = g[c] * inv;
    sh[c]       = scl;
    sh[128 + c] = be[c] - mean * scl;
}

__global__ __launch_bounds__(256)
void bn_apply(const h8* __restrict__ y, const float* __restrict__ sh,
              half_t* __restrict__ xh, float* __restrict__ dst32)
{
    int gid = blockIdx.x * 256 + threadIdx.x;   // over TROWS*16 (8 ch each)
    int c = (gid & 15) * 8;
    h8 v = y[gid];
    h8 hv;
    float o[8];
    #pragma unroll
    for (int r = 0; r < 8; ++r) {
        o[r] = (float)v[r] * sh[c + r] + sh[128 + c + r];
        hv[r] = (half_t)o[r];
    }
    *reinterpret_cast<h8*>(xh + (size_t)gid * 8) = hv;
    if (dst32) {
        f32x4 lo = { o[0], o[1], o[2], o[3] };
        f32x4 hi = { o[4], o[5], o[6], o[7] };
        ((f32x4*)dst32)[gid * 2]     = lo;
        ((f32x4*)dst32)[gid * 2 + 1] = hi;
    }
}

// ---------------- launch ----------------
extern "C" void kernel_launch(void* const* d_in, const int* in_sizes, int n_in,
                              void* d_out, int out_size, void* d_ws, size_t ws_size,
                              hipStream_t stream)
{
    const float* s    = (const float*)d_in[0];
    const int*   dd   = (const int*)d_in[1];
    const float* e_w  = (const float*)d_in[2];
    const float* e_b  = (const float*)d_in[3];
    const float* ep_w = (const float*)d_in[4];
    const float* ep_b = (const float*)d_in[5];
    const float* Wq   = (const float*)d_in[6];
    const float* bq   = (const float*)d_in[7];
    const float* Wk   = (const float*)d_in[8];
    const float* bk   = (const float*)d_in[9];
    const float* Wv   = (const float*)d_in[10];
    const float* bv   = (const float*)d_in[11];
    const float* Wo   = (const float*)d_in[12];
    const float* bo   = (const float*)d_in[13];
    const float* Wf1  = (const float*)d_in[14];
    const float* bf1  = (const float*)d_in[15];
    const float* Wf2  = (const float*)d_in[16];
    const float* bf2  = (const float*)d_in[17];
    const float* g1   = (const float*)d_in[18];
    const float* be1  = (const float*)d_in[19];
    const float* g2   = (const float*)d_in[20];
    const float* be2  = (const float*)d_in[21];

    char* ws = (char*)d_ws;
    size_t off = 0;
    auto alloc = [&](size_t bytes) -> void* {
        void* p = ws + off;
        off += (bytes + 255) & ~(size_t)255;
        return p;
    };
    half_t* y16   = (half_t*)alloc((size_t)TROWS * 128 * 2);
    half_t* xh    = (half_t*)alloc((size_t)TROWS * 128 * 2);
    // attention tensors, all [bh][101][16]; h1 aliases Qh..oh (4 x 13.238 MB = exactly TROWS*512 fp16)
    half_t* Qh    = (half_t*)alloc((size_t)NBH * NCITY * 16 * 2);
    half_t* Kh    = (half_t*)alloc((size_t)NBH * NCITY * 16 * 2);
    half_t* Vb    = (half_t*)alloc((size_t)NBH * NCITY * 16 * 2);
    half_t* oh    = (half_t*)alloc((size_t)TROWS * 128 * 2);
    half_t* h1    = Qh;
    half_t* wqkv  = (half_t*)alloc((size_t)3 * 384 * 128 * 2);
    half_t* wo    = (half_t*)alloc((size_t)3 * 128 * 128 * 2);
    half_t* wf1   = (half_t*)alloc((size_t)3 * 512 * 128 * 2);
    half_t* wf2   = (half_t*)alloc((size_t)3 * 128 * 512 * 2);
    float*  bqkv  = (float*) alloc((size_t)3 * 384 * 4);
    float*  stats = (float*) alloc(256 * 4);
    float*  sh    = (float*) alloc(256 * 4);

    dim3 blk(256);

    // weight prep
    transpose_w<<<dim3(192), blk, 0, stream>>>(Wq,  wqkv, 128, 128, 0,     49152);
    transpose_w<<<dim3(192), blk, 0, stream>>>(Wk,  wqkv, 128, 128, 16384, 49152);
    transpose_w<<<dim3(192), blk, 0, stream>>>(Wv,  wqkv, 128, 128, 32768, 49152);
    transpose_w<<<dim3(192), blk, 0, stream>>>(Wo,  wo,   128, 128, 0,     16384);
    transpose_w<<<dim3(768), blk, 0, stream>>>(Wf1, wf1,  128, 512, 0,     65536);
    transpose_w<<<dim3(768), blk, 0, stream>>>(Wf2, wf2,  512, 128, 0,     65536);
    pack_bias<<<dim3(5), blk, 0, stream>>>(bq, bk, bv, bqkv);

    embed_kernel<<<dim3(TROWS * 128 / 256), blk, 0, stream>>>(s, dd, e_w, e_b, ep_w, ep_b, xh);

    for (int l = 0; l < 3; ++l) {
        // QKV -> Q/K/V all [bh][tok][16]
        gemm_tile<0, 4><<<dim3(3, 404), blk, 0, stream>>>(xh, wqkv + (size_t)l * 49152,
                                                          bqkv + l * 384, nullptr,
                                                          Qh, Kh, Vb, nullptr, 384);
        // attention (LDS-free fp16 MFMA)
        attn_kernel<<<dim3(7168), blk, 0, stream>>>(Qh, Kh, Vb, oh);
        // O-proj + bias + residual(xh) + fused BN1 stats -> y16
        hipMemsetAsync(stats, 0, 256 * 4, stream);
        gemm_tile<1, 4><<<dim3(1, 404), blk, 0, stream>>>(oh, wo + (size_t)l * 16384,
                                                          bo + l * 128, xh,
                                                          y16, nullptr, nullptr, stats, 128);
        bn_final<<<dim3(1), dim3(128), 0, stream>>>(stats, g1 + l * 128, be1 + l * 128, sh);
        bn_apply<<<dim3(TROWS * 16 / 256), blk, 0, stream>>>((const h8*)y16, sh, xh, nullptr);
        // FF1 (ReLU fp16 out), K=128, N=512
        gemm_tile<2, 4><<<dim3(4, 404), blk, 0, stream>>>(xh, wf1 + (size_t)l * 65536,
                                                          bf1 + l * 512, nullptr,
                                                          h1, nullptr, nullptr, nullptr, 512);
        // FF2 + bias + residual(xh) + fused BN2 stats -> y16, K=512
        hipMemsetAsync(stats, 0, 256 * 4, stream);
        gemm_tile<1, 16><<<dim3(1, 404), blk, 0, stream>>>(h1, wf2 + (size_t)l * 65536,
                                                           bf2 + l * 128, xh,
                                                           y16, nullptr, nullptr, stats, 128);
        bn_final<<<dim3(1), dim3(128), 0, stream>>>(stats, g2 + l * 128, be2 + l * 128, sh);
        bn_apply<<<dim3(TROWS * 16 / 256), blk, 0, stream>>>((const h8*)y16, sh, xh,
                                                             (l == 2) ? (float*)d_out : nullptr);
    }
}

// Round 10
// 567.690 us; speedup vs baseline: 3.3983x; 1.0476x over previous
//
#include <hip/hip_runtime.h>
#include <hip/hip_fp16.h>
#include <stdint.h>

#define TROWS 51712   // 512*101
#define NCITY 101
#define BATCH 512
#define EDIM  128
#define NBH   4096    // BATCH*8 heads

using half_t = _Float16;
typedef __attribute__((ext_vector_type(8))) _Float16 h8;
typedef __attribute__((ext_vector_type(4))) _Float16 h4;
typedef __attribute__((ext_vector_type(4))) float   f32x4;

typedef __attribute__((address_space(1))) const unsigned int gu32;
typedef __attribute__((address_space(3))) unsigned int lu32;
static __device__ __forceinline__ void async16(const void* g, const void* l) {
    __builtin_amdgcn_global_load_lds((gu32*)g, (lu32*)(uint32_t)(uintptr_t)l, 16, 0, 0);
}

// ---------------- weight prep: transpose to [n][k] fp16 ----------------
__global__ __launch_bounds__(256)
void transpose_w(const float* __restrict__ src, half_t* __restrict__ dst,
                 int K, int N, int dstOff, int dstLS)
{
    int gid = blockIdx.x * 256 + threadIdx.x;
    int total = 3 * K * N;
    if (gid >= total) return;
    int l = gid / (K * N);
    int r = gid - l * (K * N);
    int k = r / N;
    int n = r - k * N;
    dst[(size_t)l * dstLS + dstOff + (size_t)n * K + k] = (half_t)src[gid];
}

__global__ __launch_bounds__(256)
void pack_bias(const float* __restrict__ bq, const float* __restrict__ bk,
               const float* __restrict__ bv, float* __restrict__ dst)
{
    int gid = blockIdx.x * 256 + threadIdx.x;
    if (gid >= 3 * 384) return;
    int l = gid / 384, c = gid - l * 384;
    float v = (c < 128) ? bq[l * 128 + c]
            : (c < 256) ? bk[l * 128 + c - 128]
                        : bv[l * 128 + c - 256];
    dst[gid] = v;
}

// ---------------- embedding (fp16 activation mirror only) ----------------
__global__ __launch_bounds__(256)
void embed_kernel(const float* __restrict__ s, const int* __restrict__ d,
                  const float* __restrict__ e_w, const float* __restrict__ e_b,
                  const float* __restrict__ ep_w, const float* __restrict__ ep_b,
                  half_t* __restrict__ xh)
{
    int gid = blockIdx.x * 256 + threadIdx.x;      // over TROWS*128
    int row = gid >> 7;
    int c   = gid & 127;
    int b = row / NCITY;
    int n = row - b * NCITY;
    const float* sp = s + ((size_t)b * NCITY + n) * 2;
    float v;
    if (n == 0) {
        v = sp[0] * ep_w[c] + sp[1] * ep_w[128 + c] + ep_b[c];
    } else {
        float dv = (float)d[b * NCITY + n];
        v = sp[0] * e_w[c] + sp[1] * e_w[128 + c] + dv * e_w[256 + c] + e_b[c];
    }
    xh[gid] = (half_t)v;
}

// ---------------- fp16 GEMM, 1-barrier double-buffered pipeline ----------------
// MODE 0: QKV — scatter fp16 to Q/K/V, all [bh][tok][16]
// MODE 1: out fp16 y = acc + bias + res(fp16), fused BN stats (O-proj)
template<int MODE, int KSTEPS>
__global__ __launch_bounds__(256)
void gemm_tile(const half_t* __restrict__ A, const half_t* __restrict__ B,
               const float* __restrict__ bias, const half_t* __restrict__ res,
               void* __restrict__ out, void* __restrict__ outK, void* __restrict__ outV,
               float* __restrict__ stats, int Nout)
{
    constexpr int K = KSTEPS * 32;
    __shared__ alignas(16) half_t sA[2][128 * 32];
    __shared__ alignas(16) half_t sB[2][128 * 32];

    const int tid  = threadIdx.x;
    const int wave = tid >> 6, lane = tid & 63;
    const int n0 = blockIdx.x * 128;
    const int m0 = blockIdx.y * 128;

    const int sr = wave * 16 + (lane >> 2);
    const int sc = (lane & 3) * 8;
    const half_t* gA = A + (size_t)(m0 + sr) * K + sc;
    const half_t* gB = B + (size_t)(n0 + sr) * K + sc;
    const int ldst = wave * 512;

    const int quad = lane >> 4, l16 = lane & 15;
    const int wm = (wave >> 1) * 64, wn = (wave & 1) * 64;

    f32x4 acc[4][4] = {};

    async16(gA,                  &sA[0][ldst]);
    async16(gA + (size_t)64 * K, &sA[0][2048 + ldst]);
    async16(gB,                  &sB[0][ldst]);
    async16(gB + (size_t)64 * K, &sB[0][2048 + ldst]);

    for (int ks = 0; ks < KSTEPS; ++ks) {
        __syncthreads();
        if (ks + 1 < KSTEPS) {
            const int k0 = (ks + 1) * 32;
            const int nb = (ks + 1) & 1;
            async16(gA + k0,                  &sA[nb][ldst]);
            async16(gA + (size_t)64 * K + k0, &sA[nb][2048 + ldst]);
            async16(gB + k0,                  &sB[nb][ldst]);
            async16(gB + (size_t)64 * K + k0, &sB[nb][2048 + ldst]);
        }
        const int cb = ks & 1;
        h8 af[4], bf[4];
        #pragma unroll
        for (int mi = 0; mi < 4; ++mi)
            af[mi] = *(const h8*)(&sA[cb][(wm + mi * 16 + l16) * 32 + quad * 8]);
        #pragma unroll
        for (int ni = 0; ni < 4; ++ni)
            bf[ni] = *(const h8*)(&sB[cb][(wn + ni * 16 + l16) * 32 + quad * 8]);
        #pragma unroll
        for (int mi = 0; mi < 4; ++mi)
        #pragma unroll
        for (int ni = 0; ni < 4; ++ni)
            acc[mi][ni] = __builtin_amdgcn_mfma_f32_16x16x32_f16(af[mi], bf[ni], acc[mi][ni], 0, 0, 0);
    }

    #pragma unroll
    for (int ni = 0; ni < 4; ++ni) {
        int col = n0 + wn + ni * 16 + l16;
        float bvv = bias[col];
        float s = 0.0f, ss = 0.0f;
        #pragma unroll
        for (int mi = 0; mi < 4; ++mi) {
            #pragma unroll
            for (int r = 0; r < 4; ++r) {
                int row = m0 + wm + mi * 16 + quad * 4 + r;
                float v = acc[mi][ni][r] + bvv;
                if (MODE == 0) {
                    int b   = row / NCITY;
                    int tok = row - b * NCITY;
                    int which = col >> 7;
                    int h     = (col >> 4) & 7;
                    int bh    = b * 8 + h;
                    half_t hv = (half_t)v;
                    half_t* dst = (which == 0) ? (half_t*)out
                                : (which == 1) ? (half_t*)outK : (half_t*)outV;
                    dst[((size_t)bh * NCITY + tok) * 16 + l16] = hv;
                } else {
                    size_t off = (size_t)row * Nout + col;
                    float o = v + (float)res[off];
                    ((half_t*)out)[off] = (half_t)o;
                    s += o; ss += o * o;
                }
            }
        }
        if (MODE == 1) {
            s  += __shfl_xor(s, 16);  s  += __shfl_xor(s, 32);
            ss += __shfl_xor(ss, 16); ss += __shfl_xor(ss, 32);
            if (quad == 0) {
                atomicAdd(&stats[col], s);
                atomicAdd(&stats[128 + col], ss);
            }
        }
    }
}

// ---------------- fused FF1(ReLU)+FF2: h1 never leaves LDS ----------------
// Per block: 128-row m-tile. xh tile resident (32 KB), loop 4 c-chunks of 128:
// stage wf1/wf2 chunks -> FF1 -> ReLU -> sH (A-frag layout) -> FF2 accumulate.
// Epilogue: y16 = acc + bf2 + res, fused BN stats.
__global__ __launch_bounds__(256)
void ff_fused(const half_t* __restrict__ xh, const half_t* __restrict__ w1,
              const half_t* __restrict__ w2, const float* __restrict__ bf1,
              const float* __restrict__ bf2, const half_t* __restrict__ res,
              half_t* __restrict__ y16, float* __restrict__ stats)
{
    __shared__ alignas(16) half_t sX[4][128 * 32];   // xh: [kc][row][32]
    __shared__ alignas(16) half_t sW1[4][128 * 32];  // wf1 chunk: [kc][n-row][32]
    __shared__ alignas(16) half_t sW2[4][128 * 32];  // wf2 chunk: [kc][n-row][32]
    __shared__ alignas(16) half_t sH[4][128 * 32];   // h1 chunk:  [kc][row][32]

    const int tid  = threadIdx.x;
    const int wave = tid >> 6, lane = tid & 63;
    const int m0 = blockIdx.x * 128;

    const int sr = wave * 16 + (lane >> 2);   // 0..63
    const int sc = (lane & 3) * 8;
    const int ldst = wave * 512;              // + lane*8 implicit in HW

    const int quad = lane >> 4, l16 = lane & 15;
    const int wm = (wave >> 1) * 64, wn = (wave & 1) * 64;

    // stage xh tile (K=128): 4 k-chunks x 2 row-halves
    #pragma unroll
    for (int kc = 0; kc < 4; ++kc) {
        async16(xh + (size_t)(m0 + sr) * 128 + kc * 32 + sc,      &sX[kc][ldst]);
        async16(xh + (size_t)(m0 + 64 + sr) * 128 + kc * 32 + sc, &sX[kc][2048 + ldst]);
    }

    f32x4 acc2[4][4] = {};

    for (int j = 0; j < 4; ++j) {
        __syncthreads();   // prev chunk's FF2 done with sW2/sH (no-op at j=0)
        // stage wf1 chunk j: rows j*128..+127 of [512][128]
        #pragma unroll
        for (int kc = 0; kc < 4; ++kc) {
            async16(w1 + (size_t)(j * 128 + sr) * 128 + kc * 32 + sc,      &sW1[kc][ldst]);
            async16(w1 + (size_t)(j * 128 + 64 + sr) * 128 + kc * 32 + sc, &sW1[kc][2048 + ldst]);
        }
        // stage wf2 chunk j: all 128 n-rows, k-range j*128..+127 of [128][512]
        #pragma unroll
        for (int kc = 0; kc < 4; ++kc) {
            async16(w2 + (size_t)sr * 512 + j * 128 + kc * 32 + sc,        &sW2[kc][ldst]);
            async16(w2 + (size_t)(64 + sr) * 512 + j * 128 + kc * 32 + sc, &sW2[kc][2048 + ldst]);
        }
        __syncthreads();   // drain staging (also covers sX at j=0)

        // FF1: h1[m][c] for c-chunk j (wave tile 64x64)
        f32x4 acc1[4][4] = {};
        #pragma unroll
        for (int kc = 0; kc < 4; ++kc) {
            h8 af[4], bf[4];
            #pragma unroll
            for (int mi = 0; mi < 4; ++mi)
                af[mi] = *(const h8*)(&sX[kc][(wm + mi * 16 + l16) * 32 + quad * 8]);
            #pragma unroll
            for (int ni = 0; ni < 4; ++ni)
                bf[ni] = *(const h8*)(&sW1[kc][(wn + ni * 16 + l16) * 32 + quad * 8]);
            #pragma unroll
            for (int mi = 0; mi < 4; ++mi)
            #pragma unroll
            for (int ni = 0; ni < 4; ++ni)
                acc1[mi][ni] = __builtin_amdgcn_mfma_f32_16x16x32_f16(af[mi], bf[ni], acc1[mi][ni], 0, 0, 0);
        }
        // ReLU + bias -> sH in A-frag layout [kc][row][32]
        #pragma unroll
        for (int ni = 0; ni < 4; ++ni) {
            int c = wn + ni * 16 + l16;          // chunk-local 0..127
            float bvv = bf1[j * 128 + c];
            #pragma unroll
            for (int mi = 0; mi < 4; ++mi)
            #pragma unroll
            for (int r = 0; r < 4; ++r) {
                int row = wm + mi * 16 + quad * 4 + r;
                float v = acc1[mi][ni][r] + bvv;
                v = v > 0.0f ? v : 0.0f;
                sH[c >> 5][row * 32 + (c & 31)] = (half_t)v;
            }
        }
        __syncthreads();   // sH visible

        // FF2 partial: acc2 += h1chunk * wf2chunk^T
        #pragma unroll
        for (int kc = 0; kc < 4; ++kc) {
            h8 af[4], bf[4];
            #pragma unroll
            for (int mi = 0; mi < 4; ++mi)
                af[mi] = *(const h8*)(&sH[kc][(wm + mi * 16 + l16) * 32 + quad * 8]);
            #pragma unroll
            for (int ni = 0; ni < 4; ++ni)
                bf[ni] = *(const h8*)(&sW2[kc][(wn + ni * 16 + l16) * 32 + quad * 8]);
            #pragma unroll
            for (int mi = 0; mi < 4; ++mi)
            #pragma unroll
            for (int ni = 0; ni < 4; ++ni)
                acc2[mi][ni] = __builtin_amdgcn_mfma_f32_16x16x32_f16(af[mi], bf[ni], acc2[mi][ni], 0, 0, 0);
        }
    }

    // epilogue (MODE 1 semantics)
    #pragma unroll
    for (int ni = 0; ni < 4; ++ni) {
        int col = wn + ni * 16 + l16;
        float bvv = bf2[col];
        float s = 0.0f, ss = 0.0f;
        #pragma unroll
        for (int mi = 0; mi < 4; ++mi) {
            #pragma unroll
            for (int r = 0; r < 4; ++r) {
                int row = m0 + wm + mi * 16 + quad * 4 + r;
                size_t off = (size_t)row * 128 + col;
                float o = acc2[mi][ni][r] + bvv + (float)res[off];
                y16[off] = (half_t)o;
                s += o; ss += o * o;
            }
        }
        s  += __shfl_xor(s, 16);  s  += __shfl_xor(s, 32);
        ss += __shfl_xor(ss, 16); ss += __shfl_xor(ss, 32);
        if (quad == 0) {
            atomicAdd(&stats[col], s);
            atomicAdd(&stats[128 + col], ss);
        }
    }
}

// ---------------- LDS-free fp16 MFMA attention: one wave per (bh, q-tile) ----------------
__global__ __launch_bounds__(256)
void attn_kernel(const half_t* __restrict__ Qh, const half_t* __restrict__ Kh,
                 const half_t* __restrict__ V, half_t* __restrict__ oh)
{
    const int wid = blockIdx.x * 4 + (threadIdx.x >> 6);
    const int bh = wid / 7;
    const int it = wid - bh * 7;
    if (bh >= NBH) return;
    const int b = bh >> 3, h = bh & 7;

    const int lane = threadIdx.x & 63, quad = lane >> 4, l16 = lane & 15;
    const int s0 = (((quad & 1) * 2)    ) * 16 + l16;
    const int s1 = (((quad & 1) * 2) + 1) * 16 + l16;
    const bool hi2 = (quad >> 1) != 0;

    const half_t* qbase = Qh + (size_t)bh * NCITY * 16;
    const half_t* kbase = Kh + (size_t)bh * NCITY * 16;
    const half_t* vbase = V  + (size_t)bh * NCITY * 16;

    h8 qf = {};
    if (quad < 2)
        qf = *reinterpret_cast<const h8*>(qbase + (it * 16 + l16) * 16 + quad * 8);

    f32x4 S[7];
    #pragma unroll
    for (int jt = 0; jt < 7; ++jt) {
        h8 kf = {};
        if (quad < 2)
            kf = *reinterpret_cast<const h8*>(kbase + (jt * 16 + l16) * 16 + quad * 8);
        f32x4 a = {};
        a = __builtin_amdgcn_mfma_f32_16x16x32_f16(kf, qf, a, 0, 0, 0);
        S[jt] = a;
    }
    float m = -1e30f;
    #pragma unroll
    for (int jt = 0; jt < 7; ++jt)
        #pragma unroll
        for (int r = 0; r < 4; ++r) {
            int jg = jt * 16 + quad * 4 + r;
            float sv = (jg < NCITY) ? S[jt][r] * 0.25f : -1e30f;
            S[jt][r] = sv;
            m = fmaxf(m, sv);
        }
    m = fmaxf(m, __shfl_xor(m, 16));
    m = fmaxf(m, __shfl_xor(m, 32));
    float sum = 0.0f;
    #pragma unroll
    for (int jt = 0; jt < 7; ++jt)
        #pragma unroll
        for (int r = 0; r < 4; ++r) {
            float e = __expf(S[jt][r] - m);
            S[jt][r] = e;
            sum += e;
        }
    sum += __shfl_xor(sum, 16);
    sum += __shfl_xor(sum, 32);
    float inv = 1.0f / sum;
    #pragma unroll
    for (int jt = 0; jt < 7; ++jt)
        #pragma unroll
        for (int r = 0; r < 4; ++r) S[jt][r] *= inv;

    f32x4 O = {};
    #pragma unroll
    for (int p = 0; p < 4; ++p) {
        h8 vf;
        #pragma unroll
        for (int jj = 0; jj < 8; ++jj)
            vf[jj] = vbase[(size_t)(p * 32 + quad * 8 + jj) * 16 + l16];
        float pj[8];
        #pragma unroll
        for (int r = 0; r < 4; ++r) {
            float a0 = __shfl(S[2 * p][r],     s0);
            float b0 = __shfl(S[2 * p + 1][r], s0);
            float a1 = __shfl(S[2 * p][r],     s1);
            float b1 = __shfl(S[2 * p + 1][r], s1);
            pj[r]     = hi2 ? b0 : a0;
            pj[4 + r] = hi2 ? b1 : a1;
        }
        h8 ph;
        #pragma unroll
        for (int jj = 0; jj < 8; ++jj)
            ph[jj] = (half_t)pj[jj];
        O = __builtin_amdgcn_mfma_f32_16x16x32_f16(ph, vf, O, 0, 0, 0);
    }
    #pragma unroll
    for (int r = 0; r < 4; ++r) {
        int q = it * 16 + quad * 4 + r;
        if (q < NCITY)
            oh[((size_t)b * NCITY + q) * 128 + h * 16 + l16] = (half_t)O[r];
    }
}

// ---------------- BatchNorm finalize (+ zero stats for next user) ----------------
__global__ void bn_final(float* __restrict__ stats, const float* __restrict__ g,
                         const float* __restrict__ be, float* __restrict__ sh)
{
    int c = threadIdx.x;  // 128 threads
    const float invN = 1.0f / (float)TROWS;
    float mean = stats[c] * invN;
    float var  = stats[128 + c] * invN - mean * mean;
    float inv  = rsqrtf(var + 1e-5f);
    float scl  = g[c] * inv;
    sh[c]       = scl;
    sh[128 + c] = be[c] - mean * scl;
    stats[c] = 0.0f;
    stats[128 + c] = 0.0f;
}

__global__ __launch_bounds__(256)
void bn_apply(const h8* __restrict__ y, const float* __restrict__ sh,
              half_t* __restrict__ xh, float* __restrict__ dst32)
{
    int gid = blockIdx.x * 256 + threadIdx.x;   // over TROWS*16 (8 ch each)
    int c = (gid & 15) * 8;
    h8 v = y[gid];
    h8 hv;
    float o[8];
    #pragma unroll
    for (int r = 0; r < 8; ++r) {
        o[r] = (float)v[r] * sh[c + r] + sh[128 + c + r];
        hv[r] = (half_t)o[r];
    }
    *reinterpret_cast<h8*>(xh + (size_t)gid * 8) = hv;
    if (dst32) {
        f32x4 lo = { o[0], o[1], o[2], o[3] };
        f32x4 hi = { o[4], o[5], o[6], o[7] };
        ((f32x4*)dst32)[gid * 2]     = lo;
        ((f32x4*)dst32)[gid * 2 + 1] = hi;
    }
}

// ---------------- launch ----------------
extern "C" void kernel_launch(void* const* d_in, const int* in_sizes, int n_in,
                              void* d_out, int out_size, void* d_ws, size_t ws_size,
                              hipStream_t stream)
{
    const float* s    = (const float*)d_in[0];
    const int*   dd   = (const int*)d_in[1];
    const float* e_w  = (const float*)d_in[2];
    const float* e_b  = (const float*)d_in[3];
    const float* ep_w = (const float*)d_in[4];
    const float* ep_b = (const float*)d_in[5];
    const float* Wq   = (const float*)d_in[6];
    const float* bq   = (const float*)d_in[7];
    const float* Wk   = (const float*)d_in[8];
    const float* bk   = (const float*)d_in[9];
    const float* Wv   = (const float*)d_in[10];
    const float* bv   = (const float*)d_in[11];
    const float* Wo   = (const float*)d_in[12];
    const float* bo   = (const float*)d_in[13];
    const float* Wf1  = (const float*)d_in[14];
    const float* bf1  = (const float*)d_in[15];
    const float* Wf2  = (const float*)d_in[16];
    const float* bf2  = (const float*)d_in[17];
    const float* g1   = (const float*)d_in[18];
    const float* be1  = (const float*)d_in[19];
    const float* g2   = (const float*)d_in[20];
    const float* be2  = (const float*)d_in[21];

    char* ws = (char*)d_ws;
    size_t off = 0;
    auto alloc = [&](size_t bytes) -> void* {
        void* p = ws + off;
        off += (bytes + 255) & ~(size_t)255;
        return p;
    };
    half_t* y16   = (half_t*)alloc((size_t)TROWS * 128 * 2);
    half_t* xh    = (half_t*)alloc((size_t)TROWS * 128 * 2);
    half_t* Qh    = (half_t*)alloc((size_t)NBH * NCITY * 16 * 2);
    half_t* Kh    = (half_t*)alloc((size_t)NBH * NCITY * 16 * 2);
    half_t* Vb    = (half_t*)alloc((size_t)NBH * NCITY * 16 * 2);
    half_t* oh    = (half_t*)alloc((size_t)TROWS * 128 * 2);
    half_t* wqkv  = (half_t*)alloc((size_t)3 * 384 * 128 * 2);
    half_t* wo    = (half_t*)alloc((size_t)3 * 128 * 128 * 2);
    half_t* wf1   = (half_t*)alloc((size_t)3 * 512 * 128 * 2);
    half_t* wf2   = (half_t*)alloc((size_t)3 * 128 * 512 * 2);
    float*  bqkv  = (float*) alloc((size_t)3 * 384 * 4);
    float*  stats = (float*) alloc(256 * 4);
    float*  sh    = (float*) alloc(256 * 4);

    dim3 blk(256);

    // stats must start zeroed (ws is poisoned); bn_final re-zeroes after each use
    hipMemsetAsync(stats, 0, 256 * 4, stream);

    // weight prep
    transpose_w<<<dim3(192), blk, 0, stream>>>(Wq,  wqkv, 128, 128, 0,     49152);
    transpose_w<<<dim3(192), blk, 0, stream>>>(Wk,  wqkv, 128, 128, 16384, 49152);
    transpose_w<<<dim3(192), blk, 0, stream>>>(Wv,  wqkv, 128, 128, 32768, 49152);
    transpose_w<<<dim3(192), blk, 0, stream>>>(Wo,  wo,   128, 128, 0,     16384);
    transpose_w<<<dim3(768), blk, 0, stream>>>(Wf1, wf1,  128, 512, 0,     65536);
    transpose_w<<<dim3(768), blk, 0, stream>>>(Wf2, wf2,  512, 128, 0,     65536);
    pack_bias<<<dim3(5), blk, 0, stream>>>(bq, bk, bv, bqkv);

    embed_kernel<<<dim3(TROWS * 128 / 256), blk, 0, stream>>>(s, dd, e_w, e_b, ep_w, ep_b, xh);

    for (int l = 0; l < 3; ++l) {
        // QKV -> Q/K/V all [bh][tok][16]
        gemm_tile<0, 4><<<dim3(3, 404), blk, 0, stream>>>(xh, wqkv + (size_t)l * 49152,
                                                          bqkv + l * 384, nullptr,
                                                          Qh, Kh, Vb, nullptr, 384);
        // attention (LDS-free fp16 MFMA)
        attn_kernel<<<dim3(7168), blk, 0, stream>>>(Qh, Kh, Vb, oh);
        // O-proj + bias + residual(xh) + fused BN1 stats -> y16
        gemm_tile<1, 4><<<dim3(1, 404), blk, 0, stream>>>(oh, wo + (size_t)l * 16384,
                                                          bo + l * 128, xh,
                                                          y16, nullptr, nullptr, stats, 128);
        bn_final<<<dim3(1), dim3(128), 0, stream>>>(stats, g1 + l * 128, be1 + l * 128, sh);
        bn_apply<<<dim3(TROWS * 16 / 256), blk, 0, stream>>>((const h8*)y16, sh, xh, nullptr);
        // fused FF1+FF2 (+ residual + BN2 stats) -> y16
        ff_fused<<<dim3(404), blk, 0, stream>>>(xh, wf1 + (size_t)l * 65536,
                                                wf2 + (size_t)l * 65536,
                                                bf1 + l * 512, bf2 + l * 128, xh,
                                                y16, stats);
        bn_final<<<dim3(1), dim3(128), 0, stream>>>(stats, g2 + l * 128, be2 + l * 128, sh);
        bn_apply<<<dim3(TROWS * 16 / 256), blk, 0, stream>>>((const h8*)y16, sh, xh,
                                                             (l == 2) ? (float*)d_out : nullptr);
    }
}